// Round 7
// baseline (422.526 us; speedup 1.0000x reference)
//
#include <hip/hip_runtime.h>
#include <hip/hip_fp16.h>

#define U_N 50000
#define I_N 100000
#define E_N 1600000
#define B_N 16384
#define UI_N (U_N + I_N)   // 150000
#define NB_U 782           // ceil(50000/64)
#define NB_I 1563          // ceil(100000/64)
#define NBK 586            // ceil(150000/256) buckets, 256 nodes each
#define CAP 10240          // entries per bucket (mean 8192 max, ~22 sigma margin)
#define NBLD 512           // blocks in k_build1
#define CHUNK (E_N / NBLD) // 3125 edges per block
#define COL_CAP 5600000    // >= 2E + 15*UI_N worst-case aligned CSR slots

// ---------------- CSR build: phase 1 (block-local binning, packed 4B entries) ---------
// entry = (key&255)<<17 | nbr   (nbr < 2^17; key bucket = key>>8)
__global__ __launch_bounds__(1024) void k_build1(
    const int* __restrict__ eu, const int* __restrict__ ei,
    int* __restrict__ bcnt, int* __restrict__ storage) {
  __shared__ int hist[NBK];
  __shared__ int lbase[NBK];
  __shared__ int loff[NBK];
  int t = threadIdx.x;
  for (int b = t; b < NBK; b += 1024) { hist[b] = 0; loff[b] = 0; }
  __syncthreads();
  int e0 = blockIdx.x * CHUNK;
  int e1 = e0 + CHUNK;
  for (int e = e0 + t; e < e1; e += 1024) {
    int u = eu[e];
    int k2 = U_N + ei[e];
    atomicAdd(&hist[u >> 8], 1);
    atomicAdd(&hist[k2 >> 8], 1);
  }
  __syncthreads();
  for (int b = t; b < NBK; b += 1024) {
    int h = hist[b];
    lbase[b] = h ? atomicAdd(&bcnt[b], h) : 0;
  }
  __syncthreads();
  for (int e = e0 + t; e < e1; e += 1024) {
    int u = eu[e], it = ei[e];
    int k2 = U_N + it;
    int b1 = u >> 8;
    int s1 = lbase[b1] + atomicAdd(&loff[b1], 1);
    storage[(size_t)b1 * CAP + s1] = ((u & 255) << 17) | it;
    int b2 = k2 >> 8;
    int s2 = lbase[b2] + atomicAdd(&loff[b2], 1);
    storage[(size_t)b2 * CAP + s2] = ((k2 & 255) << 17) | u;
  }
}

// ---------------- per-node degree counts from buckets ----------------
__global__ __launch_bounds__(256) void k_count(const int* __restrict__ bcnt,
                                               const int* __restrict__ storage,
                                               int* __restrict__ cnt) {
  __shared__ int c[256];
  int b = blockIdx.x;
  c[threadIdx.x] = 0;
  __syncthreads();
  int n = bcnt[b];
  const int* s = storage + (size_t)b * CAP;
  for (int i = threadIdx.x; i < n; i += 256) atomicAdd(&c[s[i] >> 17], 1);
  __syncthreads();
  int node = b * 256 + threadIdx.x;
  if (node <= UI_N) cnt[node] = c[threadIdx.x];  // cnt[UI_N] = 0 (scan tail)
}

// ---------------- CSR build: phase 2 (scatter + sentinel padding to 16-aligned) -------
__global__ __launch_bounds__(256) void k_build2(const int* __restrict__ bcnt,
                                                const int* __restrict__ storage,
                                                const int* __restrict__ ptr,
                                                int* __restrict__ col) {
  __shared__ int pb[256];
  __shared__ int cur[256];
  int b = blockIdx.x;
  int node = b * 256 + threadIdx.x;
  pb[threadIdx.x] = (node < UI_N) ? ptr[node] : 0;
  cur[threadIdx.x] = 0;
  __syncthreads();
  int n = bcnt[b];
  const int* s = storage + (size_t)b * CAP;
  for (int i = threadIdx.x; i < n; i += 256) {
    int e = s[i];
    int local = e >> 17;
    int slot = pb[local] + atomicAdd(&cur[local], 1);
    col[slot] = e & 0x1FFFF;
  }
  __syncthreads();
  if (node < UI_N) {
    int myEnd = pb[threadIdx.x] + cur[threadIdx.x];
    int padEnd = pb[threadIdx.x] + ((cur[threadIdx.x] + 15) & ~15);
    int sent = (node < U_N) ? I_N : U_N;   // sentinel neighbor index
    for (int j = myEnd; j < padEnd; j++) col[j] = sent;
  }
}

// ---------------- Prefix scans: ptr[n+1]-ptr[n] = align16(cnt[n]) ----------------
__global__ void k_scan1(const int* __restrict__ cnt, int* __restrict__ ptr,
                        int* __restrict__ bsum, int n) {
  __shared__ int lds[256];
  int t = threadIdx.x;
  int base = blockIdx.x * 1024 + t * 4;
  int v0 = (base + 0 < n) ? ((cnt[base + 0] + 15) & ~15) : 0;
  int v1 = (base + 1 < n) ? ((cnt[base + 1] + 15) & ~15) : 0;
  int v2 = (base + 2 < n) ? ((cnt[base + 2] + 15) & ~15) : 0;
  int v3 = (base + 3 < n) ? ((cnt[base + 3] + 15) & ~15) : 0;
  int s = v0 + v1 + v2 + v3;
  lds[t] = s;
  __syncthreads();
  int val = s;
  for (int off = 1; off < 256; off <<= 1) {
    int x = (t >= off) ? lds[t - off] : 0;
    __syncthreads();
    val += x;
    lds[t] = val;
    __syncthreads();
  }
  int excl = val - s;
  if (base + 0 < n) ptr[base + 0] = excl;
  if (base + 1 < n) ptr[base + 1] = excl + v0;
  if (base + 2 < n) ptr[base + 2] = excl + v0 + v1;
  if (base + 3 < n) ptr[base + 3] = excl + v0 + v1 + v2;
  if (t == 255) bsum[blockIdx.x] = val;
}

__global__ void k_scan2(int* __restrict__ bsum, int nb) {
  __shared__ int lds[256];
  int t = threadIdx.x;
  int v = (t < nb) ? bsum[t] : 0;
  lds[t] = v;
  __syncthreads();
  int val = v;
  for (int off = 1; off < 256; off <<= 1) {
    int x = (t >= off) ? lds[t - off] : 0;
    __syncthreads();
    val += x;
    lds[t] = val;
    __syncthreads();
  }
  if (t < nb) bsum[t] = val - v;
}

__global__ void k_scan3(int* __restrict__ ptr, const int* __restrict__ bsum, int n) {
  int i = blockIdx.x * blockDim.x + threadIdx.x;
  if (i < n) ptr[i] += bsum[i >> 10];
}

// ---------------- Sentinel init: +inf scores, zero feature rows ----------------
__global__ void k_sent(__half* f16U, __half* f16I, __half* s16U, __half* s16I,
                       __half* s2U, __half* s2I) {
  int t = threadIdx.x;
  unsigned short inf = 0x7C00;
  if (t < 64) {
    ((unsigned short*)f16U)[(size_t)U_N * 64 + t] = 0;
    ((unsigned short*)f16I)[(size_t)I_N * 64 + t] = 0;
  }
  if (t < 8) {
    ((unsigned short*)s16U)[(size_t)U_N * 8 + t] = inf;
    ((unsigned short*)s16I)[(size_t)I_N * 8 + t] = inf;
  }
  if (t == 0) {
    ((unsigned short*)s2U)[U_N] = inf;
    ((unsigned short*)s2I)[I_N] = inf;
  }
}

// ---------------- Fused matmul + attention scores (users + items, one launch) ---------
__global__ __launch_bounds__(256) void k_mm2(
    const float* Xu, const float* Xi,
    const float* __restrict__ Wu, const float* __restrict__ Wi,
    const float* __restrict__ a, int layer,
    float* featU, float* featI,
    __half* __restrict__ f16U, __half* __restrict__ f16I,
    __half* __restrict__ s16U, __half* __restrict__ s16I) {
  __shared__ float Wl[4096];
  __shared__ float Xs[4096];
  const bool isU = blockIdx.x < NB_U;
  const int N = isU ? U_N : I_N;
  const int base = (isU ? blockIdx.x : blockIdx.x - NB_U) * 64;
  const float* X = isU ? Xu : Xi;
  const float* W = isU ? Wu : Wi;
  float* feat = isU ? featU : featI;
  __half* f16 = isU ? f16U : f16I;
  __half* s16 = isU ? s16U : s16I;
  const int aoff = (layer == 1) ? (isU ? 0 : 8) : (isU ? 0 : 64);
  int t = threadIdx.x;

  if (layer == 1) {
#pragma unroll
    for (int k = 0; k < 4; k++) {
      int i = t + 256 * k;
      int h = i >> 7, d = (i >> 1) & 63, half = i & 1;
      float4 v = *(const float4*)(W + h * 512 + d * 8 + half * 4);
      *(float4*)(Wl + d * 64 + h * 8 + half * 4) = v;
    }
  } else {
#pragma unroll
    for (int k = 0; k < 4; k++) {
      int i = t + 256 * k;
      *(float4*)(Wl + i * 4) = *(const float4*)(W + i * 4);
    }
  }
#pragma unroll
  for (int k = 0; k < 4; k++) {
    int i = t + 256 * k;
    int r = i >> 4, ch = i & 15;
    int node = base + r;
    float4 v = make_float4(0.f, 0.f, 0.f, 0.f);
    if (node < N) v = *(const float4*)(X + (size_t)node * 64 + ch * 4);
    *(float4*)(Xs + r * 64 + ch * 4) = v;
  }
  __syncthreads();

  const int c0 = t & 31;
  const int rb = t >> 5;
  float acc0[8], acc1[8];
#pragma unroll
  for (int k = 0; k < 8; k++) { acc0[k] = 0.f; acc1[k] = 0.f; }

  for (int d0 = 0; d0 < 64; d0 += 4) {
    float2 wA = *(float2*)(Wl + (d0 + 0) * 64 + 2 * c0);
    float2 wB = *(float2*)(Wl + (d0 + 1) * 64 + 2 * c0);
    float2 wC = *(float2*)(Wl + (d0 + 2) * 64 + 2 * c0);
    float2 wD = *(float2*)(Wl + (d0 + 3) * 64 + 2 * c0);
#pragma unroll
    for (int k = 0; k < 8; k++) {
      float4 x = *(float4*)(Xs + (rb + 8 * k) * 64 + d0);
      acc0[k] += x.x * wA.x + x.y * wB.x + x.z * wC.x + x.w * wD.x;
      acc1[k] += x.x * wA.y + x.y * wB.y + x.z * wC.y + x.w * wD.y;
    }
  }

  float av0, av1;
  if (layer == 1) {
    int h = c0 >> 2, j = 2 * (c0 & 3);
    av0 = a[h * 16 + aoff + j];
    av1 = a[h * 16 + aoff + j + 1];
  } else {
    av0 = a[aoff + 2 * c0];
    av1 = a[aoff + 2 * c0 + 1];
  }
#pragma unroll
  for (int k = 0; k < 8; k++) {
    int node = base + rb + 8 * k;
    float s = acc0[k] * av0 + acc1[k] * av1;
    s += __shfl_xor(s, 1);
    s += __shfl_xor(s, 2);
    if (layer != 1) {
      s += __shfl_xor(s, 4);
      s += __shfl_xor(s, 8);
      s += __shfl_xor(s, 16);
    }
    if (node < N) {
      float2 f;
      f.x = acc0[k];
      f.y = acc1[k];
      *(float2*)(feat + (size_t)node * 64 + 2 * c0) = f;
      *(__half2*)(f16 + (size_t)node * 64 + 2 * c0) = __float22half2_rn(f);
      if (layer == 1) {
        if ((c0 & 3) == 0) s16[node * 8 + (c0 >> 2)] = __float2half_rn(s);
      } else {
        if (c0 == 0) s16[node] = __float2half_rn(s);
      }
    }
  }
}

// ---------------- Layer-2 edge weights (lane per edge; sentinel -> w=0) ---------------
__global__ __launch_bounds__(256) void k_ew2(const int* __restrict__ ptr,
                                             const int* __restrict__ col,
                                             const __half* __restrict__ s2U,
                                             const __half* __restrict__ s2I,
                                             __half* __restrict__ w2) {
  int gid = blockIdx.x * blockDim.x + threadIdx.x;
  int n = gid >> 6;
  if (n >= UI_N) return;
  int l = threadIdx.x & 63;
  bool isU = n < U_N;
  int nl = isU ? n : n - U_N;
  const __half* nbrS = isU ? s2I : s2U;
  float sself = __half2float((isU ? s2U : s2I)[nl]);
  int beg = ptr[n], endA = ptr[n + 1];
  for (int p = beg + l; p < endA; p += 64) {
    int nb = col[p];
    float x = sself + __half2float(nbrS[nb]);
    float w = __expf(-fmaxf(x, 0.2f * x));   // sentinel: x=+inf -> w=0
    w2[p] = __float2half_rn(w);
  }
}

// ---------------- Fused aggregation, IN PLACE, maskless, unroll-2 ----------------
__global__ __launch_bounds__(256) void k_agg2(
    const int* __restrict__ ptr, const int* __restrict__ col,
    float* selfU, float* selfI,
    const __half* __restrict__ f16U, const __half* __restrict__ f16I,
    const __half* __restrict__ s16U, const __half* __restrict__ s16I,
    const __half* __restrict__ w2, int layer) {
  int gid = blockIdx.x * blockDim.x + threadIdx.x;
  int n = gid >> 6;
  if (n >= UI_N) return;
  int l = threadIdx.x & 63;
  int g = l >> 3;       // edge group 0..7
  int cc = l & 7;       // feature chunk / head
  bool isU = n < U_N;
  int nl = isU ? n : n - U_N;
  const __half* nbrF = isU ? f16I : f16U;
  float* selfp = isU ? selfU : selfI;

  int beg = ptr[n], endA = ptr[n + 1];
  float acc[8];
#pragma unroll
  for (int k = 0; k < 8; k++) acc[k] = 0.f;
  float wsum = 0.f;

  if (layer == 1) {
    const __half* nbrS = isU ? s16I : s16U;
    const __half* selfS = isU ? s16U : s16I;
    float sself = __half2float(selfS[(size_t)nl * 8 + cc]);
    for (int p = beg; p < endA; p += 16) {
      int iA = p + g, iB = p + 8 + g;
      int nbA = col[iA], nbB = col[iB];
      float xA = sself + __half2float(nbrS[(size_t)nbA * 8 + cc]);
      float xB = sself + __half2float(nbrS[(size_t)nbB * 8 + cc]);
      float4 rA = *(const float4*)(nbrF + (size_t)nbA * 64 + cc * 8);
      float4 rB = *(const float4*)(nbrF + (size_t)nbB * 64 + cc * 8);
      float wA = __expf(-fmaxf(xA, 0.2f * xA));  // sentinel -> 0
      float wB = __expf(-fmaxf(xB, 0.2f * xB));
      wsum += wA + wB;
      const __half* hA = (const __half*)&rA;
      const __half* hB = (const __half*)&rB;
#pragma unroll
      for (int k = 0; k < 8; k++) acc[k] += wA * (float)hA[k];
#pragma unroll
      for (int k = 0; k < 8; k++) acc[k] += wB * (float)hB[k];
    }
  } else {
    for (int p = beg; p < endA; p += 16) {
      int iA = p + g, iB = p + 8 + g;
      int nbA = col[iA], nbB = col[iB];
      float wA = __half2float(w2[iA]);           // pads carry 0
      float wB = __half2float(w2[iB]);
      float4 rA = *(const float4*)(nbrF + (size_t)nbA * 64 + cc * 8);
      float4 rB = *(const float4*)(nbrF + (size_t)nbB * 64 + cc * 8);
      wsum += wA + wB;
      const __half* hA = (const __half*)&rA;
      const __half* hB = (const __half*)&rB;
#pragma unroll
      for (int k = 0; k < 8; k++) acc[k] += wA * (float)hA[k];
#pragma unroll
      for (int k = 0; k < 8; k++) acc[k] += wB * (float)hB[k];
    }
  }

#pragma unroll
  for (int k = 0; k < 8; k++) {
    acc[k] += __shfl_xor(acc[k], 8);
    acc[k] += __shfl_xor(acc[k], 16);
    acc[k] += __shfl_xor(acc[k], 32);
  }
  wsum += __shfl_xor(wsum, 8);
  wsum += __shfl_xor(wsum, 16);
  wsum += __shfl_xor(wsum, 32);

  if (l < 8) {
    float4 v0 = *(float4*)(selfp + (size_t)nl * 64 + cc * 8);
    float4 v1 = *(float4*)(selfp + (size_t)nl * 64 + cc * 8 + 4);
    if (endA > beg) {
      float inv = 1.f / wsum;
      v0.x += acc[0] * inv; v0.y += acc[1] * inv;
      v0.z += acc[2] * inv; v0.w += acc[3] * inv;
      v1.x += acc[4] * inv; v1.y += acc[5] * inv;
      v1.z += acc[6] * inv; v1.w += acc[7] * inv;
    }
    v0.x = (v0.x > 0.f) ? v0.x : (__expf(v0.x) - 1.f);
    v0.y = (v0.y > 0.f) ? v0.y : (__expf(v0.y) - 1.f);
    v0.z = (v0.z > 0.f) ? v0.z : (__expf(v0.z) - 1.f);
    v0.w = (v0.w > 0.f) ? v0.w : (__expf(v0.w) - 1.f);
    v1.x = (v1.x > 0.f) ? v1.x : (__expf(v1.x) - 1.f);
    v1.y = (v1.y > 0.f) ? v1.y : (__expf(v1.y) - 1.f);
    v1.z = (v1.z > 0.f) ? v1.z : (__expf(v1.z) - 1.f);
    v1.w = (v1.w > 0.f) ? v1.w : (__expf(v1.w) - 1.f);
    *(float4*)(selfp + (size_t)nl * 64 + cc * 8) = v0;
    *(float4*)(selfp + (size_t)nl * 64 + cc * 8 + 4) = v1;
  }
}

// ---------------- Final pair dot ----------------
__global__ void k_dot(const int* __restrict__ uIdx, const int* __restrict__ iIdx,
                      const float* __restrict__ u_f, const float* __restrict__ i_f,
                      float* __restrict__ out) {
  int t = threadIdx.x;
  int pair = blockIdx.x * 16 + (t >> 4);
  int cc = t & 15;
  float4 a = *(const float4*)(u_f + (size_t)uIdx[pair] * 64 + cc * 4);
  float4 b = *(const float4*)(i_f + (size_t)iIdx[pair] * 64 + cc * 4);
  float v = a.x * b.x + a.y * b.y + a.z * b.z + a.w * b.w;
  v += __shfl_xor(v, 1);
  v += __shfl_xor(v, 2);
  v += __shfl_xor(v, 4);
  v += __shfl_xor(v, 8);
  if (cc == 0) out[pair] = v;
}

extern "C" void kernel_launch(void* const* d_in, const int* in_sizes, int n_in,
                              void* d_out, int out_size, void* d_ws, size_t ws_size,
                              hipStream_t stream) {
  const int* userIdx = (const int*)d_in[0];
  const int* itemIdx = (const int*)d_in[1];
  const int* edge_u = (const int*)d_in[2];
  const int* edge_i = (const int*)d_in[3];
  const float* uEmbd = (const float*)d_in[4];
  const float* iEmbd = (const float*)d_in[5];
  const float* Wu_h = (const float*)d_in[6];
  const float* Wi_h = (const float*)d_in[7];
  const float* a_h = (const float*)d_in[8];
  const float* Wu_out = (const float*)d_in[9];
  const float* Wi_out = (const float*)d_in[10];
  const float* a_out = (const float*)d_in[11];
  float* out = (float*)d_out;

  char* w = (char*)d_ws;
  size_t off = 0;
  auto alloc = [&](size_t bytes) -> void* {
    void* p = w + off;
    off += (bytes + 511) & ~(size_t)511;
    return p;
  };
  int* bcnt = (int*)alloc((size_t)NBK * 4);
  int* cnt = (int*)alloc((size_t)(UI_N + 16) * 4);
  int* ptr = (int*)alloc((size_t)(UI_N + 1) * 4);
  int* bsum = (int*)alloc(1024);
  int* col = (int*)alloc((size_t)COL_CAP * 4);
  // union: storage (24 MB, dead after k_build2) aliases everything below
  size_t union_off = off;
  int* storage = (int*)alloc((size_t)NBK * CAP * 4);
  size_t end_storage = off;
  off = union_off;
  float* uF = (float*)alloc((size_t)U_N * 64 * 4);
  float* iF = (float*)alloc((size_t)I_N * 64 * 4);
  __half* f16U = (__half*)alloc((size_t)(U_N + 1) * 64 * 2);  // +1 sentinel row
  __half* f16I = (__half*)alloc((size_t)(I_N + 1) * 64 * 2);
  __half* s16U = (__half*)alloc(((size_t)U_N * 8 + 8) * 2);   // +8 sentinel scores
  __half* s16I = (__half*)alloc(((size_t)I_N * 8 + 8) * 2);
  __half* s2U = (__half*)alloc((size_t)(U_N + 1) * 2);        // layer-2 scores + sentinel
  __half* s2I = (__half*)alloc((size_t)(I_N + 1) * 2);
  __half* w2 = (__half*)alloc((size_t)COL_CAP * 2);           // layer-2 edge weights
  if (off < end_storage) off = end_storage;

  // CSR/CSC build (16-aligned rows, sentinel pads)
  hipMemsetAsync(bcnt, 0, (size_t)NBK * 4, stream);
  k_build1<<<NBLD, 1024, 0, stream>>>(edge_u, edge_i, bcnt, storage);
  k_count<<<NBK, 256, 0, stream>>>(bcnt, storage, cnt);
  const int nscan = UI_N + 1;
  const int nb1 = (nscan + 1023) / 1024;  // 147
  k_scan1<<<nb1, 256, 0, stream>>>(cnt, ptr, bsum, nscan);
  k_scan2<<<1, 256, 0, stream>>>(bsum, nb1);
  k_scan3<<<(nscan + 255) / 256, 256, 0, stream>>>(ptr, bsum, nscan);
  k_build2<<<NBK, 256, 0, stream>>>(bcnt, storage, ptr, col);
  k_sent<<<1, 256, 0, stream>>>(f16U, f16I, s16U, s16I, s2U, s2I);

  // Layer 1
  k_mm2<<<NB_U + NB_I, 256, 0, stream>>>(uEmbd, iEmbd, Wu_h, Wi_h, a_h, 1,
                                         uF, iF, f16U, f16I, s16U, s16I);
  k_agg2<<<UI_N * 64 / 256, 256, 0, stream>>>(ptr, col, uF, iF, f16U, f16I,
                                              s16U, s16I, w2, 1);

  // Layer 2 (in place), with precomputed edge weights
  k_mm2<<<NB_U + NB_I, 256, 0, stream>>>(uF, iF, Wu_out, Wi_out, a_out, 2,
                                         uF, iF, f16U, f16I, s2U, s2I);
  k_ew2<<<UI_N * 64 / 256, 256, 0, stream>>>(ptr, col, s2U, s2I, w2);
  k_agg2<<<UI_N * 64 / 256, 256, 0, stream>>>(ptr, col, uF, iF, f16U, f16I,
                                              s16U, s16I, w2, 2);

  // Final per-pair dot
  k_dot<<<B_N / 16, 256, 0, stream>>>(userIdx, itemIdx, uF, iF, out);
}

// Round 8
// 409.768 us; speedup vs baseline: 1.0311x; 1.0311x over previous
//
#include <hip/hip_runtime.h>
#include <hip/hip_fp16.h>

#define U_N 50000
#define I_N 100000
#define E_N 1600000
#define B_N 16384
#define UI_N (U_N + I_N)   // 150000
#define NB_U 782           // ceil(50000/64)
#define NB_I 1563          // ceil(100000/64)
#define NBK 586            // ceil(150000/256) buckets, 256 nodes each
#define CAP 10240          // entries per bucket (mean 8192 max, ~22 sigma margin)
#define NBLD 512           // blocks in k_build1
#define CHUNK (E_N / NBLD) // 3125 edges per block
#define COL_CAP 5600000    // >= 2E + 15*UI_N worst-case aligned CSR slots

// ---------------- CSR build: phase 1 (block-local binning, packed 4B entries) ---------
// entry = (key&255)<<17 | nbr   (nbr < 2^17; key bucket = key>>8)
__global__ __launch_bounds__(1024) void k_build1(
    const int* __restrict__ eu, const int* __restrict__ ei,
    int* __restrict__ bcnt, int* __restrict__ storage) {
  __shared__ int hist[NBK];
  __shared__ int lbase[NBK];
  __shared__ int loff[NBK];
  int t = threadIdx.x;
  for (int b = t; b < NBK; b += 1024) { hist[b] = 0; loff[b] = 0; }
  __syncthreads();
  int e0 = blockIdx.x * CHUNK;
  int e1 = e0 + CHUNK;
  for (int e = e0 + t; e < e1; e += 1024) {
    int u = eu[e];
    int k2 = U_N + ei[e];
    atomicAdd(&hist[u >> 8], 1);
    atomicAdd(&hist[k2 >> 8], 1);
  }
  __syncthreads();
  for (int b = t; b < NBK; b += 1024) {
    int h = hist[b];
    lbase[b] = h ? atomicAdd(&bcnt[b], h) : 0;
  }
  __syncthreads();
  for (int e = e0 + t; e < e1; e += 1024) {
    int u = eu[e], it = ei[e];
    int k2 = U_N + it;
    int b1 = u >> 8;
    int s1 = lbase[b1] + atomicAdd(&loff[b1], 1);
    storage[(size_t)b1 * CAP + s1] = ((u & 255) << 17) | it;
    int b2 = k2 >> 8;
    int s2 = lbase[b2] + atomicAdd(&loff[b2], 1);
    storage[(size_t)b2 * CAP + s2] = ((k2 & 255) << 17) | u;
  }
}

// ---------------- per-node degree counts from buckets ----------------
__global__ __launch_bounds__(256) void k_count(const int* __restrict__ bcnt,
                                               const int* __restrict__ storage,
                                               int* __restrict__ cnt) {
  __shared__ int c[256];
  int b = blockIdx.x;
  c[threadIdx.x] = 0;
  __syncthreads();
  int n = bcnt[b];
  const int* s = storage + (size_t)b * CAP;
  for (int i = threadIdx.x; i < n; i += 256) atomicAdd(&c[s[i] >> 17], 1);
  __syncthreads();
  int node = b * 256 + threadIdx.x;
  if (node <= UI_N) cnt[node] = c[threadIdx.x];  // cnt[UI_N] = 0 (scan tail)
}

// ---------------- CSR build: phase 2 (scatter + sentinel pads + sentinel tables) ------
__global__ __launch_bounds__(256) void k_build2(const int* __restrict__ bcnt,
                                                const int* __restrict__ storage,
                                                const int* __restrict__ ptr,
                                                int* __restrict__ col,
                                                __half* f16U, __half* f16I,
                                                __half* s16U, __half* s16I,
                                                __half* s2U, __half* s2I) {
  __shared__ int pb[256];
  __shared__ int cur[256];
  int b = blockIdx.x;
  int node = b * 256 + threadIdx.x;
  pb[threadIdx.x] = (node < UI_N) ? ptr[node] : 0;
  cur[threadIdx.x] = 0;
  __syncthreads();
  int n = bcnt[b];
  const int* s = storage + (size_t)b * CAP;
  for (int i = threadIdx.x; i < n; i += 256) {
    int e = s[i];
    int local = e >> 17;
    int slot = pb[local] + atomicAdd(&cur[local], 1);
    col[slot] = e & 0x1FFFF;
  }
  __syncthreads();
  if (node < UI_N) {
    int myEnd = pb[threadIdx.x] + cur[threadIdx.x];
    int padEnd = pb[threadIdx.x] + ((cur[threadIdx.x] + 15) & ~15);
    int sent = (node < U_N) ? I_N : U_N;   // sentinel neighbor index
    for (int j = myEnd; j < padEnd; j++) col[j] = sent;
  }
  // sentinel rows/scores (block 0 only): zero feature rows, +inf scores
  if (b == 0) {
    int t = threadIdx.x;
    unsigned short inf = 0x7C00;
    if (t < 64) {
      ((unsigned short*)f16U)[(size_t)U_N * 64 + t] = 0;
      ((unsigned short*)f16I)[(size_t)I_N * 64 + t] = 0;
    }
    if (t < 8) {
      ((unsigned short*)s16U)[(size_t)U_N * 8 + t] = inf;
      ((unsigned short*)s16I)[(size_t)I_N * 8 + t] = inf;
    }
    if (t == 0) {
      ((unsigned short*)s2U)[U_N] = inf;
      ((unsigned short*)s2I)[I_N] = inf;
    }
  }
}

// ---------------- Prefix scans: ptr[n+1]-ptr[n] = align16(cnt[n]) ----------------
__global__ void k_scan1(const int* __restrict__ cnt, int* __restrict__ ptr,
                        int* __restrict__ bsum, int n) {
  __shared__ int lds[256];
  int t = threadIdx.x;
  int base = blockIdx.x * 1024 + t * 4;
  int v0 = (base + 0 < n) ? ((cnt[base + 0] + 15) & ~15) : 0;
  int v1 = (base + 1 < n) ? ((cnt[base + 1] + 15) & ~15) : 0;
  int v2 = (base + 2 < n) ? ((cnt[base + 2] + 15) & ~15) : 0;
  int v3 = (base + 3 < n) ? ((cnt[base + 3] + 15) & ~15) : 0;
  int s = v0 + v1 + v2 + v3;
  lds[t] = s;
  __syncthreads();
  int val = s;
  for (int off = 1; off < 256; off <<= 1) {
    int x = (t >= off) ? lds[t - off] : 0;
    __syncthreads();
    val += x;
    lds[t] = val;
    __syncthreads();
  }
  int excl = val - s;
  if (base + 0 < n) ptr[base + 0] = excl;
  if (base + 1 < n) ptr[base + 1] = excl + v0;
  if (base + 2 < n) ptr[base + 2] = excl + v0 + v1;
  if (base + 3 < n) ptr[base + 3] = excl + v0 + v1 + v2;
  if (t == 255) bsum[blockIdx.x] = val;
}

__global__ void k_scan2(int* __restrict__ bsum, int nb) {
  __shared__ int lds[256];
  int t = threadIdx.x;
  int v = (t < nb) ? bsum[t] : 0;
  lds[t] = v;
  __syncthreads();
  int val = v;
  for (int off = 1; off < 256; off <<= 1) {
    int x = (t >= off) ? lds[t - off] : 0;
    __syncthreads();
    val += x;
    lds[t] = val;
    __syncthreads();
  }
  if (t < nb) bsum[t] = val - v;
}

__global__ void k_scan3(int* __restrict__ ptr, const int* __restrict__ bsum, int n) {
  int i = blockIdx.x * blockDim.x + threadIdx.x;
  if (i < n) ptr[i] += bsum[i >> 10];
}

// ---------------- Fused matmul + attention scores (users + items, one launch) ---------
__global__ __launch_bounds__(256) void k_mm2(
    const float* Xu, const float* Xi,
    const float* __restrict__ Wu, const float* __restrict__ Wi,
    const float* __restrict__ a, int layer,
    float* featU, float* featI,
    __half* __restrict__ f16U, __half* __restrict__ f16I,
    __half* __restrict__ s16U, __half* __restrict__ s16I) {
  __shared__ float Wl[4096];
  __shared__ float Xs[4096];
  const bool isU = blockIdx.x < NB_U;
  const int N = isU ? U_N : I_N;
  const int base = (isU ? blockIdx.x : blockIdx.x - NB_U) * 64;
  const float* X = isU ? Xu : Xi;
  const float* W = isU ? Wu : Wi;
  float* feat = isU ? featU : featI;
  __half* f16 = isU ? f16U : f16I;
  __half* s16 = isU ? s16U : s16I;
  const int aoff = (layer == 1) ? (isU ? 0 : 8) : (isU ? 0 : 64);
  int t = threadIdx.x;

  if (layer == 1) {
#pragma unroll
    for (int k = 0; k < 4; k++) {
      int i = t + 256 * k;
      int h = i >> 7, d = (i >> 1) & 63, half = i & 1;
      float4 v = *(const float4*)(W + h * 512 + d * 8 + half * 4);
      *(float4*)(Wl + d * 64 + h * 8 + half * 4) = v;
    }
  } else {
#pragma unroll
    for (int k = 0; k < 4; k++) {
      int i = t + 256 * k;
      *(float4*)(Wl + i * 4) = *(const float4*)(W + i * 4);
    }
  }
#pragma unroll
  for (int k = 0; k < 4; k++) {
    int i = t + 256 * k;
    int r = i >> 4, ch = i & 15;
    int node = base + r;
    float4 v = make_float4(0.f, 0.f, 0.f, 0.f);
    if (node < N) v = *(const float4*)(X + (size_t)node * 64 + ch * 4);
    *(float4*)(Xs + r * 64 + ch * 4) = v;
  }
  __syncthreads();

  const int c0 = t & 31;
  const int rb = t >> 5;
  float acc0[8], acc1[8];
#pragma unroll
  for (int k = 0; k < 8; k++) { acc0[k] = 0.f; acc1[k] = 0.f; }

  for (int d0 = 0; d0 < 64; d0 += 4) {
    float2 wA = *(float2*)(Wl + (d0 + 0) * 64 + 2 * c0);
    float2 wB = *(float2*)(Wl + (d0 + 1) * 64 + 2 * c0);
    float2 wC = *(float2*)(Wl + (d0 + 2) * 64 + 2 * c0);
    float2 wD = *(float2*)(Wl + (d0 + 3) * 64 + 2 * c0);
#pragma unroll
    for (int k = 0; k < 8; k++) {
      float4 x = *(float4*)(Xs + (rb + 8 * k) * 64 + d0);
      acc0[k] += x.x * wA.x + x.y * wB.x + x.z * wC.x + x.w * wD.x;
      acc1[k] += x.x * wA.y + x.y * wB.y + x.z * wC.y + x.w * wD.y;
    }
  }

  float av0, av1;
  if (layer == 1) {
    int h = c0 >> 2, j = 2 * (c0 & 3);
    av0 = a[h * 16 + aoff + j];
    av1 = a[h * 16 + aoff + j + 1];
  } else {
    av0 = a[aoff + 2 * c0];
    av1 = a[aoff + 2 * c0 + 1];
  }
#pragma unroll
  for (int k = 0; k < 8; k++) {
    int node = base + rb + 8 * k;
    float s = acc0[k] * av0 + acc1[k] * av1;
    s += __shfl_xor(s, 1);
    s += __shfl_xor(s, 2);
    if (layer != 1) {
      s += __shfl_xor(s, 4);
      s += __shfl_xor(s, 8);
      s += __shfl_xor(s, 16);
    }
    if (node < N) {
      float2 f;
      f.x = acc0[k];
      f.y = acc1[k];
      *(float2*)(feat + (size_t)node * 64 + 2 * c0) = f;
      *(__half2*)(f16 + (size_t)node * 64 + 2 * c0) = __float22half2_rn(f);
      if (layer == 1) {
        if ((c0 & 3) == 0) s16[node * 8 + (c0 >> 2)] = __float2half_rn(s);
      } else {
        if (c0 == 0) s16[node] = __float2half_rn(s);
      }
    }
  }
}

// ---------------- Fused aggregation, IN PLACE, maskless, unroll-2 ----------------
// One wave per node; 8 edges/group x 2 groups in flight; fp16 gathers; inline exp.
// layer1: per-head scores (stride 8); layer2: per-node scores (stride 1).
__global__ __launch_bounds__(256) void k_agg2(
    const int* __restrict__ ptr, const int* __restrict__ col,
    float* selfU, float* selfI,
    const __half* __restrict__ f16U, const __half* __restrict__ f16I,
    const __half* __restrict__ s16U, const __half* __restrict__ s16I,
    int layer) {
  int gid = blockIdx.x * blockDim.x + threadIdx.x;
  int n = gid >> 6;
  if (n >= UI_N) return;
  int l = threadIdx.x & 63;
  int g = l >> 3;       // edge group 0..7
  int cc = l & 7;       // feature chunk / head
  bool isU = n < U_N;
  int nl = isU ? n : n - U_N;
  const __half* nbrF = isU ? f16I : f16U;
  const __half* nbrS = isU ? s16I : s16U;
  const __half* selfS = isU ? s16U : s16I;
  float* selfp = isU ? selfU : selfI;

  int beg = ptr[n], endA = ptr[n + 1];
  float acc[8];
#pragma unroll
  for (int k = 0; k < 8; k++) acc[k] = 0.f;
  float wsum = 0.f;

  if (layer == 1) {
    float sself = __half2float(selfS[(size_t)nl * 8 + cc]);
    for (int p = beg; p < endA; p += 16) {
      int iA = p + g, iB = p + 8 + g;
      int nbA = __builtin_nontemporal_load(col + iA);
      int nbB = __builtin_nontemporal_load(col + iB);
      float xA = sself + __half2float(nbrS[(size_t)nbA * 8 + cc]);
      float xB = sself + __half2float(nbrS[(size_t)nbB * 8 + cc]);
      float4 rA = *(const float4*)(nbrF + (size_t)nbA * 64 + cc * 8);
      float4 rB = *(const float4*)(nbrF + (size_t)nbB * 64 + cc * 8);
      float wA = __expf(-fmaxf(xA, 0.2f * xA));  // sentinel -> 0
      float wB = __expf(-fmaxf(xB, 0.2f * xB));
      wsum += wA + wB;
      const __half* hA = (const __half*)&rA;
      const __half* hB = (const __half*)&rB;
#pragma unroll
      for (int k = 0; k < 8; k++) acc[k] += wA * (float)hA[k];
#pragma unroll
      for (int k = 0; k < 8; k++) acc[k] += wB * (float)hB[k];
    }
  } else {
    float sself = __half2float(selfS[nl]);
    for (int p = beg; p < endA; p += 16) {
      int iA = p + g, iB = p + 8 + g;
      int nbA = __builtin_nontemporal_load(col + iA);
      int nbB = __builtin_nontemporal_load(col + iB);
      float xA = sself + __half2float(nbrS[nbA]);
      float xB = sself + __half2float(nbrS[nbB]);
      float4 rA = *(const float4*)(nbrF + (size_t)nbA * 64 + cc * 8);
      float4 rB = *(const float4*)(nbrF + (size_t)nbB * 64 + cc * 8);
      float wA = __expf(-fmaxf(xA, 0.2f * xA));  // sentinel -> 0
      float wB = __expf(-fmaxf(xB, 0.2f * xB));
      wsum += wA + wB;
      const __half* hA = (const __half*)&rA;
      const __half* hB = (const __half*)&rB;
#pragma unroll
      for (int k = 0; k < 8; k++) acc[k] += wA * (float)hA[k];
#pragma unroll
      for (int k = 0; k < 8; k++) acc[k] += wB * (float)hB[k];
    }
  }

#pragma unroll
  for (int k = 0; k < 8; k++) {
    acc[k] += __shfl_xor(acc[k], 8);
    acc[k] += __shfl_xor(acc[k], 16);
    acc[k] += __shfl_xor(acc[k], 32);
  }
  wsum += __shfl_xor(wsum, 8);
  wsum += __shfl_xor(wsum, 16);
  wsum += __shfl_xor(wsum, 32);

  if (l < 8) {
    float4 v0 = *(float4*)(selfp + (size_t)nl * 64 + cc * 8);
    float4 v1 = *(float4*)(selfp + (size_t)nl * 64 + cc * 8 + 4);
    if (endA > beg) {
      float inv = 1.f / wsum;
      v0.x += acc[0] * inv; v0.y += acc[1] * inv;
      v0.z += acc[2] * inv; v0.w += acc[3] * inv;
      v1.x += acc[4] * inv; v1.y += acc[5] * inv;
      v1.z += acc[6] * inv; v1.w += acc[7] * inv;
    }
    v0.x = (v0.x > 0.f) ? v0.x : (__expf(v0.x) - 1.f);
    v0.y = (v0.y > 0.f) ? v0.y : (__expf(v0.y) - 1.f);
    v0.z = (v0.z > 0.f) ? v0.z : (__expf(v0.z) - 1.f);
    v0.w = (v0.w > 0.f) ? v0.w : (__expf(v0.w) - 1.f);
    v1.x = (v1.x > 0.f) ? v1.x : (__expf(v1.x) - 1.f);
    v1.y = (v1.y > 0.f) ? v1.y : (__expf(v1.y) - 1.f);
    v1.z = (v1.z > 0.f) ? v1.z : (__expf(v1.z) - 1.f);
    v1.w = (v1.w > 0.f) ? v1.w : (__expf(v1.w) - 1.f);
    *(float4*)(selfp + (size_t)nl * 64 + cc * 8) = v0;
    *(float4*)(selfp + (size_t)nl * 64 + cc * 8 + 4) = v1;
  }
}

// ---------------- Final pair dot ----------------
__global__ void k_dot(const int* __restrict__ uIdx, const int* __restrict__ iIdx,
                      const float* __restrict__ u_f, const float* __restrict__ i_f,
                      float* __restrict__ out) {
  int t = threadIdx.x;
  int pair = blockIdx.x * 16 + (t >> 4);
  int cc = t & 15;
  float4 a = *(const float4*)(u_f + (size_t)uIdx[pair] * 64 + cc * 4);
  float4 b = *(const float4*)(i_f + (size_t)iIdx[pair] * 64 + cc * 4);
  float v = a.x * b.x + a.y * b.y + a.z * b.z + a.w * b.w;
  v += __shfl_xor(v, 1);
  v += __shfl_xor(v, 2);
  v += __shfl_xor(v, 4);
  v += __shfl_xor(v, 8);
  if (cc == 0) out[pair] = v;
}

extern "C" void kernel_launch(void* const* d_in, const int* in_sizes, int n_in,
                              void* d_out, int out_size, void* d_ws, size_t ws_size,
                              hipStream_t stream) {
  const int* userIdx = (const int*)d_in[0];
  const int* itemIdx = (const int*)d_in[1];
  const int* edge_u = (const int*)d_in[2];
  const int* edge_i = (const int*)d_in[3];
  const float* uEmbd = (const float*)d_in[4];
  const float* iEmbd = (const float*)d_in[5];
  const float* Wu_h = (const float*)d_in[6];
  const float* Wi_h = (const float*)d_in[7];
  const float* a_h = (const float*)d_in[8];
  const float* Wu_out = (const float*)d_in[9];
  const float* Wi_out = (const float*)d_in[10];
  const float* a_out = (const float*)d_in[11];
  float* out = (float*)d_out;

  char* w = (char*)d_ws;
  size_t off = 0;
  auto alloc = [&](size_t bytes) -> void* {
    void* p = w + off;
    off += (bytes + 511) & ~(size_t)511;
    return p;
  };
  int* bcnt = (int*)alloc((size_t)NBK * 4);
  int* cnt = (int*)alloc((size_t)(UI_N + 16) * 4);
  int* ptr = (int*)alloc((size_t)(UI_N + 1) * 4);
  int* bsum = (int*)alloc(1024);
  int* col = (int*)alloc((size_t)COL_CAP * 4);
  // union: storage (24 MB, dead after k_build2) aliases everything below
  size_t union_off = off;
  int* storage = (int*)alloc((size_t)NBK * CAP * 4);
  size_t end_storage = off;
  off = union_off;
  float* uF = (float*)alloc((size_t)U_N * 64 * 4);
  float* iF = (float*)alloc((size_t)I_N * 64 * 4);
  __half* f16U = (__half*)alloc((size_t)(U_N + 1) * 64 * 2);  // +1 sentinel row
  __half* f16I = (__half*)alloc((size_t)(I_N + 1) * 64 * 2);
  __half* s16U = (__half*)alloc(((size_t)U_N * 8 + 8) * 2);   // +8 sentinel scores
  __half* s16I = (__half*)alloc(((size_t)I_N * 8 + 8) * 2);
  __half* s2U = (__half*)alloc((size_t)(U_N + 1) * 2);        // layer-2 scores + sentinel
  __half* s2I = (__half*)alloc((size_t)(I_N + 1) * 2);
  if (off < end_storage) off = end_storage;

  // CSR/CSC build (16-aligned rows, sentinel pads + sentinel tables)
  hipMemsetAsync(bcnt, 0, (size_t)NBK * 4, stream);
  k_build1<<<NBLD, 1024, 0, stream>>>(edge_u, edge_i, bcnt, storage);
  k_count<<<NBK, 256, 0, stream>>>(bcnt, storage, cnt);
  const int nscan = UI_N + 1;
  const int nb1 = (nscan + 1023) / 1024;  // 147
  k_scan1<<<nb1, 256, 0, stream>>>(cnt, ptr, bsum, nscan);
  k_scan2<<<1, 256, 0, stream>>>(bsum, nb1);
  k_scan3<<<(nscan + 255) / 256, 256, 0, stream>>>(ptr, bsum, nscan);
  k_build2<<<NBK, 256, 0, stream>>>(bcnt, storage, ptr, col,
                                    f16U, f16I, s16U, s16I, s2U, s2I);

  // Layer 1
  k_mm2<<<NB_U + NB_I, 256, 0, stream>>>(uEmbd, iEmbd, Wu_h, Wi_h, a_h, 1,
                                         uF, iF, f16U, f16I, s16U, s16I);
  k_agg2<<<UI_N * 64 / 256, 256, 0, stream>>>(ptr, col, uF, iF, f16U, f16I,
                                              s16U, s16I, 1);

  // Layer 2 (in place), inline edge weights from s2 tables
  k_mm2<<<NB_U + NB_I, 256, 0, stream>>>(uF, iF, Wu_out, Wi_out, a_out, 2,
                                         uF, iF, f16U, f16I, s2U, s2I);
  k_agg2<<<UI_N * 64 / 256, 256, 0, stream>>>(ptr, col, uF, iF, f16U, f16I,
                                              s2U, s2I, 2);

  // Final per-pair dot
  k_dot<<<B_N / 16, 256, 0, stream>>>(userIdx, itemIdx, uF, iF, out);
}

// Round 9
// 392.208 us; speedup vs baseline: 1.0773x; 1.0448x over previous
//
#include <hip/hip_runtime.h>
#include <hip/hip_fp16.h>

#define U_N 50000
#define I_N 100000
#define E_N 1600000
#define B_N 16384
#define UI_N (U_N + I_N)   // 150000
#define NB_U 782           // ceil(50000/64)
#define NB_I 1563          // ceil(100000/64)
#define NBK 586            // ceil(150000/256) buckets, 256 nodes each
#define CAP 10240          // entries per bucket (mean 8192 max, ~22 sigma margin)
#define NBLD 512           // blocks in k_build1
#define CHUNK (E_N / NBLD) // 3125 edges per block
#define COL_CAP 5600000    // >= 2E + 15*UI_N worst-case aligned CSR slots

// ---------------- CSR build: phase 1 (block-local binning, packed 4B entries) ---------
// entry = (key&255)<<17 | nbr   (nbr < 2^17; key bucket = key>>8)
__global__ __launch_bounds__(1024) void k_build1(
    const int* __restrict__ eu, const int* __restrict__ ei,
    int* __restrict__ bcnt, int* __restrict__ storage) {
  __shared__ int hist[NBK];
  __shared__ int lbase[NBK];
  __shared__ int loff[NBK];
  int t = threadIdx.x;
  for (int b = t; b < NBK; b += 1024) { hist[b] = 0; loff[b] = 0; }
  __syncthreads();
  int e0 = blockIdx.x * CHUNK;
  int e1 = e0 + CHUNK;
  for (int e = e0 + t; e < e1; e += 1024) {
    int u = eu[e];
    int k2 = U_N + ei[e];
    atomicAdd(&hist[u >> 8], 1);
    atomicAdd(&hist[k2 >> 8], 1);
  }
  __syncthreads();
  for (int b = t; b < NBK; b += 1024) {
    int h = hist[b];
    lbase[b] = h ? atomicAdd(&bcnt[b], h) : 0;
  }
  __syncthreads();
  for (int e = e0 + t; e < e1; e += 1024) {
    int u = eu[e], it = ei[e];
    int k2 = U_N + it;
    int b1 = u >> 8;
    int s1 = lbase[b1] + atomicAdd(&loff[b1], 1);
    storage[(size_t)b1 * CAP + s1] = ((u & 255) << 17) | it;
    int b2 = k2 >> 8;
    int s2 = lbase[b2] + atomicAdd(&loff[b2], 1);
    storage[(size_t)b2 * CAP + s2] = ((k2 & 255) << 17) | u;
  }
}

// ---------------- per-node degrees + per-bucket aligned slot totals ----------------
__global__ __launch_bounds__(256) void k_count(const int* __restrict__ bcnt,
                                               const int* __restrict__ storage,
                                               int* __restrict__ cnt,
                                               int* __restrict__ bsum) {
  __shared__ int c[256];
  __shared__ int red[256];
  int b = blockIdx.x;
  int t = threadIdx.x;
  c[t] = 0;
  __syncthreads();
  int n = bcnt[b];
  const int* s = storage + (size_t)b * CAP;
  for (int i = t; i < n; i += 256) atomicAdd(&c[s[i] >> 17], 1);
  __syncthreads();
  int node = b * 256 + t;
  int deg = c[t];                 // 0 for nonexistent nodes (keys can't occur)
  if (node < UI_N) cnt[node] = deg;
  // reduce aligned slot counts -> bsum[b]
  red[t] = (deg + 15) & ~15;
  __syncthreads();
  for (int off = 128; off > 0; off >>= 1) {
    if (t < off) red[t] += red[t + off];
    __syncthreads();
  }
  if (t == 0) bsum[b] = red[0];
}

// ---------------- single-block exclusive scan over bucket totals ----------------
__global__ __launch_bounds__(1024) void k_scanb(const int* __restrict__ bsum,
                                                int* __restrict__ bbase) {
  __shared__ int sc[1024];
  int t = threadIdx.x;
  int v = (t < NBK) ? bsum[t] : 0;
  sc[t] = v;
  __syncthreads();
  int val = v;
  for (int off = 1; off < 1024; off <<= 1) {
    int x = (t >= off) ? sc[t - off] : 0;
    __syncthreads();
    val += x;
    sc[t] = val;
    __syncthreads();
  }
  if (t < NBK) bbase[t] = val - v;  // exclusive
}

// ---- CSR build: phase 2 (local prefix -> ptr, scatter, sentinel pads + tables) ------
__global__ __launch_bounds__(256) void k_build2(const int* __restrict__ bcnt,
                                                const int* __restrict__ storage,
                                                const int* __restrict__ cnt,
                                                const int* __restrict__ bbase,
                                                int* __restrict__ ptr,
                                                int* __restrict__ col,
                                                __half* f16U, __half* f16I,
                                                __half* s16U, __half* s16I,
                                                __half* s2U, __half* s2I) {
  __shared__ int pb[256];
  __shared__ int cur[256];
  __shared__ int sc[256];
  int b = blockIdx.x;
  int t = threadIdx.x;
  int node = b * 256 + t;
  int deg = (node < UI_N) ? cnt[node] : 0;
  int al = (deg + 15) & ~15;
  // exclusive prefix of al within the bucket
  sc[t] = al;
  __syncthreads();
  int val = al;
  for (int off = 1; off < 256; off <<= 1) {
    int x = (t >= off) ? sc[t - off] : 0;
    __syncthreads();
    val += x;
    sc[t] = val;
    __syncthreads();
  }
  int base = bbase[b];
  int myPtr = base + (val - al);
  pb[t] = myPtr;
  cur[t] = 0;
  if (node < UI_N) ptr[node] = myPtr;
  if (b == NBK - 1 && t == 255) ptr[UI_N] = base + val;  // total end
  __syncthreads();
  int n = bcnt[b];
  const int* s = storage + (size_t)b * CAP;
  for (int i = t; i < n; i += 256) {
    int e = s[i];
    int local = e >> 17;
    int slot = pb[local] + atomicAdd(&cur[local], 1);
    col[slot] = e & 0x1FFFF;
  }
  __syncthreads();
  if (node < UI_N) {
    int myEnd = pb[t] + cur[t];
    int padEnd = pb[t] + al;
    int sent = (node < U_N) ? I_N : U_N;   // sentinel neighbor index
    for (int j = myEnd; j < padEnd; j++) col[j] = sent;
  }
  // sentinel rows/scores (block 0 only): zero feature rows, +inf scores
  if (b == 0) {
    unsigned short inf = 0x7C00;
    if (t < 64) {
      ((unsigned short*)f16U)[(size_t)U_N * 64 + t] = 0;
      ((unsigned short*)f16I)[(size_t)I_N * 64 + t] = 0;
    }
    if (t < 8) {
      ((unsigned short*)s16U)[(size_t)U_N * 8 + t] = inf;
      ((unsigned short*)s16I)[(size_t)I_N * 8 + t] = inf;
    }
    if (t == 0) {
      ((unsigned short*)s2U)[U_N] = inf;
      ((unsigned short*)s2I)[I_N] = inf;
    }
  }
}

// ---------------- Fused matmul + attention scores (users + items, one launch) ---------
__global__ __launch_bounds__(256) void k_mm2(
    const float* Xu, const float* Xi,
    const float* __restrict__ Wu, const float* __restrict__ Wi,
    const float* __restrict__ a, int layer,
    float* featU, float* featI,
    __half* __restrict__ f16U, __half* __restrict__ f16I,
    __half* __restrict__ s16U, __half* __restrict__ s16I) {
  __shared__ float Wl[4096];
  __shared__ float Xs[4096];
  const bool isU = blockIdx.x < NB_U;
  const int N = isU ? U_N : I_N;
  const int base = (isU ? blockIdx.x : blockIdx.x - NB_U) * 64;
  const float* X = isU ? Xu : Xi;
  const float* W = isU ? Wu : Wi;
  float* feat = isU ? featU : featI;
  __half* f16 = isU ? f16U : f16I;
  __half* s16 = isU ? s16U : s16I;
  const int aoff = (layer == 1) ? (isU ? 0 : 8) : (isU ? 0 : 64);
  int t = threadIdx.x;

  if (layer == 1) {
#pragma unroll
    for (int k = 0; k < 4; k++) {
      int i = t + 256 * k;
      int h = i >> 7, d = (i >> 1) & 63, half = i & 1;
      float4 v = *(const float4*)(W + h * 512 + d * 8 + half * 4);
      *(float4*)(Wl + d * 64 + h * 8 + half * 4) = v;
    }
  } else {
#pragma unroll
    for (int k = 0; k < 4; k++) {
      int i = t + 256 * k;
      *(float4*)(Wl + i * 4) = *(const float4*)(W + i * 4);
    }
  }
#pragma unroll
  for (int k = 0; k < 4; k++) {
    int i = t + 256 * k;
    int r = i >> 4, ch = i & 15;
    int node = base + r;
    float4 v = make_float4(0.f, 0.f, 0.f, 0.f);
    if (node < N) v = *(const float4*)(X + (size_t)node * 64 + ch * 4);
    *(float4*)(Xs + r * 64 + ch * 4) = v;
  }
  __syncthreads();

  const int c0 = t & 31;
  const int rb = t >> 5;
  float acc0[8], acc1[8];
#pragma unroll
  for (int k = 0; k < 8; k++) { acc0[k] = 0.f; acc1[k] = 0.f; }

  for (int d0 = 0; d0 < 64; d0 += 4) {
    float2 wA = *(float2*)(Wl + (d0 + 0) * 64 + 2 * c0);
    float2 wB = *(float2*)(Wl + (d0 + 1) * 64 + 2 * c0);
    float2 wC = *(float2*)(Wl + (d0 + 2) * 64 + 2 * c0);
    float2 wD = *(float2*)(Wl + (d0 + 3) * 64 + 2 * c0);
#pragma unroll
    for (int k = 0; k < 8; k++) {
      float4 x = *(float4*)(Xs + (rb + 8 * k) * 64 + d0);
      acc0[k] += x.x * wA.x + x.y * wB.x + x.z * wC.x + x.w * wD.x;
      acc1[k] += x.x * wA.y + x.y * wB.y + x.z * wC.y + x.w * wD.y;
    }
  }

  float av0, av1;
  if (layer == 1) {
    int h = c0 >> 2, j = 2 * (c0 & 3);
    av0 = a[h * 16 + aoff + j];
    av1 = a[h * 16 + aoff + j + 1];
  } else {
    av0 = a[aoff + 2 * c0];
    av1 = a[aoff + 2 * c0 + 1];
  }
#pragma unroll
  for (int k = 0; k < 8; k++) {
    int node = base + rb + 8 * k;
    float s = acc0[k] * av0 + acc1[k] * av1;
    s += __shfl_xor(s, 1);
    s += __shfl_xor(s, 2);
    if (layer != 1) {
      s += __shfl_xor(s, 4);
      s += __shfl_xor(s, 8);
      s += __shfl_xor(s, 16);
    }
    if (node < N) {
      float2 f;
      f.x = acc0[k];
      f.y = acc1[k];
      *(float2*)(feat + (size_t)node * 64 + 2 * c0) = f;
      *(__half2*)(f16 + (size_t)node * 64 + 2 * c0) = __float22half2_rn(f);
      if (layer == 1) {
        if ((c0 & 3) == 0) s16[node * 8 + (c0 >> 2)] = __float2half_rn(s);
      } else {
        if (c0 == 0) s16[node] = __float2half_rn(s);
      }
    }
  }
}

// ---------------- Fused aggregation, IN PLACE, maskless, unroll-2 ----------------
// One wave per node; 8 edges/group x 2 groups in flight; fp16 gathers; inline exp.
__global__ __launch_bounds__(256) void k_agg2(
    const int* __restrict__ ptr, const int* __restrict__ col,
    float* selfU, float* selfI,
    const __half* __restrict__ f16U, const __half* __restrict__ f16I,
    const __half* __restrict__ s16U, const __half* __restrict__ s16I,
    int layer) {
  int gid = blockIdx.x * blockDim.x + threadIdx.x;
  int n = gid >> 6;
  if (n >= UI_N) return;
  int l = threadIdx.x & 63;
  int g = l >> 3;       // edge group 0..7
  int cc = l & 7;       // feature chunk / head
  bool isU = n < U_N;
  int nl = isU ? n : n - U_N;
  const __half* nbrF = isU ? f16I : f16U;
  const __half* nbrS = isU ? s16I : s16U;
  const __half* selfS = isU ? s16U : s16I;
  float* selfp = isU ? selfU : selfI;

  int beg = ptr[n], endA = ptr[n + 1];
  float acc[8];
#pragma unroll
  for (int k = 0; k < 8; k++) acc[k] = 0.f;
  float wsum = 0.f;

  if (layer == 1) {
    float sself = __half2float(selfS[(size_t)nl * 8 + cc]);
    for (int p = beg; p < endA; p += 16) {
      int iA = p + g, iB = p + 8 + g;
      int nbA = col[iA];
      int nbB = col[iB];
      float xA = sself + __half2float(nbrS[(size_t)nbA * 8 + cc]);
      float xB = sself + __half2float(nbrS[(size_t)nbB * 8 + cc]);
      float4 rA = *(const float4*)(nbrF + (size_t)nbA * 64 + cc * 8);
      float4 rB = *(const float4*)(nbrF + (size_t)nbB * 64 + cc * 8);
      float wA = __expf(-fmaxf(xA, 0.2f * xA));  // sentinel -> 0
      float wB = __expf(-fmaxf(xB, 0.2f * xB));
      wsum += wA + wB;
      const __half* hA = (const __half*)&rA;
      const __half* hB = (const __half*)&rB;
#pragma unroll
      for (int k = 0; k < 8; k++) acc[k] += wA * (float)hA[k];
#pragma unroll
      for (int k = 0; k < 8; k++) acc[k] += wB * (float)hB[k];
    }
  } else {
    float sself = __half2float(selfS[nl]);
    for (int p = beg; p < endA; p += 16) {
      int iA = p + g, iB = p + 8 + g;
      int nbA = col[iA];
      int nbB = col[iB];
      float xA = sself + __half2float(nbrS[nbA]);
      float xB = sself + __half2float(nbrS[nbB]);
      float4 rA = *(const float4*)(nbrF + (size_t)nbA * 64 + cc * 8);
      float4 rB = *(const float4*)(nbrF + (size_t)nbB * 64 + cc * 8);
      float wA = __expf(-fmaxf(xA, 0.2f * xA));  // sentinel -> 0
      float wB = __expf(-fmaxf(xB, 0.2f * xB));
      wsum += wA + wB;
      const __half* hA = (const __half*)&rA;
      const __half* hB = (const __half*)&rB;
#pragma unroll
      for (int k = 0; k < 8; k++) acc[k] += wA * (float)hA[k];
#pragma unroll
      for (int k = 0; k < 8; k++) acc[k] += wB * (float)hB[k];
    }
  }

#pragma unroll
  for (int k = 0; k < 8; k++) {
    acc[k] += __shfl_xor(acc[k], 8);
    acc[k] += __shfl_xor(acc[k], 16);
    acc[k] += __shfl_xor(acc[k], 32);
  }
  wsum += __shfl_xor(wsum, 8);
  wsum += __shfl_xor(wsum, 16);
  wsum += __shfl_xor(wsum, 32);

  if (l < 8) {
    float4 v0 = *(float4*)(selfp + (size_t)nl * 64 + cc * 8);
    float4 v1 = *(float4*)(selfp + (size_t)nl * 64 + cc * 8 + 4);
    if (endA > beg) {
      float inv = 1.f / wsum;
      v0.x += acc[0] * inv; v0.y += acc[1] * inv;
      v0.z += acc[2] * inv; v0.w += acc[3] * inv;
      v1.x += acc[4] * inv; v1.y += acc[5] * inv;
      v1.z += acc[6] * inv; v1.w += acc[7] * inv;
    }
    v0.x = (v0.x > 0.f) ? v0.x : (__expf(v0.x) - 1.f);
    v0.y = (v0.y > 0.f) ? v0.y : (__expf(v0.y) - 1.f);
    v0.z = (v0.z > 0.f) ? v0.z : (__expf(v0.z) - 1.f);
    v0.w = (v0.w > 0.f) ? v0.w : (__expf(v0.w) - 1.f);
    v1.x = (v1.x > 0.f) ? v1.x : (__expf(v1.x) - 1.f);
    v1.y = (v1.y > 0.f) ? v1.y : (__expf(v1.y) - 1.f);
    v1.z = (v1.z > 0.f) ? v1.z : (__expf(v1.z) - 1.f);
    v1.w = (v1.w > 0.f) ? v1.w : (__expf(v1.w) - 1.f);
    *(float4*)(selfp + (size_t)nl * 64 + cc * 8) = v0;
    *(float4*)(selfp + (size_t)nl * 64 + cc * 8 + 4) = v1;
  }
}

// ---------------- Final pair dot ----------------
__global__ void k_dot(const int* __restrict__ uIdx, const int* __restrict__ iIdx,
                      const float* __restrict__ u_f, const float* __restrict__ i_f,
                      float* __restrict__ out) {
  int t = threadIdx.x;
  int pair = blockIdx.x * 16 + (t >> 4);
  int cc = t & 15;
  float4 a = *(const float4*)(u_f + (size_t)uIdx[pair] * 64 + cc * 4);
  float4 b = *(const float4*)(i_f + (size_t)iIdx[pair] * 64 + cc * 4);
  float v = a.x * b.x + a.y * b.y + a.z * b.z + a.w * b.w;
  v += __shfl_xor(v, 1);
  v += __shfl_xor(v, 2);
  v += __shfl_xor(v, 4);
  v += __shfl_xor(v, 8);
  if (cc == 0) out[pair] = v;
}

extern "C" void kernel_launch(void* const* d_in, const int* in_sizes, int n_in,
                              void* d_out, int out_size, void* d_ws, size_t ws_size,
                              hipStream_t stream) {
  const int* userIdx = (const int*)d_in[0];
  const int* itemIdx = (const int*)d_in[1];
  const int* edge_u = (const int*)d_in[2];
  const int* edge_i = (const int*)d_in[3];
  const float* uEmbd = (const float*)d_in[4];
  const float* iEmbd = (const float*)d_in[5];
  const float* Wu_h = (const float*)d_in[6];
  const float* Wi_h = (const float*)d_in[7];
  const float* a_h = (const float*)d_in[8];
  const float* Wu_out = (const float*)d_in[9];
  const float* Wi_out = (const float*)d_in[10];
  const float* a_out = (const float*)d_in[11];
  float* out = (float*)d_out;

  char* w = (char*)d_ws;
  size_t off = 0;
  auto alloc = [&](size_t bytes) -> void* {
    void* p = w + off;
    off += (bytes + 511) & ~(size_t)511;
    return p;
  };
  int* bcnt = (int*)alloc((size_t)NBK * 4);
  int* cnt = (int*)alloc((size_t)UI_N * 4);
  int* ptr = (int*)alloc((size_t)(UI_N + 1) * 4);
  int* bsum = (int*)alloc(4096);
  int* bbase = (int*)alloc(4096);
  int* col = (int*)alloc((size_t)COL_CAP * 4);
  // union: storage (24 MB, dead after k_build2) aliases everything below
  size_t union_off = off;
  int* storage = (int*)alloc((size_t)NBK * CAP * 4);
  size_t end_storage = off;
  off = union_off;
  float* uF = (float*)alloc((size_t)U_N * 64 * 4);
  float* iF = (float*)alloc((size_t)I_N * 64 * 4);
  __half* f16U = (__half*)alloc((size_t)(U_N + 1) * 64 * 2);  // +1 sentinel row
  __half* f16I = (__half*)alloc((size_t)(I_N + 1) * 64 * 2);
  __half* s16U = (__half*)alloc(((size_t)U_N * 8 + 8) * 2);   // +8 sentinel scores
  __half* s16I = (__half*)alloc(((size_t)I_N * 8 + 8) * 2);
  __half* s2U = (__half*)alloc((size_t)(U_N + 1) * 2);        // layer-2 scores + sentinel
  __half* s2I = (__half*)alloc((size_t)(I_N + 1) * 2);
  if (off < end_storage) off = end_storage;

  // CSR/CSC build (16-aligned rows, bucket-level scan, sentinel pads + tables)
  hipMemsetAsync(bcnt, 0, (size_t)NBK * 4, stream);
  k_build1<<<NBLD, 1024, 0, stream>>>(edge_u, edge_i, bcnt, storage);
  k_count<<<NBK, 256, 0, stream>>>(bcnt, storage, cnt, bsum);
  k_scanb<<<1, 1024, 0, stream>>>(bsum, bbase);
  k_build2<<<NBK, 256, 0, stream>>>(bcnt, storage, cnt, bbase, ptr, col,
                                    f16U, f16I, s16U, s16I, s2U, s2I);

  // Layer 1
  k_mm2<<<NB_U + NB_I, 256, 0, stream>>>(uEmbd, iEmbd, Wu_h, Wi_h, a_h, 1,
                                         uF, iF, f16U, f16I, s16U, s16I);
  k_agg2<<<UI_N * 64 / 256, 256, 0, stream>>>(ptr, col, uF, iF, f16U, f16I,
                                              s16U, s16I, 1);

  // Layer 2 (in place), inline edge weights from s2 tables
  k_mm2<<<NB_U + NB_I, 256, 0, stream>>>(uF, iF, Wu_out, Wi_out, a_out, 2,
                                         uF, iF, f16U, f16I, s2U, s2I);
  k_agg2<<<UI_N * 64 / 256, 256, 0, stream>>>(ptr, col, uF, iF, f16U, f16I,
                                              s2U, s2I, 2);

  // Final per-pair dot
  k_dot<<<B_N / 16, 256, 0, stream>>>(userIdx, itemIdx, uF, iF, out);
}

// Round 10
// 387.904 us; speedup vs baseline: 1.0893x; 1.0111x over previous
//
#include <hip/hip_runtime.h>
#include <hip/hip_fp16.h>

#define U_N 50000
#define I_N 100000
#define E_N 1600000
#define B_N 16384
#define UI_N (U_N + I_N)   // 150000
#define NB_U 782           // ceil(50000/64)
#define NB_I 1563          // ceil(100000/64)
#define NBK 586            // ceil(150000/256) buckets, 256 nodes each
#define CAP 10240          // entries per bucket (mean 8192 max, ~22 sigma margin)
#define NBLD 512           // blocks in k_build1
#define CHUNK (E_N / NBLD) // 3125 edges per block
#define COL_CAP 5600000    // >= 2E + 15*UI_N worst-case aligned CSR slots

// ---------------- CSR build: phase 1 (block-local binning, packed 4B entries) ---------
// entry = (key&255)<<17 | nbr   (nbr < 2^17; key bucket = key>>8)
__global__ __launch_bounds__(1024) void k_build1(
    const int* __restrict__ eu, const int* __restrict__ ei,
    int* __restrict__ bcnt, int* __restrict__ storage) {
  __shared__ int hist[NBK];
  __shared__ int lbase[NBK];
  __shared__ int loff[NBK];
  int t = threadIdx.x;
  for (int b = t; b < NBK; b += 1024) { hist[b] = 0; loff[b] = 0; }
  __syncthreads();
  int e0 = blockIdx.x * CHUNK;
  int e1 = e0 + CHUNK;
  for (int e = e0 + t; e < e1; e += 1024) {
    int u = eu[e];
    int k2 = U_N + ei[e];
    atomicAdd(&hist[u >> 8], 1);
    atomicAdd(&hist[k2 >> 8], 1);
  }
  __syncthreads();
  for (int b = t; b < NBK; b += 1024) {
    int h = hist[b];
    lbase[b] = h ? atomicAdd(&bcnt[b], h) : 0;
  }
  __syncthreads();
  for (int e = e0 + t; e < e1; e += 1024) {
    int u = eu[e], it = ei[e];
    int k2 = U_N + it;
    int b1 = u >> 8;
    int s1 = lbase[b1] + atomicAdd(&loff[b1], 1);
    storage[(size_t)b1 * CAP + s1] = ((u & 255) << 17) | it;
    int b2 = k2 >> 8;
    int s2 = lbase[b2] + atomicAdd(&loff[b2], 1);
    storage[(size_t)b2 * CAP + s2] = ((k2 & 255) << 17) | u;
  }
}

// ---------------- per-node degrees + per-bucket aligned slot totals ----------------
__global__ __launch_bounds__(256) void k_count(const int* __restrict__ bcnt,
                                               const int* __restrict__ storage,
                                               int* __restrict__ cnt,
                                               int* __restrict__ bsum) {
  __shared__ int c[256];
  __shared__ int red[256];
  int b = blockIdx.x;
  int t = threadIdx.x;
  c[t] = 0;
  __syncthreads();
  int n = bcnt[b];
  const int* s = storage + (size_t)b * CAP;
  for (int i = t; i < n; i += 256) atomicAdd(&c[s[i] >> 17], 1);
  __syncthreads();
  int node = b * 256 + t;
  int deg = c[t];
  if (node < UI_N) cnt[node] = deg;
  red[t] = (deg + 15) & ~15;
  __syncthreads();
  for (int off = 128; off > 0; off >>= 1) {
    if (t < off) red[t] += red[t + off];
    __syncthreads();
  }
  if (t == 0) bsum[b] = red[0];
}

// ---------------- single-block exclusive scan over bucket totals ----------------
__global__ __launch_bounds__(1024) void k_scanb(const int* __restrict__ bsum,
                                                int* __restrict__ bbase) {
  __shared__ int sc[1024];
  int t = threadIdx.x;
  int v = (t < NBK) ? bsum[t] : 0;
  sc[t] = v;
  __syncthreads();
  int val = v;
  for (int off = 1; off < 1024; off <<= 1) {
    int x = (t >= off) ? sc[t - off] : 0;
    __syncthreads();
    val += x;
    sc[t] = val;
    __syncthreads();
  }
  if (t < NBK) bbase[t] = val - v;  // exclusive
}

// ---- CSR build: phase 2 (local prefix -> ptr, scatter, sentinel pads + tables) ------
// NOTE: sentinel tables (fA/scores) are NOT aliased with storage in the ws layout,
// so block 0's sentinel writes cannot corrupt unread storage entries.
__global__ __launch_bounds__(256) void k_build2(const int* __restrict__ bcnt,
                                                const int* __restrict__ storage,
                                                const int* __restrict__ cnt,
                                                const int* __restrict__ bbase,
                                                int* __restrict__ ptr,
                                                int* __restrict__ col,
                                                __half* fA_U, __half* fA_I,
                                                __half* s16U, __half* s16I,
                                                __half* s2U, __half* s2I) {
  __shared__ int pb[256];
  __shared__ int cur[256];
  __shared__ int sc[256];
  int b = blockIdx.x;
  int t = threadIdx.x;
  int node = b * 256 + t;
  int deg = (node < UI_N) ? cnt[node] : 0;
  int al = (deg + 15) & ~15;
  sc[t] = al;
  __syncthreads();
  int val = al;
  for (int off = 1; off < 256; off <<= 1) {
    int x = (t >= off) ? sc[t - off] : 0;
    __syncthreads();
    val += x;
    sc[t] = val;
    __syncthreads();
  }
  int base = bbase[b];
  int myPtr = base + (val - al);
  pb[t] = myPtr;
  cur[t] = 0;
  if (node < UI_N) ptr[node] = myPtr;
  if (b == NBK - 1 && t == 255) ptr[UI_N] = base + val;
  __syncthreads();
  int n = bcnt[b];
  const int* s = storage + (size_t)b * CAP;
  for (int i = t; i < n; i += 256) {
    int e = s[i];
    int local = e >> 17;
    int slot = pb[local] + atomicAdd(&cur[local], 1);
    col[slot] = e & 0x1FFFF;
  }
  __syncthreads();
  if (node < UI_N) {
    int myEnd = pb[t] + cur[t];
    int padEnd = pb[t] + al;
    int sent = (node < U_N) ? I_N : U_N;   // sentinel neighbor index
    for (int j = myEnd; j < padEnd; j++) col[j] = sent;
  }
  // sentinel rows/scores (block 0): zero fA rows, +inf scores (fA not storage-aliased)
  if (b == 0) {
    unsigned short inf = 0x7C00;
    if (t < 64) {
      ((unsigned short*)fA_U)[(size_t)U_N * 64 + t] = 0;
      ((unsigned short*)fA_I)[(size_t)I_N * 64 + t] = 0;
    }
    if (t < 8) {
      ((unsigned short*)s16U)[(size_t)U_N * 8 + t] = inf;
      ((unsigned short*)s16I)[(size_t)I_N * 8 + t] = inf;
    }
    if (t == 0) {
      ((unsigned short*)s2U)[U_N] = inf;
      ((unsigned short*)s2I)[I_N] = inf;
    }
  }
}

// ---------------- Fused matmul + attention scores (users + items, one launch) ---------
// layer1: input fp32 embeddings; layer2: input fp16 fB. Output: fp16 fA + scores.
__global__ __launch_bounds__(256) void k_mm2(
    const float* __restrict__ Xu32, const float* __restrict__ Xi32,
    const __half* __restrict__ Xu16, const __half* __restrict__ Xi16,
    const float* __restrict__ Wu, const float* __restrict__ Wi,
    const float* __restrict__ a, int layer,
    __half* __restrict__ fA_U, __half* __restrict__ fA_I,
    __half* __restrict__ s16U, __half* __restrict__ s16I) {
  __shared__ float Wl[4096];
  __shared__ float Xs[4096];
  const bool isU = blockIdx.x < NB_U;
  const int N = isU ? U_N : I_N;
  const int base = (isU ? blockIdx.x : blockIdx.x - NB_U) * 64;
  const float* W = isU ? Wu : Wi;
  __half* f16 = isU ? fA_U : fA_I;
  __half* s16 = isU ? s16U : s16I;
  const int aoff = (layer == 1) ? (isU ? 0 : 8) : (isU ? 0 : 64);
  int t = threadIdx.x;

  if (layer == 1) {
#pragma unroll
    for (int k = 0; k < 4; k++) {
      int i = t + 256 * k;
      int h = i >> 7, d = (i >> 1) & 63, half = i & 1;
      float4 v = *(const float4*)(W + h * 512 + d * 8 + half * 4);
      *(float4*)(Wl + d * 64 + h * 8 + half * 4) = v;
    }
    const float* X = isU ? Xu32 : Xi32;
#pragma unroll
    for (int k = 0; k < 4; k++) {
      int i = t + 256 * k;
      int r = i >> 4, ch = i & 15;
      int node = base + r;
      float4 v = make_float4(0.f, 0.f, 0.f, 0.f);
      if (node < N) v = *(const float4*)(X + (size_t)node * 64 + ch * 4);
      *(float4*)(Xs + r * 64 + ch * 4) = v;
    }
  } else {
#pragma unroll
    for (int k = 0; k < 4; k++) {
      int i = t + 256 * k;
      *(float4*)(Wl + i * 4) = *(const float4*)(W + i * 4);
    }
    const __half* X = isU ? Xu16 : Xi16;
#pragma unroll
    for (int k = 0; k < 4; k++) {
      int i = t + 256 * k;
      int r = i >> 4, ch = i & 15;
      int node = base + r;
      float4 v = make_float4(0.f, 0.f, 0.f, 0.f);
      if (node < N) {
        const __half2* hp = (const __half2*)(X + (size_t)node * 64 + ch * 4);
        float2 f0 = __half22float2(hp[0]);
        float2 f1 = __half22float2(hp[1]);
        v = make_float4(f0.x, f0.y, f1.x, f1.y);
      }
      *(float4*)(Xs + r * 64 + ch * 4) = v;
    }
  }
  __syncthreads();

  const int c0 = t & 31;
  const int rb = t >> 5;
  float acc0[8], acc1[8];
#pragma unroll
  for (int k = 0; k < 8; k++) { acc0[k] = 0.f; acc1[k] = 0.f; }

  for (int d0 = 0; d0 < 64; d0 += 4) {
    float2 wA = *(float2*)(Wl + (d0 + 0) * 64 + 2 * c0);
    float2 wB = *(float2*)(Wl + (d0 + 1) * 64 + 2 * c0);
    float2 wC = *(float2*)(Wl + (d0 + 2) * 64 + 2 * c0);
    float2 wD = *(float2*)(Wl + (d0 + 3) * 64 + 2 * c0);
#pragma unroll
    for (int k = 0; k < 8; k++) {
      float4 x = *(float4*)(Xs + (rb + 8 * k) * 64 + d0);
      acc0[k] += x.x * wA.x + x.y * wB.x + x.z * wC.x + x.w * wD.x;
      acc1[k] += x.x * wA.y + x.y * wB.y + x.z * wC.y + x.w * wD.y;
    }
  }

  float av0, av1;
  if (layer == 1) {
    int h = c0 >> 2, j = 2 * (c0 & 3);
    av0 = a[h * 16 + aoff + j];
    av1 = a[h * 16 + aoff + j + 1];
  } else {
    av0 = a[aoff + 2 * c0];
    av1 = a[aoff + 2 * c0 + 1];
  }
#pragma unroll
  for (int k = 0; k < 8; k++) {
    int node = base + rb + 8 * k;
    float s = acc0[k] * av0 + acc1[k] * av1;
    s += __shfl_xor(s, 1);
    s += __shfl_xor(s, 2);
    if (layer != 1) {
      s += __shfl_xor(s, 4);
      s += __shfl_xor(s, 8);
      s += __shfl_xor(s, 16);
    }
    if (node < N) {
      float2 f;
      f.x = acc0[k];
      f.y = acc1[k];
      *(__half2*)(f16 + (size_t)node * 64 + 2 * c0) = __float22half2_rn(f);
      if (layer == 1) {
        if ((c0 & 3) == 0) s16[node * 8 + (c0 >> 2)] = __float2half_rn(s);
      } else {
        if (c0 == 0) s16[node] = __float2half_rn(s);
      }
    }
  }
}

// ---------------- Fused aggregation: gather fA -> write fB (fp16), maskless ----------
// One wave per node; 8 edges/group x 2 groups in flight; inline exp; fused ELU.
__global__ __launch_bounds__(256) void k_agg2(
    const int* __restrict__ ptr, const int* __restrict__ col,
    const __half* __restrict__ fA_U, const __half* __restrict__ fA_I,
    __half* __restrict__ fB_U, __half* __restrict__ fB_I,
    const __half* __restrict__ s16U, const __half* __restrict__ s16I,
    int layer) {
  int gid = blockIdx.x * blockDim.x + threadIdx.x;
  int n = gid >> 6;
  if (n >= UI_N) return;
  int l = threadIdx.x & 63;
  int g = l >> 3;       // edge group 0..7
  int cc = l & 7;       // feature chunk / head
  bool isU = n < U_N;
  int nl = isU ? n : n - U_N;
  const __half* nbrF = isU ? fA_I : fA_U;
  const __half* nbrS = isU ? s16I : s16U;
  const __half* selfS = isU ? s16U : s16I;
  const __half* selfF = isU ? fA_U : fA_I;
  __half* outp = isU ? fB_U : fB_I;

  int beg = ptr[n], endA = ptr[n + 1];
  float acc[8];
#pragma unroll
  for (int k = 0; k < 8; k++) acc[k] = 0.f;
  float wsum = 0.f;

  if (layer == 1) {
    float sself = __half2float(selfS[(size_t)nl * 8 + cc]);
    for (int p = beg; p < endA; p += 16) {
      int iA = p + g, iB = p + 8 + g;
      int nbA = col[iA];
      int nbB = col[iB];
      float xA = sself + __half2float(nbrS[(size_t)nbA * 8 + cc]);
      float xB = sself + __half2float(nbrS[(size_t)nbB * 8 + cc]);
      float4 rA = *(const float4*)(nbrF + (size_t)nbA * 64 + cc * 8);
      float4 rB = *(const float4*)(nbrF + (size_t)nbB * 64 + cc * 8);
      float wA = __expf(-fmaxf(xA, 0.2f * xA));  // sentinel -> 0
      float wB = __expf(-fmaxf(xB, 0.2f * xB));
      wsum += wA + wB;
      const __half* hA = (const __half*)&rA;
      const __half* hB = (const __half*)&rB;
#pragma unroll
      for (int k = 0; k < 8; k++) acc[k] += wA * (float)hA[k];
#pragma unroll
      for (int k = 0; k < 8; k++) acc[k] += wB * (float)hB[k];
    }
  } else {
    float sself = __half2float(selfS[nl]);
    for (int p = beg; p < endA; p += 16) {
      int iA = p + g, iB = p + 8 + g;
      int nbA = col[iA];
      int nbB = col[iB];
      float xA = sself + __half2float(nbrS[nbA]);
      float xB = sself + __half2float(nbrS[nbB]);
      float4 rA = *(const float4*)(nbrF + (size_t)nbA * 64 + cc * 8);
      float4 rB = *(const float4*)(nbrF + (size_t)nbB * 64 + cc * 8);
      float wA = __expf(-fmaxf(xA, 0.2f * xA));
      float wB = __expf(-fmaxf(xB, 0.2f * xB));
      wsum += wA + wB;
      const __half* hA = (const __half*)&rA;
      const __half* hB = (const __half*)&rB;
#pragma unroll
      for (int k = 0; k < 8; k++) acc[k] += wA * (float)hA[k];
#pragma unroll
      for (int k = 0; k < 8; k++) acc[k] += wB * (float)hB[k];
    }
  }

#pragma unroll
  for (int k = 0; k < 8; k++) {
    acc[k] += __shfl_xor(acc[k], 8);
    acc[k] += __shfl_xor(acc[k], 16);
    acc[k] += __shfl_xor(acc[k], 32);
  }
  wsum += __shfl_xor(wsum, 8);
  wsum += __shfl_xor(wsum, 16);
  wsum += __shfl_xor(wsum, 32);

  if (l < 8) {
    float4 raw = *(const float4*)(selfF + (size_t)nl * 64 + cc * 8);
    const __half2* sp = (const __half2*)&raw;
    float2 s0 = __half22float2(sp[0]);
    float2 s1 = __half22float2(sp[1]);
    float2 s2 = __half22float2(sp[2]);
    float2 s3 = __half22float2(sp[3]);
    float v[8] = {s0.x, s0.y, s1.x, s1.y, s2.x, s2.y, s3.x, s3.y};
    if (endA > beg) {
      float inv = 1.f / wsum;
#pragma unroll
      for (int k = 0; k < 8; k++) v[k] += acc[k] * inv;
    }
#pragma unroll
    for (int k = 0; k < 8; k++) v[k] = (v[k] > 0.f) ? v[k] : (__expf(v[k]) - 1.f);
    __half2 o[4];
    o[0] = __floats2half2_rn(v[0], v[1]);
    o[1] = __floats2half2_rn(v[2], v[3]);
    o[2] = __floats2half2_rn(v[4], v[5]);
    o[3] = __floats2half2_rn(v[6], v[7]);
    *(float4*)(outp + (size_t)nl * 64 + cc * 8) = *(float4*)o;
  }
}

// ---------------- Final pair dot (fp16 inputs; 32 pairs/block, 8 lanes each) ----------
__global__ void k_dot(const int* __restrict__ uIdx, const int* __restrict__ iIdx,
                      const __half* __restrict__ u_f, const __half* __restrict__ i_f,
                      float* __restrict__ out) {
  int t = threadIdx.x;
  int pair = blockIdx.x * 32 + (t >> 3);
  int cc = t & 7;
  float4 ra = *(const float4*)(u_f + (size_t)uIdx[pair] * 64 + cc * 8);
  float4 rb = *(const float4*)(i_f + (size_t)iIdx[pair] * 64 + cc * 8);
  const __half* ha = (const __half*)&ra;
  const __half* hb = (const __half*)&rb;
  float v = 0.f;
#pragma unroll
  for (int k = 0; k < 8; k++) v += (float)ha[k] * (float)hb[k];
  v += __shfl_xor(v, 1);
  v += __shfl_xor(v, 2);
  v += __shfl_xor(v, 4);
  if (cc == 0) out[pair] = v;
}

extern "C" void kernel_launch(void* const* d_in, const int* in_sizes, int n_in,
                              void* d_out, int out_size, void* d_ws, size_t ws_size,
                              hipStream_t stream) {
  const int* userIdx = (const int*)d_in[0];
  const int* itemIdx = (const int*)d_in[1];
  const int* edge_u = (const int*)d_in[2];
  const int* edge_i = (const int*)d_in[3];
  const float* uEmbd = (const float*)d_in[4];
  const float* iEmbd = (const float*)d_in[5];
  const float* Wu_h = (const float*)d_in[6];
  const float* Wi_h = (const float*)d_in[7];
  const float* a_h = (const float*)d_in[8];
  const float* Wu_out = (const float*)d_in[9];
  const float* Wi_out = (const float*)d_in[10];
  const float* a_out = (const float*)d_in[11];
  float* out = (float*)d_out;

  char* w = (char*)d_ws;
  size_t off = 0;
  auto alloc = [&](size_t bytes) -> void* {
    void* p = w + off;
    off += (bytes + 511) & ~(size_t)511;
    return p;
  };
  int* bcnt = (int*)alloc((size_t)NBK * 4);
  int* cnt = (int*)alloc((size_t)UI_N * 4);
  int* ptr = (int*)alloc((size_t)(UI_N + 1) * 4);
  int* bsum = (int*)alloc(4096);
  int* bbase = (int*)alloc(4096);
  int* col = (int*)alloc((size_t)COL_CAP * 4);
  // fA (pre-agg gather tables, +1 sentinel row) and scores: NOT aliased with storage
  __half* fA_U = (__half*)alloc((size_t)(U_N + 1) * 64 * 2);
  __half* fA_I = (__half*)alloc((size_t)(I_N + 1) * 64 * 2);
  __half* s16U = (__half*)alloc(((size_t)U_N * 8 + 8) * 2);
  __half* s16I = (__half*)alloc(((size_t)I_N * 8 + 8) * 2);
  __half* s2U = (__half*)alloc((size_t)(U_N + 1) * 2);
  __half* s2I = (__half*)alloc((size_t)(I_N + 1) * 2);
  // union tail: storage (24 MB, dead after k_build2) aliases fB (first write: agg L1)
  size_t union_off = off;
  int* storage = (int*)alloc((size_t)NBK * CAP * 4);
  size_t end_storage = off;
  off = union_off;
  __half* fB_U = (__half*)alloc((size_t)U_N * 64 * 2);
  __half* fB_I = (__half*)alloc((size_t)I_N * 64 * 2);
  if (off < end_storage) off = end_storage;

  // CSR/CSC build (16-aligned rows, bucket-level scan, sentinel pads + tables)
  hipMemsetAsync(bcnt, 0, (size_t)NBK * 4, stream);
  k_build1<<<NBLD, 1024, 0, stream>>>(edge_u, edge_i, bcnt, storage);
  k_count<<<NBK, 256, 0, stream>>>(bcnt, storage, cnt, bsum);
  k_scanb<<<1, 1024, 0, stream>>>(bsum, bbase);
  k_build2<<<NBK, 256, 0, stream>>>(bcnt, storage, cnt, bbase, ptr, col,
                                    fA_U, fA_I, s16U, s16I, s2U, s2I);

  // Layer 1: mm (fp32 in -> fA fp16 + scores); agg (gather fA -> fB)
  k_mm2<<<NB_U + NB_I, 256, 0, stream>>>(uEmbd, iEmbd, (const __half*)nullptr,
                                         (const __half*)nullptr, Wu_h, Wi_h, a_h, 1,
                                         fA_U, fA_I, s16U, s16I);
  k_agg2<<<UI_N * 64 / 256, 256, 0, stream>>>(ptr, col, fA_U, fA_I, fB_U, fB_I,
                                              s16U, s16I, 1);

  // Layer 2: mm (fB fp16 in -> fA fp16 + s2); agg (gather fA -> fB)
  k_mm2<<<NB_U + NB_I, 256, 0, stream>>>((const float*)nullptr, (const float*)nullptr,
                                         fB_U, fB_I, Wu_out, Wi_out, a_out, 2,
                                         fA_U, fA_I, s2U, s2I);
  k_agg2<<<UI_N * 64 / 256, 256, 0, stream>>>(ptr, col, fA_U, fA_I, fB_U, fB_I,
                                              s2U, s2I, 2);

  // Final per-pair dot (fp16 features)
  k_dot<<<B_N / 32, 256, 0, stream>>>(userIdx, itemIdx, fB_U, fB_I, out);
}

// Round 11
// 386.052 us; speedup vs baseline: 1.0945x; 1.0048x over previous
//
#include <hip/hip_runtime.h>
#include <hip/hip_fp16.h>

#define U_N 50000
#define I_N 100000
#define E_N 1600000
#define B_N 16384
#define UI_N (U_N + I_N)   // 150000
#define NB_U 782           // ceil(50000/64)
#define NB_I 1563          // ceil(100000/64)
#define NBK 586            // ceil(150000/256) buckets, 256 nodes each
#define CAP 10240          // entries per bucket (mean 8192 max, ~22 sigma margin)
#define NBLD 512           // blocks in k_build1
#define CHUNK (E_N / NBLD) // 3125 edges per block
#define COL_CAP 5600000    // >= 2E + 15*UI_N worst-case aligned CSR slots

// ---------------- CSR build: phase 1 (block-local binning, packed 4B entries) ---------
// entry = (key&255)<<17 | nbr   (nbr < 2^17; key bucket = key>>8)
__global__ __launch_bounds__(1024) void k_build1(
    const int* __restrict__ eu, const int* __restrict__ ei,
    int* __restrict__ bcnt, int* __restrict__ storage) {
  __shared__ int hist[NBK];
  __shared__ int lbase[NBK];
  __shared__ int loff[NBK];
  int t = threadIdx.x;
  for (int b = t; b < NBK; b += 1024) { hist[b] = 0; loff[b] = 0; }
  __syncthreads();
  int e0 = blockIdx.x * CHUNK;
  int e1 = e0 + CHUNK;
  for (int e = e0 + t; e < e1; e += 1024) {
    int u = eu[e];
    int k2 = U_N + ei[e];
    atomicAdd(&hist[u >> 8], 1);
    atomicAdd(&hist[k2 >> 8], 1);
  }
  __syncthreads();
  for (int b = t; b < NBK; b += 1024) {
    int h = hist[b];
    lbase[b] = h ? atomicAdd(&bcnt[b], h) : 0;
  }
  __syncthreads();
  for (int e = e0 + t; e < e1; e += 1024) {
    int u = eu[e], it = ei[e];
    int k2 = U_N + it;
    int b1 = u >> 8;
    int s1 = lbase[b1] + atomicAdd(&loff[b1], 1);
    storage[(size_t)b1 * CAP + s1] = ((u & 255) << 17) | it;
    int b2 = k2 >> 8;
    int s2 = lbase[b2] + atomicAdd(&loff[b2], 1);
    storage[(size_t)b2 * CAP + s2] = ((k2 & 255) << 17) | u;
  }
}

// ---------------- per-node degrees + per-bucket aligned slot totals ----------------
__global__ __launch_bounds__(256) void k_count(const int* __restrict__ bcnt,
                                               const int* __restrict__ storage,
                                               int* __restrict__ cnt,
                                               int* __restrict__ bsum) {
  __shared__ int c[256];
  __shared__ int red[256];
  int b = blockIdx.x;
  int t = threadIdx.x;
  c[t] = 0;
  __syncthreads();
  int n = bcnt[b];
  const int* s = storage + (size_t)b * CAP;
  for (int i = t; i < n; i += 256) atomicAdd(&c[s[i] >> 17], 1);
  __syncthreads();
  int node = b * 256 + t;
  int deg = c[t];
  if (node < UI_N) cnt[node] = deg;
  red[t] = (deg + 15) & ~15;
  __syncthreads();
  for (int off = 128; off > 0; off >>= 1) {
    if (t < off) red[t] += red[t + off];
    __syncthreads();
  }
  if (t == 0) bsum[b] = red[0];
}

// ---------------- single-block exclusive scan over bucket totals ----------------
__global__ __launch_bounds__(1024) void k_scanb(const int* __restrict__ bsum,
                                                int* __restrict__ bbase) {
  __shared__ int sc[1024];
  int t = threadIdx.x;
  int v = (t < NBK) ? bsum[t] : 0;
  sc[t] = v;
  __syncthreads();
  int val = v;
  for (int off = 1; off < 1024; off <<= 1) {
    int x = (t >= off) ? sc[t - off] : 0;
    __syncthreads();
    val += x;
    sc[t] = val;
    __syncthreads();
  }
  if (t < NBK) bbase[t] = val - v;  // exclusive
}

// ---- CSR build: phase 2 (local prefix -> ptr, scatter, sentinel pads + tables) ------
__global__ __launch_bounds__(256) void k_build2(const int* __restrict__ bcnt,
                                                const int* __restrict__ storage,
                                                const int* __restrict__ cnt,
                                                const int* __restrict__ bbase,
                                                int* __restrict__ ptr,
                                                int* __restrict__ col,
                                                __half* fA_U, __half* fA_I,
                                                __half* s16U, __half* s16I,
                                                __half* s2U, __half* s2I) {
  __shared__ int pb[256];
  __shared__ int cur[256];
  __shared__ int sc[256];
  int b = blockIdx.x;
  int t = threadIdx.x;
  int node = b * 256 + t;
  int deg = (node < UI_N) ? cnt[node] : 0;
  int al = (deg + 15) & ~15;
  sc[t] = al;
  __syncthreads();
  int val = al;
  for (int off = 1; off < 256; off <<= 1) {
    int x = (t >= off) ? sc[t - off] : 0;
    __syncthreads();
    val += x;
    sc[t] = val;
    __syncthreads();
  }
  int base = bbase[b];
  int myPtr = base + (val - al);
  pb[t] = myPtr;
  cur[t] = 0;
  if (node < UI_N) ptr[node] = myPtr;
  if (b == NBK - 1 && t == 255) ptr[UI_N] = base + val;
  __syncthreads();
  int n = bcnt[b];
  const int* s = storage + (size_t)b * CAP;
  for (int i = t; i < n; i += 256) {
    int e = s[i];
    int local = e >> 17;
    int slot = pb[local] + atomicAdd(&cur[local], 1);
    col[slot] = e & 0x1FFFF;
  }
  __syncthreads();
  if (node < UI_N) {
    int myEnd = pb[t] + cur[t];
    int padEnd = pb[t] + al;
    int sent = (node < U_N) ? I_N : U_N;   // sentinel neighbor index
    for (int j = myEnd; j < padEnd; j++) col[j] = sent;
  }
  // sentinel rows/scores (block 0): zero fA rows, +inf scores (fA not storage-aliased)
  if (b == 0) {
    unsigned short inf = 0x7C00;
    if (t < 64) {
      ((unsigned short*)fA_U)[(size_t)U_N * 64 + t] = 0;
      ((unsigned short*)fA_I)[(size_t)I_N * 64 + t] = 0;
    }
    if (t < 8) {
      ((unsigned short*)s16U)[(size_t)U_N * 8 + t] = inf;
      ((unsigned short*)s16I)[(size_t)I_N * 8 + t] = inf;
    }
    if (t == 0) {
      ((unsigned short*)s2U)[U_N] = inf;
      ((unsigned short*)s2I)[I_N] = inf;
    }
  }
}

// ---------------- Fused matmul + attention scores (users + items, one launch) ---------
__global__ __launch_bounds__(256) void k_mm2(
    const float* __restrict__ Xu32, const float* __restrict__ Xi32,
    const __half* __restrict__ Xu16, const __half* __restrict__ Xi16,
    const float* __restrict__ Wu, const float* __restrict__ Wi,
    const float* __restrict__ a, int layer,
    __half* __restrict__ fA_U, __half* __restrict__ fA_I,
    __half* __restrict__ s16U, __half* __restrict__ s16I) {
  __shared__ float Wl[4096];
  __shared__ float Xs[4096];
  const bool isU = blockIdx.x < NB_U;
  const int N = isU ? U_N : I_N;
  const int base = (isU ? blockIdx.x : blockIdx.x - NB_U) * 64;
  const float* W = isU ? Wu : Wi;
  __half* f16 = isU ? fA_U : fA_I;
  __half* s16 = isU ? s16U : s16I;
  const int aoff = (layer == 1) ? (isU ? 0 : 8) : (isU ? 0 : 64);
  int t = threadIdx.x;

  if (layer == 1) {
#pragma unroll
    for (int k = 0; k < 4; k++) {
      int i = t + 256 * k;
      int h = i >> 7, d = (i >> 1) & 63, half = i & 1;
      float4 v = *(const float4*)(W + h * 512 + d * 8 + half * 4);
      *(float4*)(Wl + d * 64 + h * 8 + half * 4) = v;
    }
    const float* X = isU ? Xu32 : Xi32;
#pragma unroll
    for (int k = 0; k < 4; k++) {
      int i = t + 256 * k;
      int r = i >> 4, ch = i & 15;
      int node = base + r;
      float4 v = make_float4(0.f, 0.f, 0.f, 0.f);
      if (node < N) v = *(const float4*)(X + (size_t)node * 64 + ch * 4);
      *(float4*)(Xs + r * 64 + ch * 4) = v;
    }
  } else {
#pragma unroll
    for (int k = 0; k < 4; k++) {
      int i = t + 256 * k;
      *(float4*)(Wl + i * 4) = *(const float4*)(W + i * 4);
    }
    const __half* X = isU ? Xu16 : Xi16;
#pragma unroll
    for (int k = 0; k < 4; k++) {
      int i = t + 256 * k;
      int r = i >> 4, ch = i & 15;
      int node = base + r;
      float4 v = make_float4(0.f, 0.f, 0.f, 0.f);
      if (node < N) {
        const __half2* hp = (const __half2*)(X + (size_t)node * 64 + ch * 4);
        float2 f0 = __half22float2(hp[0]);
        float2 f1 = __half22float2(hp[1]);
        v = make_float4(f0.x, f0.y, f1.x, f1.y);
      }
      *(float4*)(Xs + r * 64 + ch * 4) = v;
    }
  }
  __syncthreads();

  const int c0 = t & 31;
  const int rb = t >> 5;
  float acc0[8], acc1[8];
#pragma unroll
  for (int k = 0; k < 8; k++) { acc0[k] = 0.f; acc1[k] = 0.f; }

  for (int d0 = 0; d0 < 64; d0 += 4) {
    float2 wA = *(float2*)(Wl + (d0 + 0) * 64 + 2 * c0);
    float2 wB = *(float2*)(Wl + (d0 + 1) * 64 + 2 * c0);
    float2 wC = *(float2*)(Wl + (d0 + 2) * 64 + 2 * c0);
    float2 wD = *(float2*)(Wl + (d0 + 3) * 64 + 2 * c0);
#pragma unroll
    for (int k = 0; k < 8; k++) {
      float4 x = *(float4*)(Xs + (rb + 8 * k) * 64 + d0);
      acc0[k] += x.x * wA.x + x.y * wB.x + x.z * wC.x + x.w * wD.x;
      acc1[k] += x.x * wA.y + x.y * wB.y + x.z * wC.y + x.w * wD.y;
    }
  }

  float av0, av1;
  if (layer == 1) {
    int h = c0 >> 2, j = 2 * (c0 & 3);
    av0 = a[h * 16 + aoff + j];
    av1 = a[h * 16 + aoff + j + 1];
  } else {
    av0 = a[aoff + 2 * c0];
    av1 = a[aoff + 2 * c0 + 1];
  }
#pragma unroll
  for (int k = 0; k < 8; k++) {
    int node = base + rb + 8 * k;
    float s = acc0[k] * av0 + acc1[k] * av1;
    s += __shfl_xor(s, 1);
    s += __shfl_xor(s, 2);
    if (layer != 1) {
      s += __shfl_xor(s, 4);
      s += __shfl_xor(s, 8);
      s += __shfl_xor(s, 16);
    }
    if (node < N) {
      float2 f;
      f.x = acc0[k];
      f.y = acc1[k];
      *(__half2*)(f16 + (size_t)node * 64 + 2 * c0) = __float22half2_rn(f);
      if (layer == 1) {
        if ((c0 & 3) == 0) s16[node * 8 + (c0 >> 2)] = __float2half_rn(s);
      } else {
        if (c0 == 0) s16[node] = __float2half_rn(s);
      }
    }
  }
}

// ---------------- Fused aggregation: gather fA -> write fB (fp16), maskless ----------
// One wave per node; 8 edges/group x 2 in flight; 32-bit byte-offset addressing;
// scalar trip count (loop control on SGPRs).
__global__ __launch_bounds__(256) void k_agg2(
    const int* __restrict__ ptr, const int* __restrict__ col,
    const __half* __restrict__ fA_U, const __half* __restrict__ fA_I,
    __half* __restrict__ fB_U, __half* __restrict__ fB_I,
    const __half* __restrict__ s16U, const __half* __restrict__ s16I,
    int layer) {
  int gid = blockIdx.x * blockDim.x + threadIdx.x;
  int n = gid >> 6;
  if (n >= UI_N) return;
  int l = threadIdx.x & 63;
  int g = l >> 3;       // edge group 0..7
  int cc = l & 7;       // feature chunk / head
  bool isU = n < U_N;
  int nl = isU ? n : n - U_N;
  const char* nbrF = (const char*)(isU ? fA_I : fA_U);
  const char* nbrS = (const char*)(isU ? s16I : s16U);
  const __half* selfS = isU ? s16U : s16I;
  const __half* selfF = isU ? fA_U : fA_I;
  __half* outp = isU ? fB_U : fB_I;
  const char* colc = (const char*)col;

  int beg = ptr[n], endA = ptr[n + 1];
  int iters = (endA - beg) >> 4;         // rows are 16-aligned: exact
  unsigned coff = ((unsigned)(beg + g)) << 2;
  const unsigned fsh = (unsigned)cc << 4;  // feature chunk byte offset in 128B row
  float acc[8];
#pragma unroll
  for (int k = 0; k < 8; k++) acc[k] = 0.f;
  float wsum = 0.f;

  if (layer == 1) {
    const unsigned ssh = (unsigned)cc << 1;  // head byte offset in 16B score row
    float sself = __half2float(selfS[(size_t)nl * 8 + cc]);
    for (; iters > 0; iters--) {
      int nbA = *(const int*)(colc + coff);
      int nbB = *(const int*)(colc + coff + 32);
      coff += 64;
      float xA = sself + __half2float(*(const __half*)(nbrS + (((unsigned)nbA << 4) + ssh)));
      float xB = sself + __half2float(*(const __half*)(nbrS + (((unsigned)nbB << 4) + ssh)));
      float4 rA = *(const float4*)(nbrF + (((unsigned)nbA << 7) + fsh));
      float4 rB = *(const float4*)(nbrF + (((unsigned)nbB << 7) + fsh));
      float wA = __expf(-fmaxf(xA, 0.2f * xA));  // sentinel -> 0
      float wB = __expf(-fmaxf(xB, 0.2f * xB));
      wsum += wA + wB;
      const __half* hA = (const __half*)&rA;
      const __half* hB = (const __half*)&rB;
#pragma unroll
      for (int k = 0; k < 8; k++) acc[k] += wA * (float)hA[k];
#pragma unroll
      for (int k = 0; k < 8; k++) acc[k] += wB * (float)hB[k];
    }
  } else {
    float sself = __half2float(selfS[nl]);
    for (; iters > 0; iters--) {
      int nbA = *(const int*)(colc + coff);
      int nbB = *(const int*)(colc + coff + 32);
      coff += 64;
      float xA = sself + __half2float(*(const __half*)(nbrS + ((unsigned)nbA << 1)));
      float xB = sself + __half2float(*(const __half*)(nbrS + ((unsigned)nbB << 1)));
      float4 rA = *(const float4*)(nbrF + (((unsigned)nbA << 7) + fsh));
      float4 rB = *(const float4*)(nbrF + (((unsigned)nbB << 7) + fsh));
      float wA = __expf(-fmaxf(xA, 0.2f * xA));
      float wB = __expf(-fmaxf(xB, 0.2f * xB));
      wsum += wA + wB;
      const __half* hA = (const __half*)&rA;
      const __half* hB = (const __half*)&rB;
#pragma unroll
      for (int k = 0; k < 8; k++) acc[k] += wA * (float)hA[k];
#pragma unroll
      for (int k = 0; k < 8; k++) acc[k] += wB * (float)hB[k];
    }
  }

#pragma unroll
  for (int k = 0; k < 8; k++) {
    acc[k] += __shfl_xor(acc[k], 8);
    acc[k] += __shfl_xor(acc[k], 16);
    acc[k] += __shfl_xor(acc[k], 32);
  }
  wsum += __shfl_xor(wsum, 8);
  wsum += __shfl_xor(wsum, 16);
  wsum += __shfl_xor(wsum, 32);

  if (l < 8) {
    float4 raw = *(const float4*)(selfF + (size_t)nl * 64 + cc * 8);
    const __half2* sp = (const __half2*)&raw;
    float2 s0 = __half22float2(sp[0]);
    float2 s1 = __half22float2(sp[1]);
    float2 s2 = __half22float2(sp[2]);
    float2 s3 = __half22float2(sp[3]);
    float v[8] = {s0.x, s0.y, s1.x, s1.y, s2.x, s2.y, s3.x, s3.y};
    if (endA > beg) {
      float inv = 1.f / wsum;
#pragma unroll
      for (int k = 0; k < 8; k++) v[k] += acc[k] * inv;
    }
#pragma unroll
    for (int k = 0; k < 8; k++) v[k] = (v[k] > 0.f) ? v[k] : (__expf(v[k]) - 1.f);
    __half2 o[4];
    o[0] = __floats2half2_rn(v[0], v[1]);
    o[1] = __floats2half2_rn(v[2], v[3]);
    o[2] = __floats2half2_rn(v[4], v[5]);
    o[3] = __floats2half2_rn(v[6], v[7]);
    *(float4*)(outp + (size_t)nl * 64 + cc * 8) = *(float4*)o;
  }
}

// ---------------- Final pair dot (fp16 inputs; 32 pairs/block, 8 lanes each) ----------
__global__ void k_dot(const int* __restrict__ uIdx, const int* __restrict__ iIdx,
                      const __half* __restrict__ u_f, const __half* __restrict__ i_f,
                      float* __restrict__ out) {
  int t = threadIdx.x;
  int pair = blockIdx.x * 32 + (t >> 3);
  int cc = t & 7;
  float4 ra = *(const float4*)(u_f + (size_t)uIdx[pair] * 64 + cc * 8);
  float4 rb = *(const float4*)(i_f + (size_t)iIdx[pair] * 64 + cc * 8);
  const __half* ha = (const __half*)&ra;
  const __half* hb = (const __half*)&rb;
  float v = 0.f;
#pragma unroll
  for (int k = 0; k < 8; k++) v += (float)ha[k] * (float)hb[k];
  v += __shfl_xor(v, 1);
  v += __shfl_xor(v, 2);
  v += __shfl_xor(v, 4);
  if (cc == 0) out[pair] = v;
}

extern "C" void kernel_launch(void* const* d_in, const int* in_sizes, int n_in,
                              void* d_out, int out_size, void* d_ws, size_t ws_size,
                              hipStream_t stream) {
  const int* userIdx = (const int*)d_in[0];
  const int* itemIdx = (const int*)d_in[1];
  const int* edge_u = (const int*)d_in[2];
  const int* edge_i = (const int*)d_in[3];
  const float* uEmbd = (const float*)d_in[4];
  const float* iEmbd = (const float*)d_in[5];
  const float* Wu_h = (const float*)d_in[6];
  const float* Wi_h = (const float*)d_in[7];
  const float* a_h = (const float*)d_in[8];
  const float* Wu_out = (const float*)d_in[9];
  const float* Wi_out = (const float*)d_in[10];
  const float* a_out = (const float*)d_in[11];
  float* out = (float*)d_out;

  char* w = (char*)d_ws;
  size_t off = 0;
  auto alloc = [&](size_t bytes) -> void* {
    void* p = w + off;
    off += (bytes + 511) & ~(size_t)511;
    return p;
  };
  int* bcnt = (int*)alloc((size_t)NBK * 4);
  int* cnt = (int*)alloc((size_t)UI_N * 4);
  int* ptr = (int*)alloc((size_t)(UI_N + 1) * 4);
  int* bsum = (int*)alloc(4096);
  int* bbase = (int*)alloc(4096);
  int* col = (int*)alloc((size_t)COL_CAP * 4);
  // fA (pre-agg gather tables, +1 sentinel row) and scores: NOT aliased with storage
  __half* fA_U = (__half*)alloc((size_t)(U_N + 1) * 64 * 2);
  __half* fA_I = (__half*)alloc((size_t)(I_N + 1) * 64 * 2);
  __half* s16U = (__half*)alloc(((size_t)U_N * 8 + 8) * 2);
  __half* s16I = (__half*)alloc(((size_t)I_N * 8 + 8) * 2);
  __half* s2U = (__half*)alloc((size_t)(U_N + 1) * 2);
  __half* s2I = (__half*)alloc((size_t)(I_N + 1) * 2);
  // union tail: storage (24 MB, dead after k_build2) aliases fB (first write: agg L1)
  size_t union_off = off;
  int* storage = (int*)alloc((size_t)NBK * CAP * 4);
  size_t end_storage = off;
  off = union_off;
  __half* fB_U = (__half*)alloc((size_t)U_N * 64 * 2);
  __half* fB_I = (__half*)alloc((size_t)I_N * 64 * 2);
  if (off < end_storage) off = end_storage;

  // CSR/CSC build (16-aligned rows, bucket-level scan, sentinel pads + tables)
  hipMemsetAsync(bcnt, 0, (size_t)NBK * 4, stream);
  k_build1<<<NBLD, 1024, 0, stream>>>(edge_u, edge_i, bcnt, storage);
  k_count<<<NBK, 256, 0, stream>>>(bcnt, storage, cnt, bsum);
  k_scanb<<<1, 1024, 0, stream>>>(bsum, bbase);
  k_build2<<<NBK, 256, 0, stream>>>(bcnt, storage, cnt, bbase, ptr, col,
                                    fA_U, fA_I, s16U, s16I, s2U, s2I);

  // Layer 1: mm (fp32 in -> fA fp16 + scores); agg (gather fA -> fB)
  k_mm2<<<NB_U + NB_I, 256, 0, stream>>>(uEmbd, iEmbd, (const __half*)nullptr,
                                         (const __half*)nullptr, Wu_h, Wi_h, a_h, 1,
                                         fA_U, fA_I, s16U, s16I);
  k_agg2<<<UI_N * 64 / 256, 256, 0, stream>>>(ptr, col, fA_U, fA_I, fB_U, fB_I,
                                              s16U, s16I, 1);

  // Layer 2: mm (fB fp16 in -> fA fp16 + s2); agg (gather fA -> fB)
  k_mm2<<<NB_U + NB_I, 256, 0, stream>>>((const float*)nullptr, (const float*)nullptr,
                                         fB_U, fB_I, Wu_out, Wi_out, a_out, 2,
                                         fA_U, fA_I, s2U, s2I);
  k_agg2<<<UI_N * 64 / 256, 256, 0, stream>>>(ptr, col, fA_U, fA_I, fB_U, fB_I,
                                              s2U, s2I, 2);

  // Final per-pair dot (fp16 features)
  k_dot<<<B_N / 32, 256, 0, stream>>>(userIdx, itemIdx, fB_U, fB_I, out);
}

// Round 12
// 385.646 us; speedup vs baseline: 1.0956x; 1.0011x over previous
//
#include <hip/hip_runtime.h>
#include <hip/hip_fp16.h>

#define U_N 50000
#define I_N 100000
#define E_N 1600000
#define B_N 16384
#define UI_N (U_N + I_N)   // 150000
#define NB_U 782           // ceil(50000/64)
#define NB_I 1563          // ceil(100000/64)
#define NBK 586            // ceil(150000/256) buckets, 256 nodes each
#define CAP 10240          // entries per bucket (mean 8192 max, ~22 sigma margin)
#define NBLD 512           // blocks in k_build1
#define CHUNK (E_N / NBLD) // 3125 edges per block
#define COL_CAP 3300000    // >= 2E exact CSR slots

// ---------------- CSR build: phase 1 (block-local binning, packed 4B entries) ---------
// entry = (key&255)<<17 | nbr   (nbr < 2^17; key bucket = key>>8)
__global__ __launch_bounds__(1024) void k_build1(
    const int* __restrict__ eu, const int* __restrict__ ei,
    int* __restrict__ bcnt, int* __restrict__ storage) {
  __shared__ int hist[NBK];
  __shared__ int lbase[NBK];
  __shared__ int loff[NBK];
  int t = threadIdx.x;
  for (int b = t; b < NBK; b += 1024) { hist[b] = 0; loff[b] = 0; }
  __syncthreads();
  int e0 = blockIdx.x * CHUNK;
  int e1 = e0 + CHUNK;
  for (int e = e0 + t; e < e1; e += 1024) {
    int u = eu[e];
    int k2 = U_N + ei[e];
    atomicAdd(&hist[u >> 8], 1);
    atomicAdd(&hist[k2 >> 8], 1);
  }
  __syncthreads();
  for (int b = t; b < NBK; b += 1024) {
    int h = hist[b];
    lbase[b] = h ? atomicAdd(&bcnt[b], h) : 0;
  }
  __syncthreads();
  for (int e = e0 + t; e < e1; e += 1024) {
    int u = eu[e], it = ei[e];
    int k2 = U_N + it;
    int b1 = u >> 8;
    int s1 = lbase[b1] + atomicAdd(&loff[b1], 1);
    storage[(size_t)b1 * CAP + s1] = ((u & 255) << 17) | it;
    int b2 = k2 >> 8;
    int s2 = lbase[b2] + atomicAdd(&loff[b2], 1);
    storage[(size_t)b2 * CAP + s2] = ((k2 & 255) << 17) | u;
  }
}

// ---------------- per-node degrees + per-bucket totals ----------------
__global__ __launch_bounds__(256) void k_count(const int* __restrict__ bcnt,
                                               const int* __restrict__ storage,
                                               int* __restrict__ cnt,
                                               int* __restrict__ bsum) {
  __shared__ int c[256];
  __shared__ int red[256];
  int b = blockIdx.x;
  int t = threadIdx.x;
  c[t] = 0;
  __syncthreads();
  int n = bcnt[b];
  const int* s = storage + (size_t)b * CAP;
  for (int i = t; i < n; i += 256) atomicAdd(&c[s[i] >> 17], 1);
  __syncthreads();
  int node = b * 256 + t;
  int deg = c[t];
  if (node < UI_N) cnt[node] = deg;
  red[t] = deg;
  __syncthreads();
  for (int off = 128; off > 0; off >>= 1) {
    if (t < off) red[t] += red[t + off];
    __syncthreads();
  }
  if (t == 0) bsum[b] = red[0];
}

// ---------------- single-block exclusive scan over bucket totals ----------------
__global__ __launch_bounds__(1024) void k_scanb(const int* __restrict__ bsum,
                                                int* __restrict__ bbase) {
  __shared__ int sc[1024];
  int t = threadIdx.x;
  int v = (t < NBK) ? bsum[t] : 0;
  sc[t] = v;
  __syncthreads();
  int val = v;
  for (int off = 1; off < 1024; off <<= 1) {
    int x = (t >= off) ? sc[t - off] : 0;
    __syncthreads();
    val += x;
    sc[t] = val;
    __syncthreads();
  }
  if (t < NBK) bbase[t] = val - v;  // exclusive
}

// ---- CSR build: phase 2 (local prefix -> exact ptr, scatter) ------
__global__ __launch_bounds__(256) void k_build2(const int* __restrict__ bcnt,
                                                const int* __restrict__ storage,
                                                const int* __restrict__ cnt,
                                                const int* __restrict__ bbase,
                                                int* __restrict__ ptr,
                                                int* __restrict__ col) {
  __shared__ int pb[256];
  __shared__ int cur[256];
  __shared__ int sc[256];
  int b = blockIdx.x;
  int t = threadIdx.x;
  int node = b * 256 + t;
  int deg = (node < UI_N) ? cnt[node] : 0;
  sc[t] = deg;
  __syncthreads();
  int val = deg;
  for (int off = 1; off < 256; off <<= 1) {
    int x = (t >= off) ? sc[t - off] : 0;
    __syncthreads();
    val += x;
    sc[t] = val;
    __syncthreads();
  }
  int base = bbase[b];
  int myPtr = base + (val - deg);
  pb[t] = myPtr;
  cur[t] = 0;
  if (node < UI_N) ptr[node] = myPtr;
  if (b == NBK - 1 && t == 255) ptr[UI_N] = base + val;
  __syncthreads();
  int n = bcnt[b];
  const int* s = storage + (size_t)b * CAP;
  for (int i = t; i < n; i += 256) {
    int e = s[i];
    int local = e >> 17;
    int slot = pb[local] + atomicAdd(&cur[local], 1);
    col[slot] = e & 0x1FFFF;
  }
}

// ---------------- Fused matmul + attention scores (users + items, one launch) ---------
__global__ __launch_bounds__(256) void k_mm2(
    const float* __restrict__ Xu32, const float* __restrict__ Xi32,
    const __half* __restrict__ Xu16, const __half* __restrict__ Xi16,
    const float* __restrict__ Wu, const float* __restrict__ Wi,
    const float* __restrict__ a, int layer,
    __half* __restrict__ fA_U, __half* __restrict__ fA_I,
    __half* __restrict__ s16U, __half* __restrict__ s16I) {
  __shared__ float Wl[4096];
  __shared__ float Xs[4096];
  const bool isU = blockIdx.x < NB_U;
  const int N = isU ? U_N : I_N;
  const int base = (isU ? blockIdx.x : blockIdx.x - NB_U) * 64;
  const float* W = isU ? Wu : Wi;
  __half* f16 = isU ? fA_U : fA_I;
  __half* s16 = isU ? s16U : s16I;
  const int aoff = (layer == 1) ? (isU ? 0 : 8) : (isU ? 0 : 64);
  int t = threadIdx.x;

  if (layer == 1) {
#pragma unroll
    for (int k = 0; k < 4; k++) {
      int i = t + 256 * k;
      int h = i >> 7, d = (i >> 1) & 63, half = i & 1;
      float4 v = *(const float4*)(W + h * 512 + d * 8 + half * 4);
      *(float4*)(Wl + d * 64 + h * 8 + half * 4) = v;
    }
    const float* X = isU ? Xu32 : Xi32;
#pragma unroll
    for (int k = 0; k < 4; k++) {
      int i = t + 256 * k;
      int r = i >> 4, ch = i & 15;
      int node = base + r;
      float4 v = make_float4(0.f, 0.f, 0.f, 0.f);
      if (node < N) v = *(const float4*)(X + (size_t)node * 64 + ch * 4);
      *(float4*)(Xs + r * 64 + ch * 4) = v;
    }
  } else {
#pragma unroll
    for (int k = 0; k < 4; k++) {
      int i = t + 256 * k;
      *(float4*)(Wl + i * 4) = *(const float4*)(W + i * 4);
    }
    const __half* X = isU ? Xu16 : Xi16;
#pragma unroll
    for (int k = 0; k < 4; k++) {
      int i = t + 256 * k;
      int r = i >> 4, ch = i & 15;
      int node = base + r;
      float4 v = make_float4(0.f, 0.f, 0.f, 0.f);
      if (node < N) {
        const __half2* hp = (const __half2*)(X + (size_t)node * 64 + ch * 4);
        float2 f0 = __half22float2(hp[0]);
        float2 f1 = __half22float2(hp[1]);
        v = make_float4(f0.x, f0.y, f1.x, f1.y);
      }
      *(float4*)(Xs + r * 64 + ch * 4) = v;
    }
  }
  __syncthreads();

  const int c0 = t & 31;
  const int rb = t >> 5;
  float acc0[8], acc1[8];
#pragma unroll
  for (int k = 0; k < 8; k++) { acc0[k] = 0.f; acc1[k] = 0.f; }

  for (int d0 = 0; d0 < 64; d0 += 4) {
    float2 wA = *(float2*)(Wl + (d0 + 0) * 64 + 2 * c0);
    float2 wB = *(float2*)(Wl + (d0 + 1) * 64 + 2 * c0);
    float2 wC = *(float2*)(Wl + (d0 + 2) * 64 + 2 * c0);
    float2 wD = *(float2*)(Wl + (d0 + 3) * 64 + 2 * c0);
#pragma unroll
    for (int k = 0; k < 8; k++) {
      float4 x = *(float4*)(Xs + (rb + 8 * k) * 64 + d0);
      acc0[k] += x.x * wA.x + x.y * wB.x + x.z * wC.x + x.w * wD.x;
      acc1[k] += x.x * wA.y + x.y * wB.y + x.z * wC.y + x.w * wD.y;
    }
  }

  float av0, av1;
  if (layer == 1) {
    int h = c0 >> 2, j = 2 * (c0 & 3);
    av0 = a[h * 16 + aoff + j];
    av1 = a[h * 16 + aoff + j + 1];
  } else {
    av0 = a[aoff + 2 * c0];
    av1 = a[aoff + 2 * c0 + 1];
  }
#pragma unroll
  for (int k = 0; k < 8; k++) {
    int node = base + rb + 8 * k;
    float s = acc0[k] * av0 + acc1[k] * av1;
    s += __shfl_xor(s, 1);
    s += __shfl_xor(s, 2);
    if (layer != 1) {
      s += __shfl_xor(s, 4);
      s += __shfl_xor(s, 8);
      s += __shfl_xor(s, 16);
    }
    if (node < N) {
      float2 f;
      f.x = acc0[k];
      f.y = acc1[k];
      *(__half2*)(f16 + (size_t)node * 64 + 2 * c0) = __float22half2_rn(f);
      if (layer == 1) {
        if ((c0 & 3) == 0) s16[node * 8 + (c0 >> 2)] = __float2half_rn(s);
      } else {
        if (c0 == 0) s16[node] = __float2half_rn(s);
      }
    }
  }
}

// ---------------- Fused aggregation: exact rows, masked tail only ----------------
// One wave per node; 8 edges/group x 2 in flight; fp16 gathers; fused ELU.
__global__ __launch_bounds__(256) void k_agg2(
    const int* __restrict__ ptr, const int* __restrict__ col,
    const __half* __restrict__ fA_U, const __half* __restrict__ fA_I,
    __half* __restrict__ fB_U, __half* __restrict__ fB_I,
    const __half* __restrict__ s16U, const __half* __restrict__ s16I,
    int layer) {
  int gid = blockIdx.x * blockDim.x + threadIdx.x;
  int n = gid >> 6;
  if (n >= UI_N) return;
  int l = threadIdx.x & 63;
  int g = l >> 3;       // edge group 0..7
  int cc = l & 7;       // feature chunk / head
  bool isU = n < U_N;
  int nl = isU ? n : n - U_N;
  const char* nbrF = (const char*)(isU ? fA_I : fA_U);
  const char* nbrS = (const char*)(isU ? s16I : s16U);
  const __half* selfS = isU ? s16U : s16I;
  const __half* selfF = isU ? fA_U : fA_I;
  __half* outp = isU ? fB_U : fB_I;
  const char* colc = (const char*)col;

  int beg = ptr[n], endA = ptr[n + 1];
  int deg = endA - beg;
  int pairs = deg >> 4;
  int rem = deg & 15;
  unsigned coff = ((unsigned)(beg + g)) << 2;
  const unsigned begb = (unsigned)beg << 2;
  const unsigned fsh = (unsigned)cc << 4;  // feature chunk byte offset in 128B row
  float acc[8];
#pragma unroll
  for (int k = 0; k < 8; k++) acc[k] = 0.f;
  float wsum = 0.f;

  if (layer == 1) {
    const unsigned ssh = (unsigned)cc << 1;  // head byte offset in 16B score row
    float sself = __half2float(selfS[(size_t)nl * 8 + cc]);
    for (; pairs > 0; pairs--) {
      int nbA = *(const int*)(colc + coff);
      int nbB = *(const int*)(colc + coff + 32);
      coff += 64;
      float xA = sself + __half2float(*(const __half*)(nbrS + (((unsigned)nbA << 4) + ssh)));
      float xB = sself + __half2float(*(const __half*)(nbrS + (((unsigned)nbB << 4) + ssh)));
      float4 rA = *(const float4*)(nbrF + (((unsigned)nbA << 7) + fsh));
      float4 rB = *(const float4*)(nbrF + (((unsigned)nbB << 7) + fsh));
      float wA = __expf(-fmaxf(xA, 0.2f * xA));
      float wB = __expf(-fmaxf(xB, 0.2f * xB));
      wsum += wA + wB;
      const __half* hA = (const __half*)&rA;
      const __half* hB = (const __half*)&rB;
#pragma unroll
      for (int k = 0; k < 8; k++) acc[k] += wA * (float)hA[k];
#pragma unroll
      for (int k = 0; k < 8; k++) acc[k] += wB * (float)hB[k];
    }
    if (rem) {
      bool vA = g < rem;
      bool vB = (8 + g) < rem;
      unsigned cA = vA ? coff : begb;
      unsigned cB = vB ? (coff + 32) : begb;
      int nbA = *(const int*)(colc + cA);
      int nbB = *(const int*)(colc + cB);
      float xA = sself + __half2float(*(const __half*)(nbrS + (((unsigned)nbA << 4) + ssh)));
      float xB = sself + __half2float(*(const __half*)(nbrS + (((unsigned)nbB << 4) + ssh)));
      float4 rA = *(const float4*)(nbrF + (((unsigned)nbA << 7) + fsh));
      float4 rB = *(const float4*)(nbrF + (((unsigned)nbB << 7) + fsh));
      float wA = vA ? __expf(-fmaxf(xA, 0.2f * xA)) : 0.f;
      float wB = vB ? __expf(-fmaxf(xB, 0.2f * xB)) : 0.f;
      wsum += wA + wB;
      const __half* hA = (const __half*)&rA;
      const __half* hB = (const __half*)&rB;
#pragma unroll
      for (int k = 0; k < 8; k++) acc[k] += wA * (float)hA[k];
#pragma unroll
      for (int k = 0; k < 8; k++) acc[k] += wB * (float)hB[k];
    }
  } else {
    float sself = __half2float(selfS[nl]);
    for (; pairs > 0; pairs--) {
      int nbA = *(const int*)(colc + coff);
      int nbB = *(const int*)(colc + coff + 32);
      coff += 64;
      float xA = sself + __half2float(*(const __half*)(nbrS + ((unsigned)nbA << 1)));
      float xB = sself + __half2float(*(const __half*)(nbrS + ((unsigned)nbB << 1)));
      float4 rA = *(const float4*)(nbrF + (((unsigned)nbA << 7) + fsh));
      float4 rB = *(const float4*)(nbrF + (((unsigned)nbB << 7) + fsh));
      float wA = __expf(-fmaxf(xA, 0.2f * xA));
      float wB = __expf(-fmaxf(xB, 0.2f * xB));
      wsum += wA + wB;
      const __half* hA = (const __half*)&rA;
      const __half* hB = (const __half*)&rB;
#pragma unroll
      for (int k = 0; k < 8; k++) acc[k] += wA * (float)hA[k];
#pragma unroll
      for (int k = 0; k < 8; k++) acc[k] += wB * (float)hB[k];
    }
    if (rem) {
      bool vA = g < rem;
      bool vB = (8 + g) < rem;
      unsigned cA = vA ? coff : begb;
      unsigned cB = vB ? (coff + 32) : begb;
      int nbA = *(const int*)(colc + cA);
      int nbB = *(const int*)(colc + cB);
      float xA = sself + __half2float(*(const __half*)(nbrS + ((unsigned)nbA << 1)));
      float xB = sself + __half2float(*(const __half*)(nbrS + ((unsigned)nbB << 1)));
      float4 rA = *(const float4*)(nbrF + (((unsigned)nbA << 7) + fsh));
      float4 rB = *(const float4*)(nbrF + (((unsigned)nbB << 7) + fsh));
      float wA = vA ? __expf(-fmaxf(xA, 0.2f * xA)) : 0.f;
      float wB = vB ? __expf(-fmaxf(xB, 0.2f * xB)) : 0.f;
      wsum += wA + wB;
      const __half* hA = (const __half*)&rA;
      const __half* hB = (const __half*)&rB;
#pragma unroll
      for (int k = 0; k < 8; k++) acc[k] += wA * (float)hA[k];
#pragma unroll
      for (int k = 0; k < 8; k++) acc[k] += wB * (float)hB[k];
    }
  }

#pragma unroll
  for (int k = 0; k < 8; k++) {
    acc[k] += __shfl_xor(acc[k], 8);
    acc[k] += __shfl_xor(acc[k], 16);
    acc[k] += __shfl_xor(acc[k], 32);
  }
  wsum += __shfl_xor(wsum, 8);
  wsum += __shfl_xor(wsum, 16);
  wsum += __shfl_xor(wsum, 32);

  if (l < 8) {
    float4 raw = *(const float4*)(selfF + (size_t)nl * 64 + cc * 8);
    const __half2* sp = (const __half2*)&raw;
    float2 s0 = __half22float2(sp[0]);
    float2 s1 = __half22float2(sp[1]);
    float2 s2 = __half22float2(sp[2]);
    float2 s3 = __half22float2(sp[3]);
    float v[8] = {s0.x, s0.y, s1.x, s1.y, s2.x, s2.y, s3.x, s3.y};
    if (deg > 0) {
      float inv = 1.f / wsum;
#pragma unroll
      for (int k = 0; k < 8; k++) v[k] += acc[k] * inv;
    }
#pragma unroll
    for (int k = 0; k < 8; k++) v[k] = (v[k] > 0.f) ? v[k] : (__expf(v[k]) - 1.f);
    __half2 o[4];
    o[0] = __floats2half2_rn(v[0], v[1]);
    o[1] = __floats2half2_rn(v[2], v[3]);
    o[2] = __floats2half2_rn(v[4], v[5]);
    o[3] = __floats2half2_rn(v[6], v[7]);
    *(float4*)(outp + (size_t)nl * 64 + cc * 8) = *(float4*)o;
  }
}

// ---------------- Final pair dot (fp16 inputs; 32 pairs/block, 8 lanes each) ----------
__global__ void k_dot(const int* __restrict__ uIdx, const int* __restrict__ iIdx,
                      const __half* __restrict__ u_f, const __half* __restrict__ i_f,
                      float* __restrict__ out) {
  int t = threadIdx.x;
  int pair = blockIdx.x * 32 + (t >> 3);
  int cc = t & 7;
  float4 ra = *(const float4*)(u_f + (size_t)uIdx[pair] * 64 + cc * 8);
  float4 rb = *(const float4*)(i_f + (size_t)iIdx[pair] * 64 + cc * 8);
  const __half* ha = (const __half*)&ra;
  const __half* hb = (const __half*)&rb;
  float v = 0.f;
#pragma unroll
  for (int k = 0; k < 8; k++) v += (float)ha[k] * (float)hb[k];
  v += __shfl_xor(v, 1);
  v += __shfl_xor(v, 2);
  v += __shfl_xor(v, 4);
  if (cc == 0) out[pair] = v;
}

extern "C" void kernel_launch(void* const* d_in, const int* in_sizes, int n_in,
                              void* d_out, int out_size, void* d_ws, size_t ws_size,
                              hipStream_t stream) {
  const int* userIdx = (const int*)d_in[0];
  const int* itemIdx = (const int*)d_in[1];
  const int* edge_u = (const int*)d_in[2];
  const int* edge_i = (const int*)d_in[3];
  const float* uEmbd = (const float*)d_in[4];
  const float* iEmbd = (const float*)d_in[5];
  const float* Wu_h = (const float*)d_in[6];
  const float* Wi_h = (const float*)d_in[7];
  const float* a_h = (const float*)d_in[8];
  const float* Wu_out = (const float*)d_in[9];
  const float* Wi_out = (const float*)d_in[10];
  const float* a_out = (const float*)d_in[11];
  float* out = (float*)d_out;

  char* w = (char*)d_ws;
  size_t off = 0;
  auto alloc = [&](size_t bytes) -> void* {
    void* p = w + off;
    off += (bytes + 511) & ~(size_t)511;
    return p;
  };
  int* bcnt = (int*)alloc((size_t)NBK * 4);
  int* cnt = (int*)alloc((size_t)UI_N * 4);
  int* ptr = (int*)alloc((size_t)(UI_N + 1) * 4);
  int* bsum = (int*)alloc(4096);
  int* bbase = (int*)alloc(4096);
  int* col = (int*)alloc((size_t)COL_CAP * 4);
  // fA (pre-agg gather tables) and scores: NOT aliased with storage
  __half* fA_U = (__half*)alloc((size_t)U_N * 64 * 2);
  __half* fA_I = (__half*)alloc((size_t)I_N * 64 * 2);
  __half* s16U = (__half*)alloc((size_t)U_N * 8 * 2);
  __half* s16I = (__half*)alloc((size_t)I_N * 8 * 2);
  __half* s2U = (__half*)alloc((size_t)U_N * 2);
  __half* s2I = (__half*)alloc((size_t)I_N * 2);
  // union tail: storage (24 MB, dead after k_build2) aliases fB (first write: agg L1)
  size_t union_off = off;
  int* storage = (int*)alloc((size_t)NBK * CAP * 4);
  size_t end_storage = off;
  off = union_off;
  __half* fB_U = (__half*)alloc((size_t)U_N * 64 * 2);
  __half* fB_I = (__half*)alloc((size_t)I_N * 64 * 2);
  if (off < end_storage) off = end_storage;

  // CSR/CSC build (exact rows, bucket-level scan)
  hipMemsetAsync(bcnt, 0, (size_t)NBK * 4, stream);
  k_build1<<<NBLD, 1024, 0, stream>>>(edge_u, edge_i, bcnt, storage);
  k_count<<<NBK, 256, 0, stream>>>(bcnt, storage, cnt, bsum);
  k_scanb<<<1, 1024, 0, stream>>>(bsum, bbase);
  k_build2<<<NBK, 256, 0, stream>>>(bcnt, storage, cnt, bbase, ptr, col);

  // Layer 1: mm (fp32 in -> fA fp16 + scores); agg (gather fA -> fB)
  k_mm2<<<NB_U + NB_I, 256, 0, stream>>>(uEmbd, iEmbd, (const __half*)nullptr,
                                         (const __half*)nullptr, Wu_h, Wi_h, a_h, 1,
                                         fA_U, fA_I, s16U, s16I);
  k_agg2<<<UI_N * 64 / 256, 256, 0, stream>>>(ptr, col, fA_U, fA_I, fB_U, fB_I,
                                              s16U, s16I, 1);

  // Layer 2: mm (fB fp16 in -> fA fp16 + s2); agg (gather fA -> fB)
  k_mm2<<<NB_U + NB_I, 256, 0, stream>>>((const float*)nullptr, (const float*)nullptr,
                                         fB_U, fB_I, Wu_out, Wi_out, a_out, 2,
                                         fA_U, fA_I, s2U, s2I);
  k_agg2<<<UI_N * 64 / 256, 256, 0, stream>>>(ptr, col, fA_U, fA_I, fB_U, fB_I,
                                              s2U, s2I, 2);

  // Final per-pair dot (fp16 features)
  k_dot<<<B_N / 32, 256, 0, stream>>>(userIdx, itemIdx, fB_U, fB_I, out);
}

// Round 13
// 376.095 us; speedup vs baseline: 1.1235x; 1.0254x over previous
//
#include <hip/hip_runtime.h>
#include <hip/hip_fp16.h>

#define U_N 50000
#define I_N 100000
#define E_N 1600000
#define B_N 16384
#define UI_N (U_N + I_N)   // 150000
#define NB_U 782           // ceil(50000/64)
#define NB_I 1563          // ceil(100000/64)
#define NBK 586            // ceil(150000/256) buckets, 256 nodes each
#define CAP 10240          // entries per bucket (mean 8192 max, ~22 sigma margin)
#define NBLD 512           // blocks in k_build1
#define CHUNK (E_N / NBLD) // 3125 edges per block
#define COL_CAP 3300000    // >= 2E exact CSR slots

// ---------------- CSR build: phase 1 (block-local binning, packed 4B entries) ---------
__global__ __launch_bounds__(1024) void k_build1(
    const int* __restrict__ eu, const int* __restrict__ ei,
    int* __restrict__ bcnt, int* __restrict__ storage) {
  __shared__ int hist[NBK];
  __shared__ int lbase[NBK];
  __shared__ int loff[NBK];
  int t = threadIdx.x;
  for (int b = t; b < NBK; b += 1024) { hist[b] = 0; loff[b] = 0; }
  __syncthreads();
  int e0 = blockIdx.x * CHUNK;
  int e1 = e0 + CHUNK;
  for (int e = e0 + t; e < e1; e += 1024) {
    int u = eu[e];
    int k2 = U_N + ei[e];
    atomicAdd(&hist[u >> 8], 1);
    atomicAdd(&hist[k2 >> 8], 1);
  }
  __syncthreads();
  for (int b = t; b < NBK; b += 1024) {
    int h = hist[b];
    lbase[b] = h ? atomicAdd(&bcnt[b], h) : 0;
  }
  __syncthreads();
  for (int e = e0 + t; e < e1; e += 1024) {
    int u = eu[e], it = ei[e];
    int k2 = U_N + it;
    int b1 = u >> 8;
    int s1 = lbase[b1] + atomicAdd(&loff[b1], 1);
    storage[(size_t)b1 * CAP + s1] = ((u & 255) << 17) | it;
    int b2 = k2 >> 8;
    int s2 = lbase[b2] + atomicAdd(&loff[b2], 1);
    storage[(size_t)b2 * CAP + s2] = ((k2 & 255) << 17) | u;
  }
}

// ---------------- per-node degrees + per-bucket totals ----------------
__global__ __launch_bounds__(256) void k_count(const int* __restrict__ bcnt,
                                               const int* __restrict__ storage,
                                               int* __restrict__ cnt,
                                               int* __restrict__ bsum) {
  __shared__ int c[256];
  __shared__ int red[256];
  int b = blockIdx.x;
  int t = threadIdx.x;
  c[t] = 0;
  __syncthreads();
  int n = bcnt[b];
  const int* s = storage + (size_t)b * CAP;
  for (int i = t; i < n; i += 256) atomicAdd(&c[s[i] >> 17], 1);
  __syncthreads();
  int node = b * 256 + t;
  int deg = c[t];
  if (node < UI_N) cnt[node] = deg;
  red[t] = deg;
  __syncthreads();
  for (int off = 128; off > 0; off >>= 1) {
    if (t < off) red[t] += red[t + off];
    __syncthreads();
  }
  if (t == 0) bsum[b] = red[0];
}

// ---------------- single-block exclusive scan over bucket totals ----------------
__global__ __launch_bounds__(1024) void k_scanb(const int* __restrict__ bsum,
                                                int* __restrict__ bbase) {
  __shared__ int sc[1024];
  int t = threadIdx.x;
  int v = (t < NBK) ? bsum[t] : 0;
  sc[t] = v;
  __syncthreads();
  int val = v;
  for (int off = 1; off < 1024; off <<= 1) {
    int x = (t >= off) ? sc[t - off] : 0;
    __syncthreads();
    val += x;
    sc[t] = val;
    __syncthreads();
  }
  if (t < NBK) bbase[t] = val - v;  // exclusive
}

// ---- CSR build: phase 2 (local prefix -> exact ptr, scatter) ------
__global__ __launch_bounds__(256) void k_build2(const int* __restrict__ bcnt,
                                                const int* __restrict__ storage,
                                                const int* __restrict__ cnt,
                                                const int* __restrict__ bbase,
                                                int* __restrict__ ptr,
                                                int* __restrict__ col) {
  __shared__ int pb[256];
  __shared__ int cur[256];
  __shared__ int sc[256];
  int b = blockIdx.x;
  int t = threadIdx.x;
  int node = b * 256 + t;
  int deg = (node < UI_N) ? cnt[node] : 0;
  sc[t] = deg;
  __syncthreads();
  int val = deg;
  for (int off = 1; off < 256; off <<= 1) {
    int x = (t >= off) ? sc[t - off] : 0;
    __syncthreads();
    val += x;
    sc[t] = val;
    __syncthreads();
  }
  int base = bbase[b];
  int myPtr = base + (val - deg);
  pb[t] = myPtr;
  cur[t] = 0;
  if (node < UI_N) ptr[node] = myPtr;
  if (b == NBK - 1 && t == 255) ptr[UI_N] = base + val;
  __syncthreads();
  int n = bcnt[b];
  const int* s = storage + (size_t)b * CAP;
  for (int i = t; i < n; i += 256) {
    int e = s[i];
    int local = e >> 17;
    int slot = pb[local] + atomicAdd(&cur[local], 1);
    col[slot] = e & 0x1FFFF;
  }
}

// ---------------- Fused matmul + attention scores (users + items, one launch) ---------
__global__ __launch_bounds__(256) void k_mm2(
    const float* __restrict__ Xu32, const float* __restrict__ Xi32,
    const __half* __restrict__ Xu16, const __half* __restrict__ Xi16,
    const float* __restrict__ Wu, const float* __restrict__ Wi,
    const float* __restrict__ a, int layer,
    __half* __restrict__ fA_U, __half* __restrict__ fA_I,
    __half* __restrict__ s16U, __half* __restrict__ s16I) {
  __shared__ float Wl[4096];
  __shared__ float Xs[4096];
  const bool isU = blockIdx.x < NB_U;
  const int N = isU ? U_N : I_N;
  const int base = (isU ? blockIdx.x : blockIdx.x - NB_U) * 64;
  const float* W = isU ? Wu : Wi;
  __half* f16 = isU ? fA_U : fA_I;
  __half* s16 = isU ? s16U : s16I;
  const int aoff = (layer == 1) ? (isU ? 0 : 8) : (isU ? 0 : 64);
  int t = threadIdx.x;

  if (layer == 1) {
#pragma unroll
    for (int k = 0; k < 4; k++) {
      int i = t + 256 * k;
      int h = i >> 7, d = (i >> 1) & 63, half = i & 1;
      float4 v = *(const float4*)(W + h * 512 + d * 8 + half * 4);
      *(float4*)(Wl + d * 64 + h * 8 + half * 4) = v;
    }
    const float* X = isU ? Xu32 : Xi32;
#pragma unroll
    for (int k = 0; k < 4; k++) {
      int i = t + 256 * k;
      int r = i >> 4, ch = i & 15;
      int node = base + r;
      float4 v = make_float4(0.f, 0.f, 0.f, 0.f);
      if (node < N) v = *(const float4*)(X + (size_t)node * 64 + ch * 4);
      *(float4*)(Xs + r * 64 + ch * 4) = v;
    }
  } else {
#pragma unroll
    for (int k = 0; k < 4; k++) {
      int i = t + 256 * k;
      *(float4*)(Wl + i * 4) = *(const float4*)(W + i * 4);
    }
    const __half* X = isU ? Xu16 : Xi16;
#pragma unroll
    for (int k = 0; k < 4; k++) {
      int i = t + 256 * k;
      int r = i >> 4, ch = i & 15;
      int node = base + r;
      float4 v = make_float4(0.f, 0.f, 0.f, 0.f);
      if (node < N) {
        const __half2* hp = (const __half2*)(X + (size_t)node * 64 + ch * 4);
        float2 f0 = __half22float2(hp[0]);
        float2 f1 = __half22float2(hp[1]);
        v = make_float4(f0.x, f0.y, f1.x, f1.y);
      }
      *(float4*)(Xs + r * 64 + ch * 4) = v;
    }
  }
  __syncthreads();

  const int c0 = t & 31;
  const int rb = t >> 5;
  float acc0[8], acc1[8];
#pragma unroll
  for (int k = 0; k < 8; k++) { acc0[k] = 0.f; acc1[k] = 0.f; }

  for (int d0 = 0; d0 < 64; d0 += 4) {
    float2 wA = *(float2*)(Wl + (d0 + 0) * 64 + 2 * c0);
    float2 wB = *(float2*)(Wl + (d0 + 1) * 64 + 2 * c0);
    float2 wC = *(float2*)(Wl + (d0 + 2) * 64 + 2 * c0);
    float2 wD = *(float2*)(Wl + (d0 + 3) * 64 + 2 * c0);
#pragma unroll
    for (int k = 0; k < 8; k++) {
      float4 x = *(float4*)(Xs + (rb + 8 * k) * 64 + d0);
      acc0[k] += x.x * wA.x + x.y * wB.x + x.z * wC.x + x.w * wD.x;
      acc1[k] += x.x * wA.y + x.y * wB.y + x.z * wC.y + x.w * wD.y;
    }
  }

  float av0, av1;
  if (layer == 1) {
    int h = c0 >> 2, j = 2 * (c0 & 3);
    av0 = a[h * 16 + aoff + j];
    av1 = a[h * 16 + aoff + j + 1];
  } else {
    av0 = a[aoff + 2 * c0];
    av1 = a[aoff + 2 * c0 + 1];
  }
#pragma unroll
  for (int k = 0; k < 8; k++) {
    int node = base + rb + 8 * k;
    float s = acc0[k] * av0 + acc1[k] * av1;
    s += __shfl_xor(s, 1);
    s += __shfl_xor(s, 2);
    if (layer != 1) {
      s += __shfl_xor(s, 4);
      s += __shfl_xor(s, 8);
      s += __shfl_xor(s, 16);
    }
    if (node < N) {
      float2 f;
      f.x = acc0[k];
      f.y = acc1[k];
      *(__half2*)(f16 + (size_t)node * 64 + 2 * c0) = __float22half2_rn(f);
      if (layer == 1) {
        if ((c0 & 3) == 0) s16[node * 8 + (c0 >> 2)] = __float2half_rn(s);
      } else {
        if (c0 == 0) s16[node] = __float2half_rn(s);
      }
    }
  }
}

// ---------------- Fused aggregation: exact rows, unroll-4 (32 edges in flight) -------
// One wave per node; 8 edges/group x 4 in flight; fp16 gathers; fused ELU.
template <int LAYER>
__global__ __launch_bounds__(256) void k_agg3(
    const int* __restrict__ ptr, const int* __restrict__ col,
    const __half* __restrict__ fA_U, const __half* __restrict__ fA_I,
    __half* __restrict__ fB_U, __half* __restrict__ fB_I,
    const __half* __restrict__ s16U, const __half* __restrict__ s16I) {
  int gid = blockIdx.x * blockDim.x + threadIdx.x;
  int n = gid >> 6;
  if (n >= UI_N) return;
  int l = threadIdx.x & 63;
  int g = l >> 3;       // edge group 0..7
  int cc = l & 7;       // feature chunk / head
  bool isU = n < U_N;
  int nl = isU ? n : n - U_N;
  const char* nbrF = (const char*)(isU ? fA_I : fA_U);
  const char* nbrS = (const char*)(isU ? s16I : s16U);
  const __half* selfS = isU ? s16U : s16I;
  const __half* selfF = isU ? fA_U : fA_I;
  __half* outp = isU ? fB_U : fB_I;
  const char* colc = (const char*)col;

  int beg = ptr[n], endA = ptr[n + 1];
  int deg = endA - beg;
  unsigned coff = ((unsigned)(beg + g)) << 2;
  const unsigned begb = (unsigned)beg << 2;
  const unsigned fsh = (unsigned)cc << 4;
  const unsigned ssh = (LAYER == 1) ? ((unsigned)cc << 1) : 0u;
  float sself = (LAYER == 1) ? __half2float(selfS[(size_t)nl * 8 + cc])
                             : __half2float(selfS[nl]);
  float acc[8];
#pragma unroll
  for (int k = 0; k < 8; k++) acc[k] = 0.f;
  float wsum = 0.f;

  auto edge = [&](unsigned off) {
    int nb = *(const int*)(colc + off);
    unsigned so = (LAYER == 1) ? (((unsigned)nb << 4) + ssh) : ((unsigned)nb << 1);
    float x = sself + __half2float(*(const __half*)(nbrS + so));
    float4 r = *(const float4*)(nbrF + (((unsigned)nb << 7) + fsh));
    float w = __expf(-fmaxf(x, 0.2f * x));
    wsum += w;
    const __half* h = (const __half*)&r;
#pragma unroll
    for (int k = 0; k < 8; k++) acc[k] += w * (float)h[k];
  };
  auto edgem = [&](unsigned off, bool valid) {
    unsigned o = valid ? off : begb;
    int nb = *(const int*)(colc + o);
    unsigned so = (LAYER == 1) ? (((unsigned)nb << 4) + ssh) : ((unsigned)nb << 1);
    float x = sself + __half2float(*(const __half*)(nbrS + so));
    float4 r = *(const float4*)(nbrF + (((unsigned)nb << 7) + fsh));
    float w = valid ? __expf(-fmaxf(x, 0.2f * x)) : 0.f;
    wsum += w;
    const __half* h = (const __half*)&r;
#pragma unroll
    for (int k = 0; k < 8; k++) acc[k] += w * (float)h[k];
  };

  int q4 = deg >> 5;                 // 32-edge chunks
  for (; q4 > 0; q4--) {
    edge(coff);
    edge(coff + 32);
    edge(coff + 64);
    edge(coff + 96);
    coff += 128;
  }
  int rem = deg & 31;
  if (rem >= 16) {
    edge(coff);
    edge(coff + 32);
    coff += 64;
    rem -= 16;
  }
  if (rem) {
    edgem(coff, g < rem);
    edgem(coff + 32, (8 + g) < rem);
  }

#pragma unroll
  for (int k = 0; k < 8; k++) {
    acc[k] += __shfl_xor(acc[k], 8);
    acc[k] += __shfl_xor(acc[k], 16);
    acc[k] += __shfl_xor(acc[k], 32);
  }
  wsum += __shfl_xor(wsum, 8);
  wsum += __shfl_xor(wsum, 16);
  wsum += __shfl_xor(wsum, 32);

  if (l < 8) {
    float4 raw = *(const float4*)(selfF + (size_t)nl * 64 + cc * 8);
    const __half2* sp = (const __half2*)&raw;
    float2 s0 = __half22float2(sp[0]);
    float2 s1 = __half22float2(sp[1]);
    float2 s2 = __half22float2(sp[2]);
    float2 s3 = __half22float2(sp[3]);
    float v[8] = {s0.x, s0.y, s1.x, s1.y, s2.x, s2.y, s3.x, s3.y};
    if (deg > 0) {
      float inv = 1.f / wsum;
#pragma unroll
      for (int k = 0; k < 8; k++) v[k] += acc[k] * inv;
    }
#pragma unroll
    for (int k = 0; k < 8; k++) v[k] = (v[k] > 0.f) ? v[k] : (__expf(v[k]) - 1.f);
    __half2 o[4];
    o[0] = __floats2half2_rn(v[0], v[1]);
    o[1] = __floats2half2_rn(v[2], v[3]);
    o[2] = __floats2half2_rn(v[4], v[5]);
    o[3] = __floats2half2_rn(v[6], v[7]);
    *(float4*)(outp + (size_t)nl * 64 + cc * 8) = *(float4*)o;
  }
}

// ---------------- Final pair dot (fp16 inputs; 32 pairs/block, 8 lanes each) ----------
__global__ void k_dot(const int* __restrict__ uIdx, const int* __restrict__ iIdx,
                      const __half* __restrict__ u_f, const __half* __restrict__ i_f,
                      float* __restrict__ out) {
  int t = threadIdx.x;
  int pair = blockIdx.x * 32 + (t >> 3);
  int cc = t & 7;
  float4 ra = *(const float4*)(u_f + (size_t)uIdx[pair] * 64 + cc * 8);
  float4 rb = *(const float4*)(i_f + (size_t)iIdx[pair] * 64 + cc * 8);
  const __half* ha = (const __half*)&ra;
  const __half* hb = (const __half*)&rb;
  float v = 0.f;
#pragma unroll
  for (int k = 0; k < 8; k++) v += (float)ha[k] * (float)hb[k];
  v += __shfl_xor(v, 1);
  v += __shfl_xor(v, 2);
  v += __shfl_xor(v, 4);
  if (cc == 0) out[pair] = v;
}

extern "C" void kernel_launch(void* const* d_in, const int* in_sizes, int n_in,
                              void* d_out, int out_size, void* d_ws, size_t ws_size,
                              hipStream_t stream) {
  const int* userIdx = (const int*)d_in[0];
  const int* itemIdx = (const int*)d_in[1];
  const int* edge_u = (const int*)d_in[2];
  const int* edge_i = (const int*)d_in[3];
  const float* uEmbd = (const float*)d_in[4];
  const float* iEmbd = (const float*)d_in[5];
  const float* Wu_h = (const float*)d_in[6];
  const float* Wi_h = (const float*)d_in[7];
  const float* a_h = (const float*)d_in[8];
  const float* Wu_out = (const float*)d_in[9];
  const float* Wi_out = (const float*)d_in[10];
  const float* a_out = (const float*)d_in[11];
  float* out = (float*)d_out;

  char* w = (char*)d_ws;
  size_t off = 0;
  auto alloc = [&](size_t bytes) -> void* {
    void* p = w + off;
    off += (bytes + 511) & ~(size_t)511;
    return p;
  };
  int* bcnt = (int*)alloc((size_t)NBK * 4);
  int* cnt = (int*)alloc((size_t)UI_N * 4);
  int* ptr = (int*)alloc((size_t)(UI_N + 1) * 4);
  int* bsum = (int*)alloc(4096);
  int* bbase = (int*)alloc(4096);
  int* col = (int*)alloc((size_t)COL_CAP * 4);
  // fA (pre-agg gather tables) and scores: NOT aliased with storage
  __half* fA_U = (__half*)alloc((size_t)U_N * 64 * 2);
  __half* fA_I = (__half*)alloc((size_t)I_N * 64 * 2);
  __half* s16U = (__half*)alloc((size_t)U_N * 8 * 2);
  __half* s16I = (__half*)alloc((size_t)I_N * 8 * 2);
  __half* s2U = (__half*)alloc((size_t)U_N * 2);
  __half* s2I = (__half*)alloc((size_t)I_N * 2);
  // union tail: storage (24 MB, dead after k_build2) aliases fB (first write: agg L1)
  size_t union_off = off;
  int* storage = (int*)alloc((size_t)NBK * CAP * 4);
  size_t end_storage = off;
  off = union_off;
  __half* fB_U = (__half*)alloc((size_t)U_N * 64 * 2);
  __half* fB_I = (__half*)alloc((size_t)I_N * 64 * 2);
  if (off < end_storage) off = end_storage;

  // CSR/CSC build (exact rows, bucket-level scan)
  hipMemsetAsync(bcnt, 0, (size_t)NBK * 4, stream);
  k_build1<<<NBLD, 1024, 0, stream>>>(edge_u, edge_i, bcnt, storage);
  k_count<<<NBK, 256, 0, stream>>>(bcnt, storage, cnt, bsum);
  k_scanb<<<1, 1024, 0, stream>>>(bsum, bbase);
  k_build2<<<NBK, 256, 0, stream>>>(bcnt, storage, cnt, bbase, ptr, col);

  // Layer 1: mm (fp32 in -> fA fp16 + scores); agg (gather fA -> fB)
  k_mm2<<<NB_U + NB_I, 256, 0, stream>>>(uEmbd, iEmbd, (const __half*)nullptr,
                                         (const __half*)nullptr, Wu_h, Wi_h, a_h, 1,
                                         fA_U, fA_I, s16U, s16I);
  k_agg3<1><<<UI_N * 64 / 256, 256, 0, stream>>>(ptr, col, fA_U, fA_I, fB_U, fB_I,
                                                 s16U, s16I);

  // Layer 2: mm (fB fp16 in -> fA fp16 + s2); agg (gather fA -> fB)
  k_mm2<<<NB_U + NB_I, 256, 0, stream>>>((const float*)nullptr, (const float*)nullptr,
                                         fB_U, fB_I, Wu_out, Wi_out, a_out, 2,
                                         fA_U, fA_I, s2U, s2I);
  k_agg3<2><<<UI_N * 64 / 256, 256, 0, stream>>>(ptr, col, fA_U, fA_I, fB_U, fB_I,
                                                 s2U, s2I);

  // Final per-pair dot (fp16 features)
  k_dot<<<B_N / 32, 256, 0, stream>>>(userIdx, itemIdx, fB_U, fB_I, out);
}

// Round 14
// 342.436 us; speedup vs baseline: 1.2339x; 1.0983x over previous
//
#include <hip/hip_runtime.h>
#include <hip/hip_fp16.h>

#define U_N 50000
#define I_N 100000
#define E_N 1600000
#define B_N 16384
#define UI_N (U_N + I_N)   // 150000
#define NB_U 782           // ceil(50000/64)
#define NB_I 1563          // ceil(100000/64)
#define NBK 586            // ceil(150000/256) buckets, 256 nodes each
#define CAP 10240          // entries per bucket (mean 8192 max, ~22 sigma margin)
#define NBLD 512           // blocks in k_build1
#define CHUNK (E_N / NBLD) // 3125 edges per block
#define COL_CAP 3300000    // >= 2E exact CSR slots

// ---------------- CSR build: phase 1 (block-local binning, packed 4B entries) ---------
// Edges cached in registers between the histogram and scatter passes.
__global__ __launch_bounds__(1024) void k_build1(
    const int* __restrict__ eu, const int* __restrict__ ei,
    int* __restrict__ bcnt, int* __restrict__ storage) {
  __shared__ int hist[NBK];
  __shared__ int lbase[NBK];
  __shared__ int loff[NBK];
  int t = threadIdx.x;
  for (int b = t; b < NBK; b += 1024) { hist[b] = 0; loff[b] = 0; }
  __syncthreads();
  int e0 = blockIdx.x * CHUNK;
  int myu[4], myi[4];
  int ne = 0;
#pragma unroll
  for (int k = 0; k < 4; k++) {
    int e = e0 + t + 1024 * k;
    if (e < e0 + CHUNK) {
      int u = eu[e], it = ei[e];
      myu[k] = u;
      myi[k] = it;
      ne = k + 1;
      atomicAdd(&hist[u >> 8], 1);
      atomicAdd(&hist[(U_N + it) >> 8], 1);
    }
  }
  __syncthreads();
  for (int b = t; b < NBK; b += 1024) {
    int h = hist[b];
    lbase[b] = h ? atomicAdd(&bcnt[b], h) : 0;
  }
  __syncthreads();
#pragma unroll
  for (int k = 0; k < 4; k++) {
    if (k < ne) {
      int u = myu[k], it = myi[k];
      int k2 = U_N + it;
      int b1 = u >> 8;
      int s1 = lbase[b1] + atomicAdd(&loff[b1], 1);
      storage[(size_t)b1 * CAP + s1] = ((u & 255) << 17) | it;
      int b2 = k2 >> 8;
      int s2 = lbase[b2] + atomicAdd(&loff[b2], 1);
      storage[(size_t)b2 * CAP + s2] = ((k2 & 255) << 17) | u;
    }
  }
}

// ---------------- per-node degrees + per-bucket totals ----------------
__global__ __launch_bounds__(256) void k_count(const int* __restrict__ bcnt,
                                               const int* __restrict__ storage,
                                               int* __restrict__ cnt,
                                               int* __restrict__ bsum) {
  __shared__ int c[256];
  __shared__ int red[256];
  int b = blockIdx.x;
  int t = threadIdx.x;
  c[t] = 0;
  __syncthreads();
  int n = bcnt[b];
  const int* s = storage + (size_t)b * CAP;
  for (int i = t; i < n; i += 256) atomicAdd(&c[s[i] >> 17], 1);
  __syncthreads();
  int node = b * 256 + t;
  int deg = c[t];
  if (node < UI_N) cnt[node] = deg;
  red[t] = deg;
  __syncthreads();
  for (int off = 128; off > 0; off >>= 1) {
    if (t < off) red[t] += red[t + off];
    __syncthreads();
  }
  if (t == 0) bsum[b] = red[0];
}

// ---------------- single-block exclusive scan over bucket totals ----------------
__global__ __launch_bounds__(1024) void k_scanb(const int* __restrict__ bsum,
                                                int* __restrict__ bbase) {
  __shared__ int sc[1024];
  int t = threadIdx.x;
  int v = (t < NBK) ? bsum[t] : 0;
  sc[t] = v;
  __syncthreads();
  int val = v;
  for (int off = 1; off < 1024; off <<= 1) {
    int x = (t >= off) ? sc[t - off] : 0;
    __syncthreads();
    val += x;
    sc[t] = val;
    __syncthreads();
  }
  if (t < NBK) bbase[t] = val - v;  // exclusive
}

// ---- CSR build: phase 2 (local prefix -> exact ptr, scatter) ------
__global__ __launch_bounds__(256) void k_build2(const int* __restrict__ bcnt,
                                                const int* __restrict__ storage,
                                                const int* __restrict__ cnt,
                                                const int* __restrict__ bbase,
                                                int* __restrict__ ptr,
                                                int* __restrict__ col) {
  __shared__ int pb[256];
  __shared__ int cur[256];
  __shared__ int sc[256];
  int b = blockIdx.x;
  int t = threadIdx.x;
  int node = b * 256 + t;
  int deg = (node < UI_N) ? cnt[node] : 0;
  sc[t] = deg;
  __syncthreads();
  int val = deg;
  for (int off = 1; off < 256; off <<= 1) {
    int x = (t >= off) ? sc[t - off] : 0;
    __syncthreads();
    val += x;
    sc[t] = val;
    __syncthreads();
  }
  int base = bbase[b];
  int myPtr = base + (val - deg);
  pb[t] = myPtr;
  cur[t] = 0;
  if (node < UI_N) ptr[node] = myPtr;
  if (b == NBK - 1 && t == 255) ptr[UI_N] = base + val;
  __syncthreads();
  int n = bcnt[b];
  const int* s = storage + (size_t)b * CAP;
  for (int i = t; i < n; i += 256) {
    int e = s[i];
    int local = e >> 17;
    int slot = pb[local] + atomicAdd(&cur[local], 1);
    col[slot] = e & 0x1FFFF;
  }
}

// ---------------- Fused matmul + attention scores (users + items, one launch) ---------
__global__ __launch_bounds__(256) void k_mm2(
    const float* __restrict__ Xu32, const float* __restrict__ Xi32,
    const __half* __restrict__ Xu16, const __half* __restrict__ Xi16,
    const float* __restrict__ Wu, const float* __restrict__ Wi,
    const float* __restrict__ a, int layer,
    __half* __restrict__ fA_U, __half* __restrict__ fA_I,
    __half* __restrict__ s16U, __half* __restrict__ s16I) {
  __shared__ float Wl[4096];
  __shared__ float Xs[4096];
  const bool isU = blockIdx.x < NB_U;
  const int N = isU ? U_N : I_N;
  const int base = (isU ? blockIdx.x : blockIdx.x - NB_U) * 64;
  const float* W = isU ? Wu : Wi;
  __half* f16 = isU ? fA_U : fA_I;
  __half* s16 = isU ? s16U : s16I;
  const int aoff = (layer == 1) ? (isU ? 0 : 8) : (isU ? 0 : 64);
  int t = threadIdx.x;

  if (layer == 1) {
#pragma unroll
    for (int k = 0; k < 4; k++) {
      int i = t + 256 * k;
      int h = i >> 7, d = (i >> 1) & 63, half = i & 1;
      float4 v = *(const float4*)(W + h * 512 + d * 8 + half * 4);
      *(float4*)(Wl + d * 64 + h * 8 + half * 4) = v;
    }
    const float* X = isU ? Xu32 : Xi32;
#pragma unroll
    for (int k = 0; k < 4; k++) {
      int i = t + 256 * k;
      int r = i >> 4, ch = i & 15;
      int node = base + r;
      float4 v = make_float4(0.f, 0.f, 0.f, 0.f);
      if (node < N) v = *(const float4*)(X + (size_t)node * 64 + ch * 4);
      *(float4*)(Xs + r * 64 + ch * 4) = v;
    }
  } else {
#pragma unroll
    for (int k = 0; k < 4; k++) {
      int i = t + 256 * k;
      *(float4*)(Wl + i * 4) = *(const float4*)(W + i * 4);
    }
    const __half* X = isU ? Xu16 : Xi16;
#pragma unroll
    for (int k = 0; k < 4; k++) {
      int i = t + 256 * k;
      int r = i >> 4, ch = i & 15;
      int node = base + r;
      float4 v = make_float4(0.f, 0.f, 0.f, 0.f);
      if (node < N) {
        const __half2* hp = (const __half2*)(X + (size_t)node * 64 + ch * 4);
        float2 f0 = __half22float2(hp[0]);
        float2 f1 = __half22float2(hp[1]);
        v = make_float4(f0.x, f0.y, f1.x, f1.y);
      }
      *(float4*)(Xs + r * 64 + ch * 4) = v;
    }
  }
  __syncthreads();

  const int c0 = t & 31;
  const int rb = t >> 5;
  float acc0[8], acc1[8];
#pragma unroll
  for (int k = 0; k < 8; k++) { acc0[k] = 0.f; acc1[k] = 0.f; }

  for (int d0 = 0; d0 < 64; d0 += 4) {
    float2 wA = *(float2*)(Wl + (d0 + 0) * 64 + 2 * c0);
    float2 wB = *(float2*)(Wl + (d0 + 1) * 64 + 2 * c0);
    float2 wC = *(float2*)(Wl + (d0 + 2) * 64 + 2 * c0);
    float2 wD = *(float2*)(Wl + (d0 + 3) * 64 + 2 * c0);
#pragma unroll
    for (int k = 0; k < 8; k++) {
      float4 x = *(float4*)(Xs + (rb + 8 * k) * 64 + d0);
      acc0[k] += x.x * wA.x + x.y * wB.x + x.z * wC.x + x.w * wD.x;
      acc1[k] += x.x * wA.y + x.y * wB.y + x.z * wC.y + x.w * wD.y;
    }
  }

  float av0, av1;
  if (layer == 1) {
    int h = c0 >> 2, j = 2 * (c0 & 3);
    av0 = a[h * 16 + aoff + j];
    av1 = a[h * 16 + aoff + j + 1];
  } else {
    av0 = a[aoff + 2 * c0];
    av1 = a[aoff + 2 * c0 + 1];
  }
#pragma unroll
  for (int k = 0; k < 8; k++) {
    int node = base + rb + 8 * k;
    float s = acc0[k] * av0 + acc1[k] * av1;
    s += __shfl_xor(s, 1);
    s += __shfl_xor(s, 2);
    if (layer != 1) {
      s += __shfl_xor(s, 4);
      s += __shfl_xor(s, 8);
      s += __shfl_xor(s, 16);
    }
    if (node < N) {
      float2 f;
      f.x = acc0[k];
      f.y = acc1[k];
      *(__half2*)(f16 + (size_t)node * 64 + 2 * c0) = __float22half2_rn(f);
      if (layer == 1) {
        if ((c0 & 3) == 0) s16[node * 8 + (c0 >> 2)] = __float2half_rn(s);
      } else {
        if (c0 == 0) s16[node] = __float2half_rn(s);
      }
    }
  }
}

// ---------------- Fused aggregation: TWO nodes per wave, unroll-4 ----------------
// Half-wave (32 lanes = 4 edge groups x 8 cc) per node; fp16 gathers; fused ELU.
template <int LAYER>
__global__ __launch_bounds__(256) void k_agg4(
    const int* __restrict__ ptr, const int* __restrict__ col,
    const __half* __restrict__ fA_U, const __half* __restrict__ fA_I,
    __half* __restrict__ fB_U, __half* __restrict__ fB_I,
    const __half* __restrict__ s16U, const __half* __restrict__ s16I) {
  int gid = blockIdx.x * blockDim.x + threadIdx.x;
  int wv = gid >> 6;                 // wave index, 0..UI_N/2-1
  int l = threadIdx.x & 63;
  int half = l >> 5;                 // 0 or 1
  int n = wv * 2 + half;             // node (UI_N even; pairs never straddle U/I)
  int lh = l & 31;
  int g = lh >> 3;                   // edge group 0..3
  int cc = lh & 7;                   // feature chunk / head
  bool isU = n < U_N;
  int nl = isU ? n : n - U_N;
  const char* nbrF = (const char*)(isU ? fA_I : fA_U);
  const char* nbrS = (const char*)(isU ? s16I : s16U);
  const __half* selfS = isU ? s16U : s16I;
  const __half* selfF = isU ? fA_U : fA_I;
  __half* outp = isU ? fB_U : fB_I;
  const char* colc = (const char*)col;

  int beg = ptr[n], endA = ptr[n + 1];
  int deg = endA - beg;
  unsigned coff = ((unsigned)(beg + g)) << 2;
  const unsigned begb = (unsigned)beg << 2;
  const unsigned fsh = (unsigned)cc << 4;
  const unsigned ssh = (LAYER == 1) ? ((unsigned)cc << 1) : 0u;
  float sself = (LAYER == 1) ? __half2float(selfS[(size_t)nl * 8 + cc])
                             : __half2float(selfS[nl]);
  float acc[8];
#pragma unroll
  for (int k = 0; k < 8; k++) acc[k] = 0.f;
  float wsum = 0.f;

  auto edge = [&](unsigned off) {      // 4 edges per node per call
    int nb = *(const int*)(colc + off);
    unsigned so = (LAYER == 1) ? (((unsigned)nb << 4) + ssh) : ((unsigned)nb << 1);
    float x = sself + __half2float(*(const __half*)(nbrS + so));
    float4 r = *(const float4*)(nbrF + (((unsigned)nb << 7) + fsh));
    float w = __expf(-fmaxf(x, 0.2f * x));
    wsum += w;
    const __half* h = (const __half*)&r;
#pragma unroll
    for (int k = 0; k < 8; k++) acc[k] += w * (float)h[k];
  };
  auto edgem = [&](unsigned off, bool valid) {
    unsigned o = valid ? off : begb;
    int nb = *(const int*)(colc + o);
    unsigned so = (LAYER == 1) ? (((unsigned)nb << 4) + ssh) : ((unsigned)nb << 1);
    float x = sself + __half2float(*(const __half*)(nbrS + so));
    float4 r = *(const float4*)(nbrF + (((unsigned)nb << 7) + fsh));
    float w = valid ? __expf(-fmaxf(x, 0.2f * x)) : 0.f;
    wsum += w;
    const __half* h = (const __half*)&r;
#pragma unroll
    for (int k = 0; k < 8; k++) acc[k] += w * (float)h[k];
  };

  int q = deg >> 4;                    // 16-edge chunks (4 edge() calls)
  for (; q > 0; q--) {
    edge(coff);
    edge(coff + 16);
    edge(coff + 32);
    edge(coff + 48);
    coff += 64;
  }
  int rem = deg & 15;
  if (rem) {
    edgem(coff, g < rem);
    edgem(coff + 16, (4 + g) < rem);
    edgem(coff + 32, (8 + g) < rem);
    edgem(coff + 48, (12 + g) < rem);
  }

#pragma unroll
  for (int k = 0; k < 8; k++) {        // reduce across the 4 groups (within half-wave)
    acc[k] += __shfl_xor(acc[k], 8);
    acc[k] += __shfl_xor(acc[k], 16);
  }
  wsum += __shfl_xor(wsum, 8);
  wsum += __shfl_xor(wsum, 16);

  if (lh < 8) {
    float4 raw = *(const float4*)(selfF + (size_t)nl * 64 + cc * 8);
    const __half2* sp = (const __half2*)&raw;
    float2 s0 = __half22float2(sp[0]);
    float2 s1 = __half22float2(sp[1]);
    float2 s2 = __half22float2(sp[2]);
    float2 s3 = __half22float2(sp[3]);
    float v[8] = {s0.x, s0.y, s1.x, s1.y, s2.x, s2.y, s3.x, s3.y};
    if (deg > 0) {
      float inv = 1.f / wsum;
#pragma unroll
      for (int k = 0; k < 8; k++) v[k] += acc[k] * inv;
    }
#pragma unroll
    for (int k = 0; k < 8; k++) v[k] = (v[k] > 0.f) ? v[k] : (__expf(v[k]) - 1.f);
    __half2 o[4];
    o[0] = __floats2half2_rn(v[0], v[1]);
    o[1] = __floats2half2_rn(v[2], v[3]);
    o[2] = __floats2half2_rn(v[4], v[5]);
    o[3] = __floats2half2_rn(v[6], v[7]);
    *(float4*)(outp + (size_t)nl * 64 + cc * 8) = *(float4*)o;
  }
}

// ---------------- Final pair dot (fp16 inputs; 32 pairs/block, 8 lanes each) ----------
__global__ void k_dot(const int* __restrict__ uIdx, const int* __restrict__ iIdx,
                      const __half* __restrict__ u_f, const __half* __restrict__ i_f,
                      float* __restrict__ out) {
  int t = threadIdx.x;
  int pair = blockIdx.x * 32 + (t >> 3);
  int cc = t & 7;
  float4 ra = *(const float4*)(u_f + (size_t)uIdx[pair] * 64 + cc * 8);
  float4 rb = *(const float4*)(i_f + (size_t)iIdx[pair] * 64 + cc * 8);
  const __half* ha = (const __half*)&ra;
  const __half* hb = (const __half*)&rb;
  float v = 0.f;
#pragma unroll
  for (int k = 0; k < 8; k++) v += (float)ha[k] * (float)hb[k];
  v += __shfl_xor(v, 1);
  v += __shfl_xor(v, 2);
  v += __shfl_xor(v, 4);
  if (cc == 0) out[pair] = v;
}

extern "C" void kernel_launch(void* const* d_in, const int* in_sizes, int n_in,
                              void* d_out, int out_size, void* d_ws, size_t ws_size,
                              hipStream_t stream) {
  const int* userIdx = (const int*)d_in[0];
  const int* itemIdx = (const int*)d_in[1];
  const int* edge_u = (const int*)d_in[2];
  const int* edge_i = (const int*)d_in[3];
  const float* uEmbd = (const float*)d_in[4];
  const float* iEmbd = (const float*)d_in[5];
  const float* Wu_h = (const float*)d_in[6];
  const float* Wi_h = (const float*)d_in[7];
  const float* a_h = (const float*)d_in[8];
  const float* Wu_out = (const float*)d_in[9];
  const float* Wi_out = (const float*)d_in[10];
  const float* a_out = (const float*)d_in[11];
  float* out = (float*)d_out;

  char* w = (char*)d_ws;
  size_t off = 0;
  auto alloc = [&](size_t bytes) -> void* {
    void* p = w + off;
    off += (bytes + 511) & ~(size_t)511;
    return p;
  };
  int* bcnt = (int*)alloc((size_t)NBK * 4);
  int* cnt = (int*)alloc((size_t)UI_N * 4);
  int* ptr = (int*)alloc((size_t)(UI_N + 1) * 4);
  int* bsum = (int*)alloc(4096);
  int* bbase = (int*)alloc(4096);
  int* col = (int*)alloc((size_t)COL_CAP * 4);
  // fA (pre-agg gather tables) and scores: NOT aliased with storage
  __half* fA_U = (__half*)alloc((size_t)U_N * 64 * 2);
  __half* fA_I = (__half*)alloc((size_t)I_N * 64 * 2);
  __half* s16U = (__half*)alloc((size_t)U_N * 8 * 2);
  __half* s16I = (__half*)alloc((size_t)I_N * 8 * 2);
  __half* s2U = (__half*)alloc((size_t)U_N * 2);
  __half* s2I = (__half*)alloc((size_t)I_N * 2);
  // union tail: storage (24 MB, dead after k_build2) aliases fB (first write: agg L1)
  size_t union_off = off;
  int* storage = (int*)alloc((size_t)NBK * CAP * 4);
  size_t end_storage = off;
  off = union_off;
  __half* fB_U = (__half*)alloc((size_t)U_N * 64 * 2);
  __half* fB_I = (__half*)alloc((size_t)I_N * 64 * 2);
  if (off < end_storage) off = end_storage;

  // CSR/CSC build (exact rows, bucket-level scan)
  hipMemsetAsync(bcnt, 0, (size_t)NBK * 4, stream);
  k_build1<<<NBLD, 1024, 0, stream>>>(edge_u, edge_i, bcnt, storage);
  k_count<<<NBK, 256, 0, stream>>>(bcnt, storage, cnt, bsum);
  k_scanb<<<1, 1024, 0, stream>>>(bsum, bbase);
  k_build2<<<NBK, 256, 0, stream>>>(bcnt, storage, cnt, bbase, ptr, col);

  // Layer 1: mm (fp32 in -> fA fp16 + scores); agg (gather fA -> fB)
  k_mm2<<<NB_U + NB_I, 256, 0, stream>>>(uEmbd, iEmbd, (const __half*)nullptr,
                                         (const __half*)nullptr, Wu_h, Wi_h, a_h, 1,
                                         fA_U, fA_I, s16U, s16I);
  k_agg4<1><<<UI_N * 32 / 256, 256, 0, stream>>>(ptr, col, fA_U, fA_I, fB_U, fB_I,
                                                 s16U, s16I);

  // Layer 2: mm (fB fp16 in -> fA fp16 + s2); agg (gather fA -> fB)
  k_mm2<<<NB_U + NB_I, 256, 0, stream>>>((const float*)nullptr, (const float*)nullptr,
                                         fB_U, fB_I, Wu_out, Wi_out, a_out, 2,
                                         fA_U, fA_I, s2U, s2I);
  k_agg4<2><<<UI_N * 32 / 256, 256, 0, stream>>>(ptr, col, fA_U, fA_I, fB_U, fB_I,
                                                 s2U, s2I);

  // Final per-pair dot (fp16 features)
  k_dot<<<B_N / 32, 256, 0, stream>>>(userIdx, itemIdx, fB_U, fB_I, out);
}

// Round 15
// 339.287 us; speedup vs baseline: 1.2453x; 1.0093x over previous
//
#include <hip/hip_runtime.h>
#include <hip/hip_fp16.h>

#define U_N 50000
#define I_N 100000
#define E_N 1600000
#define B_N 16384
#define UI_N (U_N + I_N)   // 150000
#define NB_U 782           // ceil(50000/64)
#define NB_I 1563          // ceil(100000/64)
#define NBK 586            // ceil(150000/256) buckets, 256 nodes each
#define CAP 10240          // entries per bucket (mean 8192 max, ~22 sigma margin)
#define NBLD 512           // blocks in k_build1
#define CHUNK (E_N / NBLD) // 3125 edges per block
#define COL_CAP 3300000    // >= 2E exact CSR slots
#define MAXACT 32768       // max unique dot nodes (16384 users + 16384 items)

// ---------------- CSR build: phase 1 (block-local binning, packed 4B entries) ---------
__global__ __launch_bounds__(1024) void k_build1(
    const int* __restrict__ eu, const int* __restrict__ ei,
    int* __restrict__ bcnt, int* __restrict__ storage) {
  __shared__ int hist[NBK];
  __shared__ int lbase[NBK];
  __shared__ int loff[NBK];
  int t = threadIdx.x;
  for (int b = t; b < NBK; b += 1024) { hist[b] = 0; loff[b] = 0; }
  __syncthreads();
  int e0 = blockIdx.x * CHUNK;
  int myu[4], myi[4];
  int ne = 0;
#pragma unroll
  for (int k = 0; k < 4; k++) {
    int e = e0 + t + 1024 * k;
    if (e < e0 + CHUNK) {
      int u = eu[e], it = ei[e];
      myu[k] = u;
      myi[k] = it;
      ne = k + 1;
      atomicAdd(&hist[u >> 8], 1);
      atomicAdd(&hist[(U_N + it) >> 8], 1);
    }
  }
  __syncthreads();
  for (int b = t; b < NBK; b += 1024) {
    int h = hist[b];
    lbase[b] = h ? atomicAdd(&bcnt[b], h) : 0;
  }
  __syncthreads();
#pragma unroll
  for (int k = 0; k < 4; k++) {
    if (k < ne) {
      int u = myu[k], it = myi[k];
      int k2 = U_N + it;
      int b1 = u >> 8;
      int s1 = lbase[b1] + atomicAdd(&loff[b1], 1);
      storage[(size_t)b1 * CAP + s1] = ((u & 255) << 17) | it;
      int b2 = k2 >> 8;
      int s2 = lbase[b2] + atomicAdd(&loff[b2], 1);
      storage[(size_t)b2 * CAP + s2] = ((k2 & 255) << 17) | u;
    }
  }
}

// ---------------- per-node degrees + per-bucket totals ----------------
__global__ __launch_bounds__(256) void k_count(const int* __restrict__ bcnt,
                                               const int* __restrict__ storage,
                                               int* __restrict__ cnt,
                                               int* __restrict__ bsum) {
  __shared__ int c[256];
  __shared__ int red[256];
  int b = blockIdx.x;
  int t = threadIdx.x;
  c[t] = 0;
  __syncthreads();
  int n = bcnt[b];
  const int* s = storage + (size_t)b * CAP;
  for (int i = t; i < n; i += 256) atomicAdd(&c[s[i] >> 17], 1);
  __syncthreads();
  int node = b * 256 + t;
  int deg = c[t];
  if (node < UI_N) cnt[node] = deg;
  red[t] = deg;
  __syncthreads();
  for (int off = 128; off > 0; off >>= 1) {
    if (t < off) red[t] += red[t + off];
    __syncthreads();
  }
  if (t == 0) bsum[b] = red[0];
}

// ---------------- single-block exclusive scan over bucket totals ----------------
__global__ __launch_bounds__(1024) void k_scanb(const int* __restrict__ bsum,
                                                int* __restrict__ bbase) {
  __shared__ int sc[1024];
  int t = threadIdx.x;
  int v = (t < NBK) ? bsum[t] : 0;
  sc[t] = v;
  __syncthreads();
  int val = v;
  for (int off = 1; off < 1024; off <<= 1) {
    int x = (t >= off) ? sc[t - off] : 0;
    __syncthreads();
    val += x;
    sc[t] = val;
    __syncthreads();
  }
  if (t < NBK) bbase[t] = val - v;  // exclusive
}

// ---- CSR build: phase 2 (local prefix -> exact ptr, scatter) ------
__global__ __launch_bounds__(256) void k_build2(const int* __restrict__ bcnt,
                                                const int* __restrict__ storage,
                                                const int* __restrict__ cnt,
                                                const int* __restrict__ bbase,
                                                int* __restrict__ ptr,
                                                int* __restrict__ col) {
  __shared__ int pb[256];
  __shared__ int cur[256];
  __shared__ int sc[256];
  int b = blockIdx.x;
  int t = threadIdx.x;
  int node = b * 256 + t;
  int deg = (node < UI_N) ? cnt[node] : 0;
  sc[t] = deg;
  __syncthreads();
  int val = deg;
  for (int off = 1; off < 256; off <<= 1) {
    int x = (t >= off) ? sc[t - off] : 0;
    __syncthreads();
    val += x;
    sc[t] = val;
    __syncthreads();
  }
  int base = bbase[b];
  int myPtr = base + (val - deg);
  pb[t] = myPtr;
  cur[t] = 0;
  if (node < UI_N) ptr[node] = myPtr;
  if (b == NBK - 1 && t == 255) ptr[UI_N] = base + val;
  __syncthreads();
  int n = bcnt[b];
  const int* s = storage + (size_t)b * CAP;
  for (int i = t; i < n; i += 256) {
    int e = s[i];
    int local = e >> 17;
    int slot = pb[local] + atomicAdd(&cur[local], 1);
    col[slot] = e & 0x1FFFF;
  }
}

// ---------------- Active-node flag + compaction (for layer-2 agg) ----------------
__global__ void k_flag(const int* __restrict__ uIdx, const int* __restrict__ iIdx,
                       int* __restrict__ flag) {
  int b = blockIdx.x * blockDim.x + threadIdx.x;
  if (b < B_N) {
    flag[uIdx[b]] = 1;
    flag[U_N + iIdx[b]] = 1;
  }
}

__global__ void k_compact(const int* __restrict__ flag, int* __restrict__ list,
                          int* __restrict__ nm) {
  int node = blockIdx.x * 256 + threadIdx.x;
  bool f = (node < UI_N) && flag[node];
  unsigned long long mask = __ballot(f);
  int lane = threadIdx.x & 63;
  int cnt = __popcll(mask);
  int base = 0;
  if (lane == 0 && cnt) base = atomicAdd(nm, cnt);
  base = __shfl(base, 0);
  int off = __popcll(mask & ((1ull << lane) - 1ull));
  if (f) list[base + off] = node;
}

// ---------------- Fused matmul + attention scores (users + items, one launch) ---------
__global__ __launch_bounds__(256) void k_mm2(
    const float* __restrict__ Xu32, const float* __restrict__ Xi32,
    const __half* __restrict__ Xu16, const __half* __restrict__ Xi16,
    const float* __restrict__ Wu, const float* __restrict__ Wi,
    const float* __restrict__ a, int layer,
    __half* __restrict__ fA_U, __half* __restrict__ fA_I,
    __half* __restrict__ s16U, __half* __restrict__ s16I) {
  __shared__ float Wl[4096];
  __shared__ float Xs[4096];
  const bool isU = blockIdx.x < NB_U;
  const int N = isU ? U_N : I_N;
  const int base = (isU ? blockIdx.x : blockIdx.x - NB_U) * 64;
  const float* W = isU ? Wu : Wi;
  __half* f16 = isU ? fA_U : fA_I;
  __half* s16 = isU ? s16U : s16I;
  const int aoff = (layer == 1) ? (isU ? 0 : 8) : (isU ? 0 : 64);
  int t = threadIdx.x;

  if (layer == 1) {
#pragma unroll
    for (int k = 0; k < 4; k++) {
      int i = t + 256 * k;
      int h = i >> 7, d = (i >> 1) & 63, half = i & 1;
      float4 v = *(const float4*)(W + h * 512 + d * 8 + half * 4);
      *(float4*)(Wl + d * 64 + h * 8 + half * 4) = v;
    }
    const float* X = isU ? Xu32 : Xi32;
#pragma unroll
    for (int k = 0; k < 4; k++) {
      int i = t + 256 * k;
      int r = i >> 4, ch = i & 15;
      int node = base + r;
      float4 v = make_float4(0.f, 0.f, 0.f, 0.f);
      if (node < N) v = *(const float4*)(X + (size_t)node * 64 + ch * 4);
      *(float4*)(Xs + r * 64 + ch * 4) = v;
    }
  } else {
#pragma unroll
    for (int k = 0; k < 4; k++) {
      int i = t + 256 * k;
      *(float4*)(Wl + i * 4) = *(const float4*)(W + i * 4);
    }
    const __half* X = isU ? Xu16 : Xi16;
#pragma unroll
    for (int k = 0; k < 4; k++) {
      int i = t + 256 * k;
      int r = i >> 4, ch = i & 15;
      int node = base + r;
      float4 v = make_float4(0.f, 0.f, 0.f, 0.f);
      if (node < N) {
        const __half2* hp = (const __half2*)(X + (size_t)node * 64 + ch * 4);
        float2 f0 = __half22float2(hp[0]);
        float2 f1 = __half22float2(hp[1]);
        v = make_float4(f0.x, f0.y, f1.x, f1.y);
      }
      *(float4*)(Xs + r * 64 + ch * 4) = v;
    }
  }
  __syncthreads();

  const int c0 = t & 31;
  const int rb = t >> 5;
  float acc0[8], acc1[8];
#pragma unroll
  for (int k = 0; k < 8; k++) { acc0[k] = 0.f; acc1[k] = 0.f; }

  for (int d0 = 0; d0 < 64; d0 += 4) {
    float2 wA = *(float2*)(Wl + (d0 + 0) * 64 + 2 * c0);
    float2 wB = *(float2*)(Wl + (d0 + 1) * 64 + 2 * c0);
    float2 wC = *(float2*)(Wl + (d0 + 2) * 64 + 2 * c0);
    float2 wD = *(float2*)(Wl + (d0 + 3) * 64 + 2 * c0);
#pragma unroll
    for (int k = 0; k < 8; k++) {
      float4 x = *(float4*)(Xs + (rb + 8 * k) * 64 + d0);
      acc0[k] += x.x * wA.x + x.y * wB.x + x.z * wC.x + x.w * wD.x;
      acc1[k] += x.x * wA.y + x.y * wB.y + x.z * wC.y + x.w * wD.y;
    }
  }

  float av0, av1;
  if (layer == 1) {
    int h = c0 >> 2, j = 2 * (c0 & 3);
    av0 = a[h * 16 + aoff + j];
    av1 = a[h * 16 + aoff + j + 1];
  } else {
    av0 = a[aoff + 2 * c0];
    av1 = a[aoff + 2 * c0 + 1];
  }
#pragma unroll
  for (int k = 0; k < 8; k++) {
    int node = base + rb + 8 * k;
    float s = acc0[k] * av0 + acc1[k] * av1;
    s += __shfl_xor(s, 1);
    s += __shfl_xor(s, 2);
    if (layer != 1) {
      s += __shfl_xor(s, 4);
      s += __shfl_xor(s, 8);
      s += __shfl_xor(s, 16);
    }
    if (node < N) {
      float2 f;
      f.x = acc0[k];
      f.y = acc1[k];
      *(__half2*)(f16 + (size_t)node * 64 + 2 * c0) = __float22half2_rn(f);
      if (layer == 1) {
        if ((c0 & 3) == 0) s16[node * 8 + (c0 >> 2)] = __float2half_rn(s);
      } else {
        if (c0 == 0) s16[node] = __float2half_rn(s);
      }
    }
  }
}

// ---------------- Fused aggregation: TWO nodes per wave, unroll-4 ----------------
// Half-wave (32 lanes = 4 edge groups x 8 cc) per node; fp16 gathers; fused ELU.
// LAYER==2 runs over the compacted active-node list only.
template <int LAYER>
__global__ __launch_bounds__(256) void k_agg4(
    const int* __restrict__ ptr, const int* __restrict__ col,
    const __half* __restrict__ fA_U, const __half* __restrict__ fA_I,
    __half* __restrict__ fB_U, __half* __restrict__ fB_I,
    const __half* __restrict__ s16U, const __half* __restrict__ s16I,
    const int* __restrict__ list, const int* __restrict__ nm) {
  int gid = blockIdx.x * blockDim.x + threadIdx.x;
  int wv = gid >> 6;
  int l = threadIdx.x & 63;
  int half = l >> 5;
  int idx = wv * 2 + half;
  bool act = true;
  int n;
  if (LAYER == 2) {
    act = idx < *nm;
    n = list[act ? idx : 0];
  } else {
    n = idx;                         // UI_N even; pairs never straddle U/I
  }
  int lh = l & 31;
  int g = lh >> 3;
  int cc = lh & 7;
  bool isU = n < U_N;
  int nl = isU ? n : n - U_N;
  const char* nbrF = (const char*)(isU ? fA_I : fA_U);
  const char* nbrS = (const char*)(isU ? s16I : s16U);
  const __half* selfS = isU ? s16U : s16I;
  const __half* selfF = isU ? fA_U : fA_I;
  __half* outp = isU ? fB_U : fB_I;
  const char* colc = (const char*)col;

  int beg = ptr[n], endA = ptr[n + 1];
  int deg = endA - beg;
  unsigned coff = ((unsigned)(beg + g)) << 2;
  const unsigned begb = (unsigned)beg << 2;
  const unsigned fsh = (unsigned)cc << 4;
  const unsigned ssh = (LAYER == 1) ? ((unsigned)cc << 1) : 0u;
  float sself = (LAYER == 1) ? __half2float(selfS[(size_t)nl * 8 + cc])
                             : __half2float(selfS[nl]);
  float acc[8];
#pragma unroll
  for (int k = 0; k < 8; k++) acc[k] = 0.f;
  float wsum = 0.f;

  auto edge = [&](unsigned off) {
    int nb = *(const int*)(colc + off);
    unsigned so = (LAYER == 1) ? (((unsigned)nb << 4) + ssh) : ((unsigned)nb << 1);
    float x = sself + __half2float(*(const __half*)(nbrS + so));
    float4 r = *(const float4*)(nbrF + (((unsigned)nb << 7) + fsh));
    float w = __expf(-fmaxf(x, 0.2f * x));
    wsum += w;
    const __half* h = (const __half*)&r;
#pragma unroll
    for (int k = 0; k < 8; k++) acc[k] += w * (float)h[k];
  };
  auto edgem = [&](unsigned off, bool valid) {
    unsigned o = valid ? off : begb;
    int nb = *(const int*)(colc + o);
    unsigned so = (LAYER == 1) ? (((unsigned)nb << 4) + ssh) : ((unsigned)nb << 1);
    float x = sself + __half2float(*(const __half*)(nbrS + so));
    float4 r = *(const float4*)(nbrF + (((unsigned)nb << 7) + fsh));
    float w = valid ? __expf(-fmaxf(x, 0.2f * x)) : 0.f;
    wsum += w;
    const __half* h = (const __half*)&r;
#pragma unroll
    for (int k = 0; k < 8; k++) acc[k] += w * (float)h[k];
  };

  int q = deg >> 4;
  for (; q > 0; q--) {
    edge(coff);
    edge(coff + 16);
    edge(coff + 32);
    edge(coff + 48);
    coff += 64;
  }
  int rem = deg & 15;
  if (rem) {
    edgem(coff, g < rem);
    edgem(coff + 16, (4 + g) < rem);
    edgem(coff + 32, (8 + g) < rem);
    edgem(coff + 48, (12 + g) < rem);
  }

#pragma unroll
  for (int k = 0; k < 8; k++) {
    acc[k] += __shfl_xor(acc[k], 8);
    acc[k] += __shfl_xor(acc[k], 16);
  }
  wsum += __shfl_xor(wsum, 8);
  wsum += __shfl_xor(wsum, 16);

  if (lh < 8 && act) {
    float4 raw = *(const float4*)(selfF + (size_t)nl * 64 + cc * 8);
    const __half2* sp = (const __half2*)&raw;
    float2 s0 = __half22float2(sp[0]);
    float2 s1 = __half22float2(sp[1]);
    float2 s2 = __half22float2(sp[2]);
    float2 s3 = __half22float2(sp[3]);
    float v[8] = {s0.x, s0.y, s1.x, s1.y, s2.x, s2.y, s3.x, s3.y};
    if (deg > 0) {
      float inv = 1.f / wsum;
#pragma unroll
      for (int k = 0; k < 8; k++) v[k] += acc[k] * inv;
    }
#pragma unroll
    for (int k = 0; k < 8; k++) v[k] = (v[k] > 0.f) ? v[k] : (__expf(v[k]) - 1.f);
    __half2 o[4];
    o[0] = __floats2half2_rn(v[0], v[1]);
    o[1] = __floats2half2_rn(v[2], v[3]);
    o[2] = __floats2half2_rn(v[4], v[5]);
    o[3] = __floats2half2_rn(v[6], v[7]);
    *(float4*)(outp + (size_t)nl * 64 + cc * 8) = *(float4*)o;
  }
}

// ---------------- Final pair dot (fp16 inputs; 32 pairs/block, 8 lanes each) ----------
__global__ void k_dot(const int* __restrict__ uIdx, const int* __restrict__ iIdx,
                      const __half* __restrict__ u_f, const __half* __restrict__ i_f,
                      float* __restrict__ out) {
  int t = threadIdx.x;
  int pair = blockIdx.x * 32 + (t >> 3);
  int cc = t & 7;
  float4 ra = *(const float4*)(u_f + (size_t)uIdx[pair] * 64 + cc * 8);
  float4 rb = *(const float4*)(i_f + (size_t)iIdx[pair] * 64 + cc * 8);
  const __half* ha = (const __half*)&ra;
  const __half* hb = (const __half*)&rb;
  float v = 0.f;
#pragma unroll
  for (int k = 0; k < 8; k++) v += (float)ha[k] * (float)hb[k];
  v += __shfl_xor(v, 1);
  v += __shfl_xor(v, 2);
  v += __shfl_xor(v, 4);
  if (cc == 0) out[pair] = v;
}

extern "C" void kernel_launch(void* const* d_in, const int* in_sizes, int n_in,
                              void* d_out, int out_size, void* d_ws, size_t ws_size,
                              hipStream_t stream) {
  const int* userIdx = (const int*)d_in[0];
  const int* itemIdx = (const int*)d_in[1];
  const int* edge_u = (const int*)d_in[2];
  const int* edge_i = (const int*)d_in[3];
  const float* uEmbd = (const float*)d_in[4];
  const float* iEmbd = (const float*)d_in[5];
  const float* Wu_h = (const float*)d_in[6];
  const float* Wi_h = (const float*)d_in[7];
  const float* a_h = (const float*)d_in[8];
  const float* Wu_out = (const float*)d_in[9];
  const float* Wi_out = (const float*)d_in[10];
  const float* a_out = (const float*)d_in[11];
  float* out = (float*)d_out;

  char* w = (char*)d_ws;
  size_t off = 0;
  auto alloc = [&](size_t bytes) -> void* {
    void* p = w + off;
    off += (bytes + 511) & ~(size_t)511;
    return p;
  };
  // zero-init block: bcnt[NBK] | nm[1..pad 16] | flag[UI_N] — one memset
  int* bcnt = (int*)alloc((size_t)(NBK + 16 + UI_N) * 4);
  int* nm = bcnt + NBK;
  int* flag = bcnt + NBK + 16;
  int* cnt = (int*)alloc((size_t)UI_N * 4);
  int* ptr = (int*)alloc((size_t)(UI_N + 1) * 4);
  int* bsum = (int*)alloc(4096);
  int* bbase = (int*)alloc(4096);
  int* list = (int*)alloc((size_t)MAXACT * 4);
  int* col = (int*)alloc((size_t)COL_CAP * 4);
  // fA (pre-agg gather tables) and scores: NOT aliased with storage
  __half* fA_U = (__half*)alloc((size_t)U_N * 64 * 2);
  __half* fA_I = (__half*)alloc((size_t)I_N * 64 * 2);
  __half* s16U = (__half*)alloc((size_t)U_N * 8 * 2);
  __half* s16I = (__half*)alloc((size_t)I_N * 8 * 2);
  __half* s2U = (__half*)alloc((size_t)U_N * 2);
  __half* s2I = (__half*)alloc((size_t)I_N * 2);
  // union tail: storage (24 MB, dead after k_build2) aliases fB (first write: agg L1)
  size_t union_off = off;
  int* storage = (int*)alloc((size_t)NBK * CAP * 4);
  size_t end_storage = off;
  off = union_off;
  __half* fB_U = (__half*)alloc((size_t)U_N * 64 * 2);
  __half* fB_I = (__half*)alloc((size_t)I_N * 64 * 2);
  if (off < end_storage) off = end_storage;

  // CSR/CSC build (exact rows, bucket-level scan) + active-node compaction
  hipMemsetAsync(bcnt, 0, (size_t)(NBK + 16 + UI_N) * 4, stream);
  k_build1<<<NBLD, 1024, 0, stream>>>(edge_u, edge_i, bcnt, storage);
  k_count<<<NBK, 256, 0, stream>>>(bcnt, storage, cnt, bsum);
  k_scanb<<<1, 1024, 0, stream>>>(bsum, bbase);
  k_build2<<<NBK, 256, 0, stream>>>(bcnt, storage, cnt, bbase, ptr, col);
  k_flag<<<(B_N + 255) / 256, 256, 0, stream>>>(userIdx, itemIdx, flag);
  k_compact<<<NBK, 256, 0, stream>>>(flag, list, nm);

  // Layer 1: mm (fp32 in -> fA fp16 + scores); agg over ALL nodes (fA -> fB)
  k_mm2<<<NB_U + NB_I, 256, 0, stream>>>(uEmbd, iEmbd, (const __half*)nullptr,
                                         (const __half*)nullptr, Wu_h, Wi_h, a_h, 1,
                                         fA_U, fA_I, s16U, s16I);
  k_agg4<1><<<UI_N * 32 / 256, 256, 0, stream>>>(ptr, col, fA_U, fA_I, fB_U, fB_I,
                                                 s16U, s16I, nullptr, nullptr);

  // Layer 2: mm over ALL nodes (fB -> fA + s2); agg over ACTIVE nodes only
  k_mm2<<<NB_U + NB_I, 256, 0, stream>>>((const float*)nullptr, (const float*)nullptr,
                                         fB_U, fB_I, Wu_out, Wi_out, a_out, 2,
                                         fA_U, fA_I, s2U, s2I);
  k_agg4<2><<<MAXACT * 32 / 256, 256, 0, stream>>>(ptr, col, fA_U, fA_I, fB_U, fB_I,
                                                   s2U, s2I, list, nm);

  // Final per-pair dot (fp16 features)
  k_dot<<<B_N / 32, 256, 0, stream>>>(userIdx, itemIdx, fB_U, fB_I, out);
}

// Round 16
// 330.142 us; speedup vs baseline: 1.2798x; 1.0277x over previous
//
#include <hip/hip_runtime.h>
#include <hip/hip_fp16.h>

#define U_N 50000
#define I_N 100000
#define E_N 1600000
#define B_N 16384
#define UI_N (U_N + I_N)   // 150000
#define NB_U 782           // ceil(50000/64)
#define NB_I 1563          // ceil(100000/64)
#define NBK 586            // ceil(150000/256) buckets, 256 nodes each
#define CAP 10240          // entries per bucket (mean 8192 max, ~22 sigma margin)
#define NBLD 512           // blocks in k_build1
#define CHUNK (E_N / NBLD) // 3125 edges per block
#define COL_CAP 3300000    // >= 2E exact CSR slots
#define MAXACT 32768       // max unique dot nodes (16384 users + 16384 items)

// ---------------- CSR build: phase 1 (block-local binning, packed 4B entries) ---------
__global__ __launch_bounds__(1024) void k_build1(
    const int* __restrict__ eu, const int* __restrict__ ei,
    int* __restrict__ bcnt, int* __restrict__ storage) {
  __shared__ int hist[NBK];
  __shared__ int lbase[NBK];
  __shared__ int loff[NBK];
  int t = threadIdx.x;
  for (int b = t; b < NBK; b += 1024) { hist[b] = 0; loff[b] = 0; }
  __syncthreads();
  int e0 = blockIdx.x * CHUNK;
  int myu[4], myi[4];
  int ne = 0;
#pragma unroll
  for (int k = 0; k < 4; k++) {
    int e = e0 + t + 1024 * k;
    if (e < e0 + CHUNK) {
      int u = eu[e], it = ei[e];
      myu[k] = u;
      myi[k] = it;
      ne = k + 1;
      atomicAdd(&hist[u >> 8], 1);
      atomicAdd(&hist[(U_N + it) >> 8], 1);
    }
  }
  __syncthreads();
  for (int b = t; b < NBK; b += 1024) {
    int h = hist[b];
    lbase[b] = h ? atomicAdd(&bcnt[b], h) : 0;
  }
  __syncthreads();
#pragma unroll
  for (int k = 0; k < 4; k++) {
    if (k < ne) {
      int u = myu[k], it = myi[k];
      int k2 = U_N + it;
      int b1 = u >> 8;
      int s1 = lbase[b1] + atomicAdd(&loff[b1], 1);
      storage[(size_t)b1 * CAP + s1] = ((u & 255) << 17) | it;
      int b2 = k2 >> 8;
      int s2 = lbase[b2] + atomicAdd(&loff[b2], 1);
      storage[(size_t)b2 * CAP + s2] = ((k2 & 255) << 17) | u;
    }
  }
}

// ---------------- single-block exclusive scan over bucket entry counts ----------------
// bucket slot total == bucket entry count (each entry is one directed edge slot)
__global__ __launch_bounds__(1024) void k_scanb(const int* __restrict__ bcnt,
                                                int* __restrict__ bbase) {
  __shared__ int sc[1024];
  int t = threadIdx.x;
  int v = (t < NBK) ? bcnt[t] : 0;
  sc[t] = v;
  __syncthreads();
  int val = v;
  for (int off = 1; off < 1024; off <<= 1) {
    int x = (t >= off) ? sc[t - off] : 0;
    __syncthreads();
    val += x;
    sc[t] = val;
    __syncthreads();
  }
  if (t < NBK) bbase[t] = val - v;  // exclusive
}

// ---- CSR build: phase 2 FUSED (count pass -> LDS prefix -> ptr write -> scatter) ----
__global__ __launch_bounds__(256) void k_build2(const int* __restrict__ bcnt,
                                                const int* __restrict__ storage,
                                                const int* __restrict__ bbase,
                                                int* __restrict__ ptr,
                                                int* __restrict__ col) {
  __shared__ int c[256];
  __shared__ int sc[256];
  __shared__ int pb[256];
  __shared__ int cur[256];
  int b = blockIdx.x;
  int t = threadIdx.x;
  c[t] = 0;
  __syncthreads();
  int n = bcnt[b];
  const int* s = storage + (size_t)b * CAP;
  for (int i = t; i < n; i += 256) atomicAdd(&c[s[i] >> 17], 1);
  __syncthreads();
  int deg = c[t];           // 0 for node ids >= UI_N (cannot occur as keys)
  sc[t] = deg;
  __syncthreads();
  int val = deg;
  for (int off = 1; off < 256; off <<= 1) {
    int x = (t >= off) ? sc[t - off] : 0;
    __syncthreads();
    val += x;
    sc[t] = val;
    __syncthreads();
  }
  int base = bbase[b];
  int myPtr = base + (val - deg);
  pb[t] = myPtr;
  cur[t] = 0;
  int node = b * 256 + t;
  if (node < UI_N) ptr[node] = myPtr;
  if (b == NBK - 1 && t == 255) ptr[UI_N] = base + val;
  __syncthreads();
  for (int i = t; i < n; i += 256) {   // storage re-read is L2-hot (same block)
    int e = s[i];
    int local = e >> 17;
    int slot = pb[local] + atomicAdd(&cur[local], 1);
    col[slot] = e & 0x1FFFF;
  }
}

// ---------------- Active-node flag + compaction (for layer-2 agg) ----------------
__global__ void k_flag(const int* __restrict__ uIdx, const int* __restrict__ iIdx,
                       int* __restrict__ flag) {
  int b = blockIdx.x * blockDim.x + threadIdx.x;
  if (b < B_N) {
    flag[uIdx[b]] = 1;
    flag[U_N + iIdx[b]] = 1;
  }
}

__global__ void k_compact(const int* __restrict__ flag, int* __restrict__ list,
                          int* __restrict__ nm) {
  int node = blockIdx.x * 256 + threadIdx.x;
  bool f = (node < UI_N) && flag[node];
  unsigned long long mask = __ballot(f);
  int lane = threadIdx.x & 63;
  int cnt = __popcll(mask);
  int base = 0;
  if (lane == 0 && cnt) base = atomicAdd(nm, cnt);
  base = __shfl(base, 0);
  int off = __popcll(mask & ((1ull << lane) - 1ull));
  if (f) list[base + off] = node;
}

// ---------------- Fused matmul + attention scores (users + items, one launch) ---------
__global__ __launch_bounds__(256) void k_mm2(
    const float* __restrict__ Xu32, const float* __restrict__ Xi32,
    const __half* __restrict__ Xu16, const __half* __restrict__ Xi16,
    const float* __restrict__ Wu, const float* __restrict__ Wi,
    const float* __restrict__ a, int layer,
    __half* __restrict__ fA_U, __half* __restrict__ fA_I,
    __half* __restrict__ s16U, __half* __restrict__ s16I) {
  __shared__ float Wl[4096];
  __shared__ float Xs[4096];
  const bool isU = blockIdx.x < NB_U;
  const int N = isU ? U_N : I_N;
  const int base = (isU ? blockIdx.x : blockIdx.x - NB_U) * 64;
  const float* W = isU ? Wu : Wi;
  __half* f16 = isU ? fA_U : fA_I;
  __half* s16 = isU ? s16U : s16I;
  const int aoff = (layer == 1) ? (isU ? 0 : 8) : (isU ? 0 : 64);
  int t = threadIdx.x;

  if (layer == 1) {
#pragma unroll
    for (int k = 0; k < 4; k++) {
      int i = t + 256 * k;
      int h = i >> 7, d = (i >> 1) & 63, half = i & 1;
      float4 v = *(const float4*)(W + h * 512 + d * 8 + half * 4);
      *(float4*)(Wl + d * 64 + h * 8 + half * 4) = v;
    }
    const float* X = isU ? Xu32 : Xi32;
#pragma unroll
    for (int k = 0; k < 4; k++) {
      int i = t + 256 * k;
      int r = i >> 4, ch = i & 15;
      int node = base + r;
      float4 v = make_float4(0.f, 0.f, 0.f, 0.f);
      if (node < N) v = *(const float4*)(X + (size_t)node * 64 + ch * 4);
      *(float4*)(Xs + r * 64 + ch * 4) = v;
    }
  } else {
#pragma unroll
    for (int k = 0; k < 4; k++) {
      int i = t + 256 * k;
      *(float4*)(Wl + i * 4) = *(const float4*)(W + i * 4);
    }
    const __half* X = isU ? Xu16 : Xi16;
#pragma unroll
    for (int k = 0; k < 4; k++) {
      int i = t + 256 * k;
      int r = i >> 4, ch = i & 15;
      int node = base + r;
      float4 v = make_float4(0.f, 0.f, 0.f, 0.f);
      if (node < N) {
        const __half2* hp = (const __half2*)(X + (size_t)node * 64 + ch * 4);
        float2 f0 = __half22float2(hp[0]);
        float2 f1 = __half22float2(hp[1]);
        v = make_float4(f0.x, f0.y, f1.x, f1.y);
      }
      *(float4*)(Xs + r * 64 + ch * 4) = v;
    }
  }
  __syncthreads();

  const int c0 = t & 31;
  const int rb = t >> 5;
  float acc0[8], acc1[8];
#pragma unroll
  for (int k = 0; k < 8; k++) { acc0[k] = 0.f; acc1[k] = 0.f; }

  for (int d0 = 0; d0 < 64; d0 += 4) {
    float2 wA = *(float2*)(Wl + (d0 + 0) * 64 + 2 * c0);
    float2 wB = *(float2*)(Wl + (d0 + 1) * 64 + 2 * c0);
    float2 wC = *(float2*)(Wl + (d0 + 2) * 64 + 2 * c0);
    float2 wD = *(float2*)(Wl + (d0 + 3) * 64 + 2 * c0);
#pragma unroll
    for (int k = 0; k < 8; k++) {
      float4 x = *(float4*)(Xs + (rb + 8 * k) * 64 + d0);
      acc0[k] += x.x * wA.x + x.y * wB.x + x.z * wC.x + x.w * wD.x;
      acc1[k] += x.x * wA.y + x.y * wB.y + x.z * wC.y + x.w * wD.y;
    }
  }

  float av0, av1;
  if (layer == 1) {
    int h = c0 >> 2, j = 2 * (c0 & 3);
    av0 = a[h * 16 + aoff + j];
    av1 = a[h * 16 + aoff + j + 1];
  } else {
    av0 = a[aoff + 2 * c0];
    av1 = a[aoff + 2 * c0 + 1];
  }
#pragma unroll
  for (int k = 0; k < 8; k++) {
    int node = base + rb + 8 * k;
    float s = acc0[k] * av0 + acc1[k] * av1;
    s += __shfl_xor(s, 1);
    s += __shfl_xor(s, 2);
    if (layer != 1) {
      s += __shfl_xor(s, 4);
      s += __shfl_xor(s, 8);
      s += __shfl_xor(s, 16);
    }
    if (node < N) {
      float2 f;
      f.x = acc0[k];
      f.y = acc1[k];
      *(__half2*)(f16 + (size_t)node * 64 + 2 * c0) = __float22half2_rn(f);
      if (layer == 1) {
        if ((c0 & 3) == 0) s16[node * 8 + (c0 >> 2)] = __float2half_rn(s);
      } else {
        if (c0 == 0) s16[node] = __float2half_rn(s);
      }
    }
  }
}

// ---------------- Fused aggregation body: TWO nodes per wave, unroll-4 ----------------
template <int LAYER>
__device__ __forceinline__ void agg_body(
    const int* __restrict__ ptr, const int* __restrict__ col,
    const __half* __restrict__ fA_U, const __half* __restrict__ fA_I,
    __half* __restrict__ fB_U, __half* __restrict__ fB_I,
    const __half* __restrict__ s16U, const __half* __restrict__ s16I,
    const int* __restrict__ list, const int* __restrict__ nm) {
  int gid = blockIdx.x * blockDim.x + threadIdx.x;
  int wv = gid >> 6;
  int l = threadIdx.x & 63;
  int half = l >> 5;
  int idx = wv * 2 + half;
  bool act = true;
  int n;
  if (LAYER == 2) {
    act = idx < *nm;
    n = list[act ? idx : 0];
  } else {
    n = idx;                         // UI_N even; pairs never straddle U/I
  }
  int lh = l & 31;
  int g = lh >> 3;
  int cc = lh & 7;
  bool isU = n < U_N;
  int nl = isU ? n : n - U_N;
  const char* nbrF = (const char*)(isU ? fA_I : fA_U);
  const char* nbrS = (const char*)(isU ? s16I : s16U);
  const __half* selfS = isU ? s16U : s16I;
  const __half* selfF = isU ? fA_U : fA_I;
  __half* outp = isU ? fB_U : fB_I;
  const char* colc = (const char*)col;

  int beg = ptr[n], endA = ptr[n + 1];
  int deg = endA - beg;
  unsigned coff = ((unsigned)(beg + g)) << 2;
  const unsigned begb = (unsigned)beg << 2;
  const unsigned fsh = (unsigned)cc << 4;
  const unsigned ssh = (LAYER == 1) ? ((unsigned)cc << 1) : 0u;
  float sself = (LAYER == 1) ? __half2float(selfS[(size_t)nl * 8 + cc])
                             : __half2float(selfS[nl]);
  float acc[8];
#pragma unroll
  for (int k = 0; k < 8; k++) acc[k] = 0.f;
  float wsum = 0.f;

  auto edge = [&](unsigned off) {
    int nb = *(const int*)(colc + off);
    unsigned so = (LAYER == 1) ? (((unsigned)nb << 4) + ssh) : ((unsigned)nb << 1);
    float x = sself + __half2float(*(const __half*)(nbrS + so));
    float4 r = *(const float4*)(nbrF + (((unsigned)nb << 7) + fsh));
    float w = __expf(-fmaxf(x, 0.2f * x));
    wsum += w;
    const __half* h = (const __half*)&r;
#pragma unroll
    for (int k = 0; k < 8; k++) acc[k] += w * (float)h[k];
  };
  auto edgem = [&](unsigned off, bool valid) {
    unsigned o = valid ? off : begb;
    int nb = *(const int*)(colc + o);
    unsigned so = (LAYER == 1) ? (((unsigned)nb << 4) + ssh) : ((unsigned)nb << 1);
    float x = sself + __half2float(*(const __half*)(nbrS + so));
    float4 r = *(const float4*)(nbrF + (((unsigned)nb << 7) + fsh));
    float w = valid ? __expf(-fmaxf(x, 0.2f * x)) : 0.f;
    wsum += w;
    const __half* h = (const __half*)&r;
#pragma unroll
    for (int k = 0; k < 8; k++) acc[k] += w * (float)h[k];
  };

  int q = deg >> 4;
  for (; q > 0; q--) {
    edge(coff);
    edge(coff + 16);
    edge(coff + 32);
    edge(coff + 48);
    coff += 64;
  }
  int rem = deg & 15;
  if (rem) {
    edgem(coff, g < rem);
    edgem(coff + 16, (4 + g) < rem);
    edgem(coff + 32, (8 + g) < rem);
    edgem(coff + 48, (12 + g) < rem);
  }

#pragma unroll
  for (int k = 0; k < 8; k++) {
    acc[k] += __shfl_xor(acc[k], 8);
    acc[k] += __shfl_xor(acc[k], 16);
  }
  wsum += __shfl_xor(wsum, 8);
  wsum += __shfl_xor(wsum, 16);

  if (lh < 8 && act) {
    float4 raw = *(const float4*)(selfF + (size_t)nl * 64 + cc * 8);
    const __half2* sp = (const __half2*)&raw;
    float2 s0 = __half22float2(sp[0]);
    float2 s1 = __half22float2(sp[1]);
    float2 s2 = __half22float2(sp[2]);
    float2 s3 = __half22float2(sp[3]);
    float v[8] = {s0.x, s0.y, s1.x, s1.y, s2.x, s2.y, s3.x, s3.y};
    if (deg > 0) {
      float inv = 1.f / wsum;
#pragma unroll
      for (int k = 0; k < 8; k++) v[k] += acc[k] * inv;
    }
#pragma unroll
    for (int k = 0; k < 8; k++) v[k] = (v[k] > 0.f) ? v[k] : (__expf(v[k]) - 1.f);
    __half2 o[4];
    o[0] = __floats2half2_rn(v[0], v[1]);
    o[1] = __floats2half2_rn(v[2], v[3]);
    o[2] = __floats2half2_rn(v[4], v[5]);
    o[3] = __floats2half2_rn(v[6], v[7]);
    *(float4*)(outp + (size_t)nl * 64 + cc * 8) = *(float4*)o;
  }
}

// Distinctly-named instantiations (rocprof attribution)
__global__ __launch_bounds__(256) void k_aggL1(
    const int* __restrict__ ptr, const int* __restrict__ col,
    const __half* __restrict__ fA_U, const __half* __restrict__ fA_I,
    __half* __restrict__ fB_U, __half* __restrict__ fB_I,
    const __half* __restrict__ s16U, const __half* __restrict__ s16I) {
  agg_body<1>(ptr, col, fA_U, fA_I, fB_U, fB_I, s16U, s16I, nullptr, nullptr);
}

__global__ __launch_bounds__(256) void k_aggL2(
    const int* __restrict__ ptr, const int* __restrict__ col,
    const __half* __restrict__ fA_U, const __half* __restrict__ fA_I,
    __half* __restrict__ fB_U, __half* __restrict__ fB_I,
    const __half* __restrict__ s2U, const __half* __restrict__ s2I,
    const int* __restrict__ list, const int* __restrict__ nm) {
  agg_body<2>(ptr, col, fA_U, fA_I, fB_U, fB_I, s2U, s2I, list, nm);
}

// ---------------- Final pair dot (fp16 inputs; 32 pairs/block, 8 lanes each) ----------
__global__ void k_dot(const int* __restrict__ uIdx, const int* __restrict__ iIdx,
                      const __half* __restrict__ u_f, const __half* __restrict__ i_f,
                      float* __restrict__ out) {
  int t = threadIdx.x;
  int pair = blockIdx.x * 32 + (t >> 3);
  int cc = t & 7;
  float4 ra = *(const float4*)(u_f + (size_t)uIdx[pair] * 64 + cc * 8);
  float4 rb = *(const float4*)(i_f + (size_t)iIdx[pair] * 64 + cc * 8);
  const __half* ha = (const __half*)&ra;
  const __half* hb = (const __half*)&rb;
  float v = 0.f;
#pragma unroll
  for (int k = 0; k < 8; k++) v += (float)ha[k] * (float)hb[k];
  v += __shfl_xor(v, 1);
  v += __shfl_xor(v, 2);
  v += __shfl_xor(v, 4);
  if (cc == 0) out[pair] = v;
}

extern "C" void kernel_launch(void* const* d_in, const int* in_sizes, int n_in,
                              void* d_out, int out_size, void* d_ws, size_t ws_size,
                              hipStream_t stream) {
  const int* userIdx = (const int*)d_in[0];
  const int* itemIdx = (const int*)d_in[1];
  const int* edge_u = (const int*)d_in[2];
  const int* edge_i = (const int*)d_in[3];
  const float* uEmbd = (const float*)d_in[4];
  const float* iEmbd = (const float*)d_in[5];
  const float* Wu_h = (const float*)d_in[6];
  const float* Wi_h = (const float*)d_in[7];
  const float* a_h = (const float*)d_in[8];
  const float* Wu_out = (const float*)d_in[9];
  const float* Wi_out = (const float*)d_in[10];
  const float* a_out = (const float*)d_in[11];
  float* out = (float*)d_out;

  char* w = (char*)d_ws;
  size_t off = 0;
  auto alloc = [&](size_t bytes) -> void* {
    void* p = w + off;
    off += (bytes + 511) & ~(size_t)511;
    return p;
  };
  // zero-init block: bcnt[NBK] | nm[1..pad 16] | flag[UI_N] — one memset
  int* bcnt = (int*)alloc((size_t)(NBK + 16 + UI_N) * 4);
  int* nm = bcnt + NBK;
  int* flag = bcnt + NBK + 16;
  int* ptr = (int*)alloc((size_t)(UI_N + 1) * 4);
  int* bbase = (int*)alloc(4096);
  int* list = (int*)alloc((size_t)MAXACT * 4);
  int* col = (int*)alloc((size_t)COL_CAP * 4);
  // fA (pre-agg gather tables) and scores: NOT aliased with storage
  __half* fA_U = (__half*)alloc((size_t)U_N * 64 * 2);
  __half* fA_I = (__half*)alloc((size_t)I_N * 64 * 2);
  __half* s16U = (__half*)alloc((size_t)U_N * 8 * 2);
  __half* s16I = (__half*)alloc((size_t)I_N * 8 * 2);
  __half* s2U = (__half*)alloc((size_t)U_N * 2);
  __half* s2I = (__half*)alloc((size_t)I_N * 2);
  // union tail: storage (24 MB, dead after k_build2) aliases fB (first write: agg L1)
  size_t union_off = off;
  int* storage = (int*)alloc((size_t)NBK * CAP * 4);
  size_t end_storage = off;
  off = union_off;
  __half* fB_U = (__half*)alloc((size_t)U_N * 64 * 2);
  __half* fB_I = (__half*)alloc((size_t)I_N * 64 * 2);
  if (off < end_storage) off = end_storage;

  // CSR/CSC build (exact rows; count fused into build2) + active-node compaction
  hipMemsetAsync(bcnt, 0, (size_t)(NBK + 16 + UI_N) * 4, stream);
  k_build1<<<NBLD, 1024, 0, stream>>>(edge_u, edge_i, bcnt, storage);
  k_scanb<<<1, 1024, 0, stream>>>(bcnt, bbase);
  k_build2<<<NBK, 256, 0, stream>>>(bcnt, storage, bbase, ptr, col);
  k_flag<<<(B_N + 255) / 256, 256, 0, stream>>>(userIdx, itemIdx, flag);
  k_compact<<<NBK, 256, 0, stream>>>(flag, list, nm);

  // Layer 1: mm (fp32 in -> fA fp16 + scores); agg over ALL nodes (fA -> fB)
  k_mm2<<<NB_U + NB_I, 256, 0, stream>>>(uEmbd, iEmbd, (const __half*)nullptr,
                                         (const __half*)nullptr, Wu_h, Wi_h, a_h, 1,
                                         fA_U, fA_I, s16U, s16I);
  k_aggL1<<<UI_N * 32 / 256, 256, 0, stream>>>(ptr, col, fA_U, fA_I, fB_U, fB_I,
                                               s16U, s16I);

  // Layer 2: mm over ALL nodes (fB -> fA + s2); agg over ACTIVE nodes only
  k_mm2<<<NB_U + NB_I, 256, 0, stream>>>((const float*)nullptr, (const float*)nullptr,
                                         fB_U, fB_I, Wu_out, Wi_out, a_out, 2,
                                         fA_U, fA_I, s2U, s2I);
  k_aggL2<<<MAXACT * 32 / 256, 256, 0, stream>>>(ptr, col, fA_U, fA_I, fB_U, fB_I,
                                                 s2U, s2I, list, nm);

  // Final per-pair dot (fp16 features)
  k_dot<<<B_N / 32, 256, 0, stream>>>(userIdx, itemIdx, fB_U, fB_I, out);
}

// Round 17
// 304.911 us; speedup vs baseline: 1.3857x; 1.0827x over previous
//
#include <hip/hip_runtime.h>
#include <hip/hip_fp16.h>

#define U_N 50000
#define I_N 100000
#define E_N 1600000
#define B_N 16384
#define UI_N (U_N + I_N)   // 150000
#define NB_U 782           // ceil(50000/64)
#define NB_I 1563          // ceil(100000/64)
#define NBK 586            // ceil(150000/256) buckets, 256 nodes each
#define CAP 10240          // entries per bucket (mean 8192 max, ~22 sigma margin)
#define NBLD 512           // blocks in k_build1
#define CHUNK (E_N / NBLD) // 3125 edges per block
#define COL_CAP 3300000    // >= 2E exact CSR slots
#define MAXACT 32768       // max unique dot nodes (16384 users + 16384 items)

// ---------------- CSR build: phase 1 (block-local binning, packed 4B entries) ---------
__global__ __launch_bounds__(1024) void k_build1(
    const int* __restrict__ eu, const int* __restrict__ ei,
    int* __restrict__ bcnt, int* __restrict__ storage) {
  __shared__ int hist[NBK];
  __shared__ int lbase[NBK];
  __shared__ int loff[NBK];
  int t = threadIdx.x;
  for (int b = t; b < NBK; b += 1024) { hist[b] = 0; loff[b] = 0; }
  __syncthreads();
  int e0 = blockIdx.x * CHUNK;
  int myu[4], myi[4];
  int ne = 0;
#pragma unroll
  for (int k = 0; k < 4; k++) {
    int e = e0 + t + 1024 * k;
    if (e < e0 + CHUNK) {
      int u = eu[e], it = ei[e];
      myu[k] = u;
      myi[k] = it;
      ne = k + 1;
      atomicAdd(&hist[u >> 8], 1);
      atomicAdd(&hist[(U_N + it) >> 8], 1);
    }
  }
  __syncthreads();
  for (int b = t; b < NBK; b += 1024) {
    int h = hist[b];
    lbase[b] = h ? atomicAdd(&bcnt[b], h) : 0;
  }
  __syncthreads();
#pragma unroll
  for (int k = 0; k < 4; k++) {
    if (k < ne) {
      int u = myu[k], it = myi[k];
      int k2 = U_N + it;
      int b1 = u >> 8;
      int s1 = lbase[b1] + atomicAdd(&loff[b1], 1);
      storage[(size_t)b1 * CAP + s1] = ((u & 255) << 17) | it;
      int b2 = k2 >> 8;
      int s2 = lbase[b2] + atomicAdd(&loff[b2], 1);
      storage[(size_t)b2 * CAP + s2] = ((k2 & 255) << 17) | u;
    }
  }
}

// ---------------- single-block exclusive scan over bucket entry counts ----------------
__global__ __launch_bounds__(1024) void k_scanb(const int* __restrict__ bcnt,
                                                int* __restrict__ bbase) {
  __shared__ int sc[1024];
  int t = threadIdx.x;
  int v = (t < NBK) ? bcnt[t] : 0;
  sc[t] = v;
  __syncthreads();
  int val = v;
  for (int off = 1; off < 1024; off <<= 1) {
    int x = (t >= off) ? sc[t - off] : 0;
    __syncthreads();
    val += x;
    sc[t] = val;
    __syncthreads();
  }
  if (t < NBK) bbase[t] = val - v;  // exclusive
}

// ---- CSR build: phase 2 FUSED (count pass -> LDS prefix -> ptr write -> scatter) ----
__global__ __launch_bounds__(256) void k_build2(const int* __restrict__ bcnt,
                                                const int* __restrict__ storage,
                                                const int* __restrict__ bbase,
                                                int* __restrict__ ptr,
                                                int* __restrict__ col) {
  __shared__ int c[256];
  __shared__ int sc[256];
  __shared__ int pb[256];
  __shared__ int cur[256];
  int b = blockIdx.x;
  int t = threadIdx.x;
  c[t] = 0;
  __syncthreads();
  int n = bcnt[b];
  const int* s = storage + (size_t)b * CAP;
  for (int i = t; i < n; i += 256) atomicAdd(&c[s[i] >> 17], 1);
  __syncthreads();
  int deg = c[t];
  sc[t] = deg;
  __syncthreads();
  int val = deg;
  for (int off = 1; off < 256; off <<= 1) {
    int x = (t >= off) ? sc[t - off] : 0;
    __syncthreads();
    val += x;
    sc[t] = val;
    __syncthreads();
  }
  int base = bbase[b];
  int myPtr = base + (val - deg);
  pb[t] = myPtr;
  cur[t] = 0;
  int node = b * 256 + t;
  if (node < UI_N) ptr[node] = myPtr;
  if (b == NBK - 1 && t == 255) ptr[UI_N] = base + val;
  __syncthreads();
  for (int i = t; i < n; i += 256) {
    int e = s[i];
    int local = e >> 17;
    int slot = pb[local] + atomicAdd(&cur[local], 1);
    col[slot] = e & 0x1FFFF;
  }
}

// ---------------- Fused active-node flag + compaction (one kernel) ----------------
__global__ void k_flagc(const int* __restrict__ uIdx, const int* __restrict__ iIdx,
                        int* __restrict__ flag, int* __restrict__ list,
                        int* __restrict__ nm) {
  int b = blockIdx.x * blockDim.x + threadIdx.x;
  if (b < B_N) {
    int u = uIdx[b];
    if (atomicExch(&flag[u], 1) == 0) list[atomicAdd(nm, 1)] = u;
    int it = U_N + iIdx[b];
    if (atomicExch(&flag[it], 1) == 0) list[atomicAdd(nm, 1)] = it;
  }
}

// ---------------- Fused matmul + attention scores (users + items, one launch) ---------
__global__ __launch_bounds__(256) void k_mm2(
    const float* __restrict__ Xu32, const float* __restrict__ Xi32,
    const __half* __restrict__ Xu16, const __half* __restrict__ Xi16,
    const float* __restrict__ Wu, const float* __restrict__ Wi,
    const float* __restrict__ a, int layer,
    __half* __restrict__ fA_U, __half* __restrict__ fA_I,
    __half* __restrict__ s16U, __half* __restrict__ s16I) {
  __shared__ float Wl[4096];
  __shared__ float Xs[4096];
  const bool isU = blockIdx.x < NB_U;
  const int N = isU ? U_N : I_N;
  const int base = (isU ? blockIdx.x : blockIdx.x - NB_U) * 64;
  const float* W = isU ? Wu : Wi;
  __half* f16 = isU ? fA_U : fA_I;
  __half* s16 = isU ? s16U : s16I;
  const int aoff = (layer == 1) ? (isU ? 0 : 8) : (isU ? 0 : 64);
  int t = threadIdx.x;

  if (layer == 1) {
#pragma unroll
    for (int k = 0; k < 4; k++) {
      int i = t + 256 * k;
      int h = i >> 7, d = (i >> 1) & 63, half = i & 1;
      float4 v = *(const float4*)(W + h * 512 + d * 8 + half * 4);
      *(float4*)(Wl + d * 64 + h * 8 + half * 4) = v;
    }
    const float* X = isU ? Xu32 : Xi32;
#pragma unroll
    for (int k = 0; k < 4; k++) {
      int i = t + 256 * k;
      int r = i >> 4, ch = i & 15;
      int node = base + r;
      float4 v = make_float4(0.f, 0.f, 0.f, 0.f);
      if (node < N) v = *(const float4*)(X + (size_t)node * 64 + ch * 4);
      *(float4*)(Xs + r * 64 + ch * 4) = v;
    }
  } else {
#pragma unroll
    for (int k = 0; k < 4; k++) {
      int i = t + 256 * k;
      *(float4*)(Wl + i * 4) = *(const float4*)(W + i * 4);
    }
    const __half* X = isU ? Xu16 : Xi16;
#pragma unroll
    for (int k = 0; k < 4; k++) {
      int i = t + 256 * k;
      int r = i >> 4, ch = i & 15;
      int node = base + r;
      float4 v = make_float4(0.f, 0.f, 0.f, 0.f);
      if (node < N) {
        const __half2* hp = (const __half2*)(X + (size_t)node * 64 + ch * 4);
        float2 f0 = __half22float2(hp[0]);
        float2 f1 = __half22float2(hp[1]);
        v = make_float4(f0.x, f0.y, f1.x, f1.y);
      }
      *(float4*)(Xs + r * 64 + ch * 4) = v;
    }
  }
  __syncthreads();

  const int c0 = t & 31;
  const int rb = t >> 5;
  float acc0[8], acc1[8];
#pragma unroll
  for (int k = 0; k < 8; k++) { acc0[k] = 0.f; acc1[k] = 0.f; }

  for (int d0 = 0; d0 < 64; d0 += 4) {
    float2 wA = *(float2*)(Wl + (d0 + 0) * 64 + 2 * c0);
    float2 wB = *(float2*)(Wl + (d0 + 1) * 64 + 2 * c0);
    float2 wC = *(float2*)(Wl + (d0 + 2) * 64 + 2 * c0);
    float2 wD = *(float2*)(Wl + (d0 + 3) * 64 + 2 * c0);
#pragma unroll
    for (int k = 0; k < 8; k++) {
      float4 x = *(float4*)(Xs + (rb + 8 * k) * 64 + d0);
      acc0[k] += x.x * wA.x + x.y * wB.x + x.z * wC.x + x.w * wD.x;
      acc1[k] += x.x * wA.y + x.y * wB.y + x.z * wC.y + x.w * wD.y;
    }
  }

  float av0, av1;
  if (layer == 1) {
    int h = c0 >> 2, j = 2 * (c0 & 3);
    av0 = a[h * 16 + aoff + j];
    av1 = a[h * 16 + aoff + j + 1];
  } else {
    av0 = a[aoff + 2 * c0];
    av1 = a[aoff + 2 * c0 + 1];
  }
#pragma unroll
  for (int k = 0; k < 8; k++) {
    int node = base + rb + 8 * k;
    float s = acc0[k] * av0 + acc1[k] * av1;
    s += __shfl_xor(s, 1);
    s += __shfl_xor(s, 2);
    if (layer != 1) {
      s += __shfl_xor(s, 4);
      s += __shfl_xor(s, 8);
      s += __shfl_xor(s, 16);
    }
    if (node < N) {
      float2 f;
      f.x = acc0[k];
      f.y = acc1[k];
      *(__half2*)(f16 + (size_t)node * 64 + 2 * c0) = __float22half2_rn(f);
      if (layer == 1) {
        if ((c0 & 3) == 0) s16[node * 8 + (c0 >> 2)] = __float2half_rn(s);
      } else {
        if (c0 == 0) s16[node] = __float2half_rn(s);
      }
    }
  }
}

// ---------------- Fused aggregation body: TWO nodes per wave, unroll-4 ----------------
// Inactive half-waves: deg forced to 0 (no loop, no store) — runaway-proof.
template <int LAYER>
__device__ __forceinline__ void agg_body(
    const int* __restrict__ ptr, const int* __restrict__ col,
    const __half* __restrict__ fA_U, const __half* __restrict__ fA_I,
    __half* __restrict__ fB_U, __half* __restrict__ fB_I,
    const __half* __restrict__ s16U, const __half* __restrict__ s16I,
    const int* __restrict__ list, const int* __restrict__ nm) {
  int gid = blockIdx.x * blockDim.x + threadIdx.x;
  int wv = gid >> 6;
  int l = threadIdx.x & 63;
  int half = l >> 5;
  int idx = wv * 2 + half;
  bool act = true;
  int n;
  if (LAYER == 2) {
    act = idx < *nm;
    n = act ? list[idx] : 0;         // node 0 always a valid row
  } else {
    n = idx;                         // UI_N even; pairs never straddle U/I
  }
  int lh = l & 31;
  int g = lh >> 3;
  int cc = lh & 7;
  bool isU = n < U_N;
  int nl = isU ? n : n - U_N;
  const char* nbrF = (const char*)(isU ? fA_I : fA_U);
  const char* nbrS = (const char*)(isU ? s16I : s16U);
  const __half* selfS = isU ? s16U : s16I;
  const __half* selfF = isU ? fA_U : fA_I;
  __half* outp = isU ? fB_U : fB_I;
  const char* colc = (const char*)col;

  int beg = ptr[n], endA = ptr[n + 1];
  int deg = act ? (endA - beg) : 0;  // hazard clamp: inactive -> no loop
  unsigned coff = ((unsigned)(beg + g)) << 2;
  const unsigned begb = (unsigned)beg << 2;
  const unsigned fsh = (unsigned)cc << 4;
  const unsigned ssh = (LAYER == 1) ? ((unsigned)cc << 1) : 0u;
  float sself = (LAYER == 1) ? __half2float(selfS[(size_t)nl * 8 + cc])
                             : __half2float(selfS[nl]);
  float acc[8];
#pragma unroll
  for (int k = 0; k < 8; k++) acc[k] = 0.f;
  float wsum = 0.f;

  auto edge = [&](unsigned off) {
    int nb = *(const int*)(colc + off);
    unsigned so = (LAYER == 1) ? (((unsigned)nb << 4) + ssh) : ((unsigned)nb << 1);
    float x = sself + __half2float(*(const __half*)(nbrS + so));
    float4 r = *(const float4*)(nbrF + (((unsigned)nb << 7) + fsh));
    float w = __expf(-fmaxf(x, 0.2f * x));
    wsum += w;
    const __half* h = (const __half*)&r;
#pragma unroll
    for (int k = 0; k < 8; k++) acc[k] += w * (float)h[k];
  };
  auto edgem = [&](unsigned off, bool valid) {
    unsigned o = valid ? off : begb;
    int nb = *(const int*)(colc + o);
    unsigned so = (LAYER == 1) ? (((unsigned)nb << 4) + ssh) : ((unsigned)nb << 1);
    float x = sself + __half2float(*(const __half*)(nbrS + so));
    float4 r = *(const float4*)(nbrF + (((unsigned)nb << 7) + fsh));
    float w = valid ? __expf(-fmaxf(x, 0.2f * x)) : 0.f;
    wsum += w;
    const __half* h = (const __half*)&r;
#pragma unroll
    for (int k = 0; k < 8; k++) acc[k] += w * (float)h[k];
  };

  int q = deg >> 4;
  for (; q > 0; q--) {
    edge(coff);
    edge(coff + 16);
    edge(coff + 32);
    edge(coff + 48);
    coff += 64;
  }
  int rem = deg & 15;
  if (rem) {
    edgem(coff, g < rem);
    edgem(coff + 16, (4 + g) < rem);
    edgem(coff + 32, (8 + g) < rem);
    edgem(coff + 48, (12 + g) < rem);
  }

#pragma unroll
  for (int k = 0; k < 8; k++) {
    acc[k] += __shfl_xor(acc[k], 8);
    acc[k] += __shfl_xor(acc[k], 16);
  }
  wsum += __shfl_xor(wsum, 8);
  wsum += __shfl_xor(wsum, 16);

  if (lh < 8 && act) {
    float4 raw = *(const float4*)(selfF + (size_t)nl * 64 + cc * 8);
    const __half2* sp = (const __half2*)&raw;
    float2 s0 = __half22float2(sp[0]);
    float2 s1 = __half22float2(sp[1]);
    float2 s2 = __half22float2(sp[2]);
    float2 s3 = __half22float2(sp[3]);
    float v[8] = {s0.x, s0.y, s1.x, s1.y, s2.x, s2.y, s3.x, s3.y};
    if (deg > 0) {
      float inv = 1.f / wsum;
#pragma unroll
      for (int k = 0; k < 8; k++) v[k] += acc[k] * inv;
    }
#pragma unroll
    for (int k = 0; k < 8; k++) v[k] = (v[k] > 0.f) ? v[k] : (__expf(v[k]) - 1.f);
    __half2 o[4];
    o[0] = __floats2half2_rn(v[0], v[1]);
    o[1] = __floats2half2_rn(v[2], v[3]);
    o[2] = __floats2half2_rn(v[4], v[5]);
    o[3] = __floats2half2_rn(v[6], v[7]);
    *(float4*)(outp + (size_t)nl * 64 + cc * 8) = *(float4*)o;
  }
}

__global__ __launch_bounds__(256) void k_aggL1(
    const int* __restrict__ ptr, const int* __restrict__ col,
    const __half* __restrict__ fA_U, const __half* __restrict__ fA_I,
    __half* __restrict__ fB_U, __half* __restrict__ fB_I,
    const __half* __restrict__ s16U, const __half* __restrict__ s16I) {
  agg_body<1>(ptr, col, fA_U, fA_I, fB_U, fB_I, s16U, s16I, nullptr, nullptr);
}

__global__ __launch_bounds__(256) void k_aggL2(
    const int* __restrict__ ptr, const int* __restrict__ col,
    const __half* __restrict__ fA_U, const __half* __restrict__ fA_I,
    __half* __restrict__ fB_U, __half* __restrict__ fB_I,
    const __half* __restrict__ s2U, const __half* __restrict__ s2I,
    const int* __restrict__ list, const int* __restrict__ nm) {
  agg_body<2>(ptr, col, fA_U, fA_I, fB_U, fB_I, s2U, s2I, list, nm);
}

// ---------------- Final pair dot (fp16 inputs; 32 pairs/block, 8 lanes each) ----------
__global__ void k_dot(const int* __restrict__ uIdx, const int* __restrict__ iIdx,
                      const __half* __restrict__ u_f, const __half* __restrict__ i_f,
                      float* __restrict__ out) {
  int t = threadIdx.x;
  int pair = blockIdx.x * 32 + (t >> 3);
  int cc = t & 7;
  float4 ra = *(const float4*)(u_f + (size_t)uIdx[pair] * 64 + cc * 8);
  float4 rb = *(const float4*)(i_f + (size_t)iIdx[pair] * 64 + cc * 8);
  const __half* ha = (const __half*)&ra;
  const __half* hb = (const __half*)&rb;
  float v = 0.f;
#pragma unroll
  for (int k = 0; k < 8; k++) v += (float)ha[k] * (float)hb[k];
  v += __shfl_xor(v, 1);
  v += __shfl_xor(v, 2);
  v += __shfl_xor(v, 4);
  if (cc == 0) out[pair] = v;
}

extern "C" void kernel_launch(void* const* d_in, const int* in_sizes, int n_in,
                              void* d_out, int out_size, void* d_ws, size_t ws_size,
                              hipStream_t stream) {
  const int* userIdx = (const int*)d_in[0];
  const int* itemIdx = (const int*)d_in[1];
  const int* edge_u = (const int*)d_in[2];
  const int* edge_i = (const int*)d_in[3];
  const float* uEmbd = (const float*)d_in[4];
  const float* iEmbd = (const float*)d_in[5];
  const float* Wu_h = (const float*)d_in[6];
  const float* Wi_h = (const float*)d_in[7];
  const float* a_h = (const float*)d_in[8];
  const float* Wu_out = (const float*)d_in[9];
  const float* Wi_out = (const float*)d_in[10];
  const float* a_out = (const float*)d_in[11];
  float* out = (float*)d_out;

  char* w = (char*)d_ws;
  size_t off = 0;
  auto alloc = [&](size_t bytes) -> void* {
    void* p = w + off;
    off += (bytes + 511) & ~(size_t)511;
    return p;
  };
  // zero-init block: bcnt[NBK] | nm[1..pad 16] | flag[UI_N] — one memset
  int* bcnt = (int*)alloc((size_t)(NBK + 16 + UI_N) * 4);
  int* nm = bcnt + NBK;
  int* flag = bcnt + NBK + 16;
  int* ptr = (int*)alloc((size_t)(UI_N + 1) * 4);
  int* bbase = (int*)alloc(4096);
  int* list = (int*)alloc((size_t)MAXACT * 4);
  int* col = (int*)alloc((size_t)COL_CAP * 4);
  // fA (pre-agg gather tables) and scores: NOT aliased with storage
  __half* fA_U = (__half*)alloc((size_t)U_N * 64 * 2);
  __half* fA_I = (__half*)alloc((size_t)I_N * 64 * 2);
  __half* s16U = (__half*)alloc((size_t)U_N * 8 * 2);
  __half* s16I = (__half*)alloc((size_t)I_N * 8 * 2);
  __half* s2U = (__half*)alloc((size_t)U_N * 2);
  __half* s2I = (__half*)alloc((size_t)I_N * 2);
  // union tail: storage (24 MB, dead after k_build2) aliases fB (first write: agg L1)
  size_t union_off = off;
  int* storage = (int*)alloc((size_t)NBK * CAP * 4);
  size_t end_storage = off;
  off = union_off;
  __half* fB_U = (__half*)alloc((size_t)U_N * 64 * 2);
  __half* fB_I = (__half*)alloc((size_t)I_N * 64 * 2);
  if (off < end_storage) off = end_storage;

  // CSR/CSC build (exact rows; count fused into build2) + fused flag/compact
  hipMemsetAsync(bcnt, 0, (size_t)(NBK + 16 + UI_N) * 4, stream);
  k_build1<<<NBLD, 1024, 0, stream>>>(edge_u, edge_i, bcnt, storage);
  k_scanb<<<1, 1024, 0, stream>>>(bcnt, bbase);
  k_build2<<<NBK, 256, 0, stream>>>(bcnt, storage, bbase, ptr, col);
  k_flagc<<<(B_N + 255) / 256, 256, 0, stream>>>(userIdx, itemIdx, flag, list, nm);

  // Layer 1: mm (fp32 in -> fA fp16 + scores); agg over ALL nodes (fA -> fB)
  k_mm2<<<NB_U + NB_I, 256, 0, stream>>>(uEmbd, iEmbd, (const __half*)nullptr,
                                         (const __half*)nullptr, Wu_h, Wi_h, a_h, 1,
                                         fA_U, fA_I, s16U, s16I);
  k_aggL1<<<UI_N * 32 / 256, 256, 0, stream>>>(ptr, col, fA_U, fA_I, fB_U, fB_I,
                                               s16U, s16I);

  // Layer 2: mm over ALL nodes (fB -> fA + s2); agg over ACTIVE nodes only
  k_mm2<<<NB_U + NB_I, 256, 0, stream>>>((const float*)nullptr, (const float*)nullptr,
                                         fB_U, fB_I, Wu_out, Wi_out, a_out, 2,
                                         fA_U, fA_I, s2U, s2I);
  k_aggL2<<<MAXACT * 32 / 256, 256, 0, stream>>>(ptr, col, fA_U, fA_I, fB_U, fB_I,
                                                 s2U, s2I, list, nm);

  // Final per-pair dot (fp16 features)
  k_dot<<<B_N / 32, 256, 0, stream>>>(userIdx, itemIdx, fB_U, fB_I, out);
}